// Round 13
// baseline (673.610 us; speedup 1.0000x reference)
//
#include <hip/hip_runtime.h>
#include <stdint.h>

#define N_NODES 100000
#define N_EDGES 600000
#define DMODEL  128
#define NLAYERS 4
#define NGRAPH  128
#define NCLASS  10
#define BN_EPS  1e-5f
#define NSLOT   32     // stat partial slots (atomic contention spreading)
#define STATSZ  (NSLOT * 2 * DMODEL)   // floats per layer-stat buffer

typedef __bf16 bf16x8 __attribute__((ext_vector_type(8)));
typedef __bf16 bf16x4 __attribute__((ext_vector_type(4)));
typedef __bf16 bf16x2 __attribute__((ext_vector_type(2)));
typedef float  f32x4  __attribute__((ext_vector_type(4)));

// ------- init: zero all per-layer stat buffers, psum, deg; transpose+split W;
//         graph boundaries by binary search -------
__global__ void k_init(int* __restrict__ deg, float* __restrict__ statA,
                       float* __restrict__ statB, float* __restrict__ psum,
                       const float* __restrict__ w1, const float* __restrict__ w2,
                       __bf16* __restrict__ wt_hi, __bf16* __restrict__ wt_lo,
                       const int* __restrict__ batch, int* __restrict__ gstart) {
  int i = blockIdx.x * 256 + threadIdx.x;   // grid 512*256 = 131072
  if (i < N_NODES) deg[i] = 0;
  if (i < NLAYERS * STATSZ) {               // 32768 floats each
    statA[i] = 0.0f;
    statB[i] = 0.0f;
  }
  if (i < NGRAPH * DMODEL) psum[i] = 0.0f;
  // weight transpose + hi/lo split: wt[mat][n][k] = split(w[mat][k][n])
  {
    int mat = i >> 14;
    int rem = i & 16383;
    int n = rem >> 7;
    int k = rem & 127;
    int l = mat >> 1;
    int which = mat & 1;
    const float* w = which ? w2 : w1;
    float v = w[(size_t)l * DMODEL * DMODEL + (size_t)k * DMODEL + n];
    __bf16 hi = (__bf16)v;
    wt_hi[i] = hi;
    wt_lo[i] = (__bf16)(v - (float)hi);
  }
  // graph boundaries by binary search over sorted batch
  if (i <= NGRAPH) {
    int lo = 0;
    int hi = N_NODES;
    while (lo < hi) {
      int mid = (lo + hi) >> 1;
      if (batch[mid] < i) lo = mid + 1; else hi = mid;
    }
    gstart[i] = lo;
  }
}

// ---------------- embedding gather: h[i,:] = bf16(emb[x[i],:]), 16B stores --------
__global__ void k_embed(const int* __restrict__ x, const float* __restrict__ emb,
                        __bf16* __restrict__ h) {
  int idx = blockIdx.x * 256 + threadIdx.x;        // over N*D/8 = 1.6M
  if (idx >= N_NODES * DMODEL / 8) return;
  int i = idx >> 4;
  int p = idx & 15;
  const float* src = emb + (size_t)x[i] * DMODEL + p * 8;
  float4 v0 = *(const float4*)(src);
  float4 v1 = *(const float4*)(src + 4);
  bf16x8 o;
  o[0] = (__bf16)v0.x; o[1] = (__bf16)v0.y; o[2] = (__bf16)v0.z; o[3] = (__bf16)v0.w;
  o[4] = (__bf16)v1.x; o[5] = (__bf16)v1.y; o[6] = (__bf16)v1.z; o[7] = (__bf16)v1.w;
  *(bf16x8*)(h + (size_t)i * DMODEL + p * 8) = o;
}

// ---------------- CSR build ----------------
__global__ void k_hist(const int* __restrict__ dst, int* __restrict__ deg) {
  int e = blockIdx.x * 256 + threadIdx.x;
  if (e < N_EDGES) atomicAdd(&deg[dst[e]], 1);
}

__global__ void k_scan1(const int* __restrict__ deg, int* __restrict__ out,
                        int* __restrict__ bsum, int n) {
  __shared__ int lds[256];
  int t = threadIdx.x;
  int idx = blockIdx.x * 256 + t;
  int v = (idx < n) ? deg[idx] : 0;
  int val = v;
  lds[t] = val;
  for (int ofs = 1; ofs < 256; ofs <<= 1) {
    __syncthreads();
    int u = (t >= ofs) ? lds[t - ofs] : 0;
    __syncthreads();
    val += u;
    lds[t] = val;
  }
  if (idx < n) out[idx] = val - v;           // exclusive within chunk
  if (t == 255) bsum[blockIdx.x] = val;      // chunk total
}

__global__ void k_scan2(const int* __restrict__ bsum, int* __restrict__ bsumx, int nb) {
  __shared__ int lds[512];
  int t = threadIdx.x;
  int v = (t < nb) ? bsum[t] : 0;
  int val = v;
  lds[t] = val;
  for (int ofs = 1; ofs < 512; ofs <<= 1) {
    __syncthreads();
    int u = (t >= ofs) ? lds[t - ofs] : 0;
    __syncthreads();
    val += u;
    lds[t] = val;
  }
  if (t < nb) bsumx[t] = val - v;
}

__global__ void k_scan3(int* __restrict__ row_start, int* __restrict__ cursor,
                        const int* __restrict__ bsumx, int n, int total) {
  int idx = blockIdx.x * 256 + threadIdx.x;
  if (idx < n) {
    int v = row_start[idx] + bsumx[blockIdx.x];
    row_start[idx] = v;
    cursor[idx] = v;
  }
  if (idx == 0) row_start[n] = total;
}

// pack each edge as 16B {src, a0, a1, pad} at its CSR slot
__global__ void k_scatter(const int* __restrict__ ei, const float* __restrict__ ea,
                          int* __restrict__ cursor, int4* __restrict__ epack) {
  int e = blockIdx.x * 256 + threadIdx.x;
  if (e >= N_EDGES) return;
  int s = ei[e];
  int d = ei[N_EDGES + e];
  int pos = atomicAdd(&cursor[d], 1);
  int4 pk;
  pk.x = s;
  pk.y = __float_as_int(ea[2 * e]);
  pk.z = __float_as_int(ea[2 * e + 1]);
  pk.w = 0;
  epack[pos] = pk;
}

// ------- message + aggregate: z = act(h_i) + sum_in relu(act(h_src) + edge_lin) -----
// act(h) = relu(s*h + t) with s/t from the PREVIOUS layer's BN2, finalized HERE in a
// fused prologue (round-12 pattern): tid<128 redundantly reduces statPrev (32 L2-hot
// slots) -> s/t in LDS, one barrier, then the edge loop. Reduction order matches the
// old k_bnfin -> bit-identical s/t. hasT=0 (layer 0): skip.
// HALF-WAVE per node: 32 lanes x 4 channels (bf16x4 8B gathers), 8 nodes/block.
__global__ void __launch_bounds__(256) k_agg(
    const __bf16* __restrict__ h, const int* __restrict__ row_start,
    const int4* __restrict__ epack,
    const float* __restrict__ ew,       // edge_w + l*2*D, layout [2][D]
    const float* __restrict__ ebp,      // edge_b + l*D
    const float* __restrict__ statPrev, // statB of layer l-1 (or null)
    const float* __restrict__ gamma, const float* __restrict__ beta, int hasT,
    __bf16* __restrict__ z) {
  __shared__ float sld[DMODEL];
  __shared__ float tld[DMODEL];
  int tid = threadIdx.x;
  if (hasT) {
    if (tid < DMODEL) {
      float sum = 0.0f;
      float sq = 0.0f;
      for (int p = 0; p < NSLOT; ++p) {
        sum += statPrev[p * (2 * DMODEL) + tid];
        sq  += statPrev[p * (2 * DMODEL) + DMODEL + tid];
      }
      float mean = sum * (1.0f / N_NODES);
      float var = sq * (1.0f / N_NODES) - mean * mean;
      float inv = rsqrtf(var + BN_EPS);
      float s = gamma[tid] * inv;
      sld[tid] = s;
      tld[tid] = beta[tid] - mean * s;
    }
    __syncthreads();
  }

  int node = blockIdx.x * 8 + (tid >> 5);
  int ln = tid & 31;
  int d0 = ln * 4;

  float4 ew0 = *(const float4*)(ew + d0);
  float4 ew1 = *(const float4*)(ew + DMODEL + d0);
  float4 eb  = *(const float4*)(ebp + d0);
  float4 s4;
  float4 t4;
  if (hasT) {
    s4 = *(const float4*)(sld + d0);
    t4 = *(const float4*)(tld + d0);
  }

  bf16x4 hv = *(const bf16x4*)(h + (size_t)node * DMODEL + d0);
  float acc0, acc1, acc2, acc3;
  {
    float r0 = (float)hv[0];
    float r1 = (float)hv[1];
    float r2 = (float)hv[2];
    float r3 = (float)hv[3];
    if (hasT) {
      acc0 = fmaxf(s4.x * r0 + t4.x, 0.0f);
      acc1 = fmaxf(s4.y * r1 + t4.y, 0.0f);
      acc2 = fmaxf(s4.z * r2 + t4.z, 0.0f);
      acc3 = fmaxf(s4.w * r3 + t4.w, 0.0f);
    } else {
      acc0 = r0; acc1 = r1; acc2 = r2; acc3 = r3;
    }
  }

  int j0 = row_start[node];
  int j1 = row_start[node + 1];
  int j = j0;

#define AGG_ONE(E, V)                                                          \
  {                                                                            \
    float a0 = __int_as_float((E).y);                                          \
    float a1 = __int_as_float((E).z);                                          \
    float f0 = (float)(V)[0];                                                  \
    float f1 = (float)(V)[1];                                                  \
    float f2 = (float)(V)[2];                                                  \
    float f3 = (float)(V)[3];                                                  \
    if (hasT) {                                                                \
      f0 = fmaxf(s4.x * f0 + t4.x, 0.0f);                                      \
      f1 = fmaxf(s4.y * f1 + t4.y, 0.0f);                                      \
      f2 = fmaxf(s4.z * f2 + t4.z, 0.0f);                                      \
      f3 = fmaxf(s4.w * f3 + t4.w, 0.0f);                                      \
    }                                                                          \
    acc0 += fmaxf(f0 + a0 * ew0.x + a1 * ew1.x + eb.x, 0.0f);                  \
    acc1 += fmaxf(f1 + a0 * ew0.y + a1 * ew1.y + eb.y, 0.0f);                  \
    acc2 += fmaxf(f2 + a0 * ew0.z + a1 * ew1.z + eb.z, 0.0f);                  \
    acc3 += fmaxf(f3 + a0 * ew0.w + a1 * ew1.w + eb.w, 0.0f);                  \
  }

  for (; j + 4 <= j1; j += 4) {
    int4 e0 = epack[j];
    int4 e1 = epack[j + 1];
    int4 e2 = epack[j + 2];
    int4 e3 = epack[j + 3];
    bf16x4 v0 = *(const bf16x4*)(h + (size_t)e0.x * DMODEL + d0);
    bf16x4 v1 = *(const bf16x4*)(h + (size_t)e1.x * DMODEL + d0);
    bf16x4 v2 = *(const bf16x4*)(h + (size_t)e2.x * DMODEL + d0);
    bf16x4 v3 = *(const bf16x4*)(h + (size_t)e3.x * DMODEL + d0);
    AGG_ONE(e0, v0)
    AGG_ONE(e1, v1)
    AGG_ONE(e2, v2)
    AGG_ONE(e3, v3)
  }
  for (; j < j1; ++j) {
    int4 e0 = epack[j];
    bf16x4 v0 = *(const bf16x4*)(h + (size_t)e0.x * DMODEL + d0);
    AGG_ONE(e0, v0)
  }
#undef AGG_ONE

  bf16x4 o;
  o[0] = (__bf16)acc0;
  o[1] = (__bf16)acc1;
  o[2] = (__bf16)acc2;
  o[3] = (__bf16)acc3;
  *(bf16x4*)(z + (size_t)node * DMODEL + d0) = o;
}

// ------- GEMM1: Y = X @ W + bias  (bf16 MFMA, split-W, register-B, 32-row chunks) ----
// Round-10 structure verbatim (measured local optimum). No barriers, no fences, no
// prefetch (round-9: those collapse the B-in-registers allocation).
// Fragment maps (m89/m92): A[m=lane&15][k=quad*8+j], B[n=lane&15][k=quad*8+j],
// C/D col=lane&15, row=quad*4+reg.
__global__ void __launch_bounds__(256) k_gemm1(
    const __bf16* __restrict__ X,
    const __bf16* __restrict__ Whi, const __bf16* __restrict__ Wlo,
    const float* __restrict__ bias,
    __bf16* __restrict__ Y,
    float* __restrict__ statpart) {
  int tid = threadIdx.x;
  int wave = tid >> 6;
  int lane = tid & 63;
  int n16 = lane & 15;
  int quad = lane >> 4;

  bf16x8 bhi[2][4];
  bf16x8 blo[2][4];
#pragma unroll
  for (int ct = 0; ct < 2; ++ct) {
    int n = (wave * 2 + ct) * 16 + n16;
#pragma unroll
    for (int kk = 0; kk < 4; ++kk) {
      int k0 = kk * 32 + quad * 8;
      bhi[ct][kk] = *(const bf16x8*)(Whi + (size_t)n * DMODEL + k0);
      blo[ct][kk] = *(const bf16x8*)(Wlo + (size_t)n * DMODEL + k0);
    }
  }
  float bc[2];
  bc[0] = bias[(wave * 2 + 0) * 16 + n16];
  bc[1] = bias[(wave * 2 + 1) * 16 + n16];

  float ssum[2] = {0.0f, 0.0f};
  float ssq[2] = {0.0f, 0.0f};

  const int NCHUNK = N_NODES / 32;   // 3125 exact
  for (int c = blockIdx.x; c < NCHUNK; c += gridDim.x) {
    int row0 = c * 32;
    bf16x8 a[2][4];
#pragma unroll
    for (int t = 0; t < 2; ++t) {
      const __bf16* xr = X + (size_t)(row0 + t * 16 + n16) * DMODEL;
#pragma unroll
      for (int kk = 0; kk < 4; ++kk) {
        a[t][kk] = *(const bf16x8*)(xr + kk * 32 + quad * 8);
      }
    }

    f32x4 acc[2][2];
#pragma unroll
    for (int t = 0; t < 2; ++t)
#pragma unroll
      for (int ct = 0; ct < 2; ++ct)
#pragma unroll
        for (int r = 0; r < 4; ++r) acc[t][ct][r] = 0.0f;

#pragma unroll
    for (int kk = 0; kk < 4; ++kk) {
#pragma unroll
      for (int ct = 0; ct < 2; ++ct) {
#pragma unroll
        for (int t = 0; t < 2; ++t) {
          acc[t][ct] = __builtin_amdgcn_mfma_f32_16x16x32_bf16(a[t][kk], bhi[ct][kk], acc[t][ct], 0, 0, 0);
          acc[t][ct] = __builtin_amdgcn_mfma_f32_16x16x32_bf16(a[t][kk], blo[ct][kk], acc[t][ct], 0, 0, 0);
        }
      }
    }

#pragma unroll
    for (int t = 0; t < 2; ++t) {
#pragma unroll
      for (int ct = 0; ct < 2; ++ct) {
        int col = (wave * 2 + ct) * 16 + n16;
#pragma unroll
        for (int r = 0; r < 4; ++r) {
          int row = row0 + t * 16 + quad * 4 + r;
          float v = acc[t][ct][r] + bc[ct];
          Y[(size_t)row * DMODEL + col] = (__bf16)v;
          ssum[ct] += v;
          ssq[ct] += v * v;
        }
      }
    }
  }

  int slot = blockIdx.x & (NSLOT - 1);
#pragma unroll
  for (int ct = 0; ct < 2; ++ct) {
    int col = (wave * 2 + ct) * 16 + n16;
    float s = ssum[ct];
    float q = ssq[ct];
    s += __shfl_xor(s, 16);
    q += __shfl_xor(q, 16);
    s += __shfl_xor(s, 32);
    q += __shfl_xor(q, 32);
    if (quad == 0) {
      atomicAdd(&statpart[slot * (2 * DMODEL) + col], s);
      atomicAdd(&statpart[slot * (2 * DMODEL) + DMODEL + col], q);
    }
  }
}

// ------- GEMM2: Y = relu(BN1(X)) @ W + bias, BN1 finalize fused into prologue ------
// (round-12 proven pattern: the single barrier precedes the B live range)
__global__ void __launch_bounds__(256) k_gemm2(
    const __bf16* __restrict__ X,
    const __bf16* __restrict__ Whi, const __bf16* __restrict__ Wlo,
    const float* __restrict__ bias,
    const float* __restrict__ statA,
    const float* __restrict__ gamma, const float* __restrict__ beta,
    __bf16* __restrict__ Y,
    float* __restrict__ statpart) {
  __shared__ float sld[DMODEL];
  __shared__ float tld[DMODEL];
  int tid = threadIdx.x;

  if (tid < DMODEL) {
    float sum = 0.0f;
    float sq = 0.0f;
    for (int p = 0; p < NSLOT; ++p) {
      sum += statA[p * (2 * DMODEL) + tid];
      sq  += statA[p * (2 * DMODEL) + DMODEL + tid];
    }
    float mean = sum * (1.0f / N_NODES);
    float var = sq * (1.0f / N_NODES) - mean * mean;
    float inv = rsqrtf(var + BN_EPS);
    float s = gamma[tid] * inv;
    sld[tid] = s;
    tld[tid] = beta[tid] - mean * s;
  }
  __syncthreads();

  int wave = tid >> 6;
  int lane = tid & 63;
  int n16 = lane & 15;
  int quad = lane >> 4;

  bf16x8 bhi[2][4];
  bf16x8 blo[2][4];
#pragma unroll
  for (int ct = 0; ct < 2; ++ct) {
    int n = (wave * 2 + ct) * 16 + n16;
#pragma unroll
    for (int kk = 0; kk < 4; ++kk) {
      int k0 = kk * 32 + quad * 8;
      bhi[ct][kk] = *(const bf16x8*)(Whi + (size_t)n * DMODEL + k0);
      blo[ct][kk] = *(const bf16x8*)(Wlo + (size_t)n * DMODEL + k0);
    }
  }
  float bc[2];
  bc[0] = bias[(wave * 2 + 0) * 16 + n16];
  bc[1] = bias[(wave * 2 + 1) * 16 + n16];

  float ssum[2] = {0.0f, 0.0f};
  float ssq[2] = {0.0f, 0.0f};

  const int NCHUNK = N_NODES / 32;   // 3125 exact
  for (int c = blockIdx.x; c < NCHUNK; c += gridDim.x) {
    int row0 = c * 32;
    bf16x8 a[2][4];
#pragma unroll
    for (int t = 0; t < 2; ++t) {
      const __bf16* xr = X + (size_t)(row0 + t * 16 + n16) * DMODEL;
#pragma unroll
      for (int kk = 0; kk < 4; ++kk) {
        a[t][kk] = *(const bf16x8*)(xr + kk * 32 + quad * 8);
      }
    }
#pragma unroll
    for (int kk = 0; kk < 4; ++kk) {
      int k0 = kk * 32 + quad * 8;
      float4 s0 = *(const float4*)(sld + k0);
      float4 s1 = *(const float4*)(sld + k0 + 4);
      float4 t0 = *(const float4*)(tld + k0);
      float4 t1 = *(const float4*)(tld + k0 + 4);
      float sv[8];
      float tv[8];
      sv[0] = s0.x; sv[1] = s0.y; sv[2] = s0.z; sv[3] = s0.w;
      sv[4] = s1.x; sv[5] = s1.y; sv[6] = s1.z; sv[7] = s1.w;
      tv[0] = t0.x; tv[1] = t0.y; tv[2] = t0.z; tv[3] = t0.w;
      tv[4] = t1.x; tv[5] = t1.y; tv[6] = t1.z; tv[7] = t1.w;
#pragma unroll
      for (int t = 0; t < 2; ++t) {
#pragma unroll
        for (int jj = 0; jj < 8; ++jj) {
          float f = (float)a[t][kk][jj];
          a[t][kk][jj] = (__bf16)fmaxf(sv[jj] * f + tv[jj], 0.0f);
        }
      }
    }

    f32x4 acc[2][2];
#pragma unroll
    for (int t = 0; t < 2; ++t)
#pragma unroll
      for (int ct = 0; ct < 2; ++ct)
#pragma unroll
        for (int r = 0; r < 4; ++r) acc[t][ct][r] = 0.0f;

#pragma unroll
    for (int kk = 0; kk < 4; ++kk) {
#pragma unroll
      for (int ct = 0; ct < 2; ++ct) {
#pragma unroll
        for (int t = 0; t < 2; ++t) {
          acc[t][ct] = __builtin_amdgcn_mfma_f32_16x16x32_bf16(a[t][kk], bhi[ct][kk], acc[t][ct], 0, 0, 0);
          acc[t][ct] = __builtin_amdgcn_mfma_f32_16x16x32_bf16(a[t][kk], blo[ct][kk], acc[t][ct], 0, 0, 0);
        }
      }
    }

#pragma unroll
    for (int t = 0; t < 2; ++t) {
#pragma unroll
      for (int ct = 0; ct < 2; ++ct) {
        int col = (wave * 2 + ct) * 16 + n16;
#pragma unroll
        for (int r = 0; r < 4; ++r) {
          int row = row0 + t * 16 + quad * 4 + r;
          float v = acc[t][ct][r] + bc[ct];
          Y[(size_t)row * DMODEL + col] = (__bf16)v;
          ssum[ct] += v;
          ssq[ct] += v * v;
        }
      }
    }
  }

  int slot = blockIdx.x & (NSLOT - 1);
#pragma unroll
  for (int ct = 0; ct < 2; ++ct) {
    int col = (wave * 2 + ct) * 16 + n16;
    float s = ssum[ct];
    float q = ssq[ct];
    s += __shfl_xor(s, 16);
    q += __shfl_xor(q, 16);
    s += __shfl_xor(s, 32);
    q += __shfl_xor(q, 32);
    if (quad == 0) {
      atomicAdd(&statpart[slot * (2 * DMODEL) + col], s);
      atomicAdd(&statpart[slot * (2 * DMODEL) + DMODEL + col], q);
    }
  }
}

// ------- pooling partial sums of raw h (affine deferred to classifier) -------
__global__ void k_pool(const __bf16* __restrict__ h, const int* __restrict__ gstart,
                       float* __restrict__ psum) {
  int g = blockIdx.x;
  int slice = blockIdx.y;   // 0..7
  int lane = threadIdx.x;   // 64
  int d0 = lane * 2;
  int i0 = gstart[g];
  int i1 = gstart[g + 1];
  float a0 = 0.0f;
  float a1 = 0.0f;
  for (int i = i0 + slice; i < i1; i += 8) {
    bf16x2 v = *(const bf16x2*)(h + (size_t)i * DMODEL + d0);
    a0 += (float)v[0];
    a1 += (float)v[1];
  }
  atomicAdd(&psum[g * DMODEL + d0], a0);
  atomicAdd(&psum[g * DMODEL + d0 + 1], a1);
}

// ------- classifier: fused final BN2 finalize (per-thread column reduction),
//         then mean + affine, Linear-ReLU-Linear -------
__global__ void k_classifier(const float* __restrict__ psum, const int* __restrict__ gstart,
                             const float* __restrict__ statB,
                             const float* __restrict__ gamma, const float* __restrict__ beta,
                             const float* __restrict__ cw1, const float* __restrict__ cb1,
                             const float* __restrict__ cw2, const float* __restrict__ cb2,
                             float* __restrict__ out) {
  __shared__ float pl[DMODEL];
  __shared__ float hid[DMODEL];
  int g = blockIdx.x;
  int d = threadIdx.x;
  // finalize BN2 for this column (identical reduction order -> bit-identical s/t)
  float sum = 0.0f;
  float sq = 0.0f;
  for (int p = 0; p < NSLOT; ++p) {
    sum += statB[p * (2 * DMODEL) + d];
    sq  += statB[p * (2 * DMODEL) + DMODEL + d];
  }
  float mean = sum * (1.0f / N_NODES);
  float var = sq * (1.0f / N_NODES) - mean * mean;
  float inv = rsqrtf(var + BN_EPS);
  float s2 = gamma[d] * inv;
  float t2 = beta[d] - mean * s2;

  int cnt = gstart[g + 1] - gstart[g];
  pl[d] = (cnt > 0) ? (s2 * (psum[g * DMODEL + d] / (float)cnt) + t2) : 0.0f;
  __syncthreads();
  float acc = cb1[d];
  for (int k = 0; k < DMODEL; ++k) acc += pl[k] * cw1[k * DMODEL + d];
  hid[d] = fmaxf(acc, 0.0f);
  __syncthreads();
  if (d < NCLASS) {
    float acc2 = cb2[d];
    for (int k = 0; k < DMODEL; ++k) acc2 += hid[k] * cw2[k * NCLASS + d];
    out[g * NCLASS + d] = acc2;
  }
}

// ---------------- launcher ----------------
extern "C" void kernel_launch(void* const* d_in, const int* in_sizes, int n_in,
                              void* d_out, int out_size, void* d_ws, size_t ws_size,
                              hipStream_t stream) {
  const int*   x      = (const int*)d_in[0];
  const int*   ei     = (const int*)d_in[1];
  const float* ea     = (const float*)d_in[2];
  const int*   batch  = (const int*)d_in[3];
  const float* emb    = (const float*)d_in[4];
  const float* edge_w = (const float*)d_in[5];
  const float* edge_b = (const float*)d_in[6];
  const float* w1     = (const float*)d_in[7];
  const float* b1     = (const float*)d_in[8];
  const float* g1     = (const float*)d_in[9];
  const float* beta1  = (const float*)d_in[10];
  const float* w2     = (const float*)d_in[11];
  const float* b2     = (const float*)d_in[12];
  const float* ng     = (const float*)d_in[13];
  const float* nb     = (const float*)d_in[14];
  const float* cw1    = (const float*)d_in[15];
  const float* cb1    = (const float*)d_in[16];
  const float* cw2    = (const float*)d_in[17];
  const float* cb2    = (const float*)d_in[18];

  char* ws = (char*)d_ws;
  size_t off = 0;
  auto alloc = [&](size_t bytes) -> void* {
    void* p = ws + off;
    off += (bytes + 255) & ~(size_t)255;
    return p;
  };

  __bf16* h_bf      = (__bf16*)alloc((size_t)N_NODES * DMODEL * sizeof(__bf16));
  __bf16* z_bf      = (__bf16*)alloc((size_t)N_NODES * DMODEL * sizeof(__bf16));
  __bf16* y1_bf     = (__bf16*)alloc((size_t)N_NODES * DMODEL * sizeof(__bf16));
  int*    row_start = (int*)alloc((N_NODES + 1) * sizeof(int));
  int*    cursor    = (int*)alloc(N_NODES * sizeof(int));
  int*    deg       = (int*)alloc(N_NODES * sizeof(int));
  int4*   epack     = (int4*)alloc((size_t)N_EDGES * sizeof(int4));
  __bf16* wt_hi     = (__bf16*)alloc((size_t)NLAYERS * 2 * DMODEL * DMODEL * sizeof(__bf16));
  __bf16* wt_lo     = (__bf16*)alloc((size_t)NLAYERS * 2 * DMODEL * DMODEL * sizeof(__bf16));
  float*  statA     = (float*)alloc((size_t)NLAYERS * STATSZ * sizeof(float));
  float*  statB     = (float*)alloc((size_t)NLAYERS * STATSZ * sizeof(float));
  int*    gstart    = (int*)alloc((NGRAPH + 1) * sizeof(int));
  float*  psum      = (float*)alloc((size_t)NGRAPH * DMODEL * sizeof(float));
  int*    bsum      = (int*)alloc(512 * sizeof(int));
  int*    bsumx     = (int*)alloc(512 * sizeof(int));

  auto statAL = [&](int l) { return statA + (size_t)l * STATSZ; };
  auto statBL = [&](int l) { return statB + (size_t)l * STATSZ; };

  const int nbScan = (N_NODES + 255) / 256;              // 391
  const int nbEdge = (N_EDGES + 255) / 256;              // 2344
  const int nbEmb  = (N_NODES * DMODEL / 8 + 255) / 256; // 6250
  const int nbGemm = 782;                                // grid-stride over 3125 chunks
  const int nbAgg  = N_NODES / 8;                        // 12500 (8 nodes/block)

  k_init<<<512, 256, 0, stream>>>(deg, statA, statB, psum,
                                  w1, w2, wt_hi, wt_lo, batch, gstart);
  k_embed<<<nbEmb, 256, 0, stream>>>(x, emb, h_bf);
  k_hist<<<nbEdge, 256, 0, stream>>>(ei + N_EDGES, deg);
  k_scan1<<<nbScan, 256, 0, stream>>>(deg, row_start, bsum, N_NODES);
  k_scan2<<<1, 512, 0, stream>>>(bsum, bsumx, nbScan);
  k_scan3<<<nbScan, 256, 0, stream>>>(row_start, cursor, bsumx, N_NODES, N_EDGES);
  k_scatter<<<nbEdge, 256, 0, stream>>>(ei, ea, cursor, epack);

  for (int l = 0; l < NLAYERS; ++l) {
    const float* sPrev = (l > 0) ? statBL(l - 1) : (const float*)nullptr;
    const float* gPrev = (l > 0) ? (ng + (size_t)(l - 1) * DMODEL) : (const float*)nullptr;
    const float* bPrev = (l > 0) ? (nb + (size_t)(l - 1) * DMODEL) : (const float*)nullptr;
    // z = act(h) + sum relu(act(h_src) + edge_lin); BN2(l-1) finalize fused
    k_agg<<<nbAgg, 256, 0, stream>>>(h_bf, row_start, epack,
                                     edge_w + (size_t)l * 2 * DMODEL,
                                     edge_b + (size_t)l * DMODEL,
                                     sPrev, gPrev, bPrev, (l > 0) ? 1 : 0, z_bf);
    // y1 = z @ w1[l] + b1[l]   (stats -> statA[l])
    k_gemm1<<<nbGemm, 256, 0, stream>>>(
        z_bf,
        wt_hi + (size_t)(l * 2 + 0) * DMODEL * DMODEL,
        wt_lo + (size_t)(l * 2 + 0) * DMODEL * DMODEL,
        b1 + (size_t)l * DMODEL,
        y1_bf, statAL(l));
    // h = relu(BN1(y1)) @ w2[l] + b2[l]; BN1 finalize fused; stats -> statB[l]
    k_gemm2<<<nbGemm, 256, 0, stream>>>(
        y1_bf,
        wt_hi + (size_t)(l * 2 + 1) * DMODEL * DMODEL,
        wt_lo + (size_t)(l * 2 + 1) * DMODEL * DMODEL,
        b2 + (size_t)l * DMODEL,
        statAL(l), g1 + (size_t)l * DMODEL, beta1 + (size_t)l * DMODEL,
        h_bf, statBL(l));
  }

  dim3 poolGrid(NGRAPH, 8);
  k_pool<<<poolGrid, 64, 0, stream>>>(h_bf, gstart, psum);
  k_classifier<<<NGRAPH, DMODEL, 0, stream>>>(psum, gstart, statBL(NLAYERS - 1),
                                              ng + (size_t)(NLAYERS - 1) * DMODEL,
                                              nb + (size_t)(NLAYERS - 1) * DMODEL,
                                              cw1, cb1, cw2, cb2, (float*)d_out);
}

// Round 14
// 664.041 us; speedup vs baseline: 1.0144x; 1.0144x over previous
//
#include <hip/hip_runtime.h>
#include <stdint.h>

#define N_NODES 100000
#define N_EDGES 600000
#define DMODEL  128
#define NLAYERS 4
#define NGRAPH  128
#define NCLASS  10
#define BN_EPS  1e-5f
#define NSLOT   32     // stat partial slots (atomic contention spreading)
#define STATSZ  (NSLOT * 2 * DMODEL)   // floats per layer-stat buffer
#define ZSTR    136    // LDS z-tile row stride in bf16 (128 + 8 pad -> 2-way-free banks)

typedef __bf16 bf16x8 __attribute__((ext_vector_type(8)));
typedef __bf16 bf16x4 __attribute__((ext_vector_type(4)));
typedef __bf16 bf16x2 __attribute__((ext_vector_type(2)));
typedef float  f32x4  __attribute__((ext_vector_type(4)));

// ------- init: zero per-layer stat buffers, psum, deg; transpose+split W;
//         graph boundaries by binary search -------
__global__ void k_init(int* __restrict__ deg, float* __restrict__ statA,
                       float* __restrict__ statB, float* __restrict__ psum,
                       const float* __restrict__ w1, const float* __restrict__ w2,
                       __bf16* __restrict__ wt_hi, __bf16* __restrict__ wt_lo,
                       const int* __restrict__ batch, int* __restrict__ gstart) {
  int i = blockIdx.x * 256 + threadIdx.x;   // grid 512*256 = 131072
  if (i < N_NODES) deg[i] = 0;
  if (i < NLAYERS * STATSZ) {
    statA[i] = 0.0f;
    statB[i] = 0.0f;
  }
  if (i < NGRAPH * DMODEL) psum[i] = 0.0f;
  {
    int mat = i >> 14;
    int rem = i & 16383;
    int n = rem >> 7;
    int k = rem & 127;
    int l = mat >> 1;
    int which = mat & 1;
    const float* w = which ? w2 : w1;
    float v = w[(size_t)l * DMODEL * DMODEL + (size_t)k * DMODEL + n];
    __bf16 hi = (__bf16)v;
    wt_hi[i] = hi;
    wt_lo[i] = (__bf16)(v - (float)hi);
  }
  if (i <= NGRAPH) {
    int lo = 0;
    int hi = N_NODES;
    while (lo < hi) {
      int mid = (lo + hi) >> 1;
      if (batch[mid] < i) lo = mid + 1; else hi = mid;
    }
    gstart[i] = lo;
  }
}

// ---------------- embedding gather: h[i,:] = bf16(emb[x[i],:]), 16B stores --------
__global__ void k_embed(const int* __restrict__ x, const float* __restrict__ emb,
                        __bf16* __restrict__ h) {
  int idx = blockIdx.x * 256 + threadIdx.x;        // over N*D/8
  if (idx >= N_NODES * DMODEL / 8) return;
  int i = idx >> 4;
  int p = idx & 15;
  const float* src = emb + (size_t)x[i] * DMODEL + p * 8;
  float4 v0 = *(const float4*)(src);
  float4 v1 = *(const float4*)(src + 4);
  bf16x8 o;
  o[0] = (__bf16)v0.x; o[1] = (__bf16)v0.y; o[2] = (__bf16)v0.z; o[3] = (__bf16)v0.w;
  o[4] = (__bf16)v1.x; o[5] = (__bf16)v1.y; o[6] = (__bf16)v1.z; o[7] = (__bf16)v1.w;
  *(bf16x8*)(h + (size_t)i * DMODEL + p * 8) = o;
}

// ---------------- CSR build ----------------
__global__ void k_hist(const int* __restrict__ dst, int* __restrict__ deg) {
  int e = blockIdx.x * 256 + threadIdx.x;
  if (e < N_EDGES) atomicAdd(&deg[dst[e]], 1);
}

__global__ void k_scan1(const int* __restrict__ deg, int* __restrict__ out,
                        int* __restrict__ bsum, int n) {
  __shared__ int lds[256];
  int t = threadIdx.x;
  int idx = blockIdx.x * 256 + t;
  int v = (idx < n) ? deg[idx] : 0;
  int val = v;
  lds[t] = val;
  for (int ofs = 1; ofs < 256; ofs <<= 1) {
    __syncthreads();
    int u = (t >= ofs) ? lds[t - ofs] : 0;
    __syncthreads();
    val += u;
    lds[t] = val;
  }
  if (idx < n) out[idx] = val - v;
  if (t == 255) bsum[blockIdx.x] = val;
}

__global__ void k_scan2(const int* __restrict__ bsum, int* __restrict__ bsumx, int nb) {
  __shared__ int lds[512];
  int t = threadIdx.x;
  int v = (t < nb) ? bsum[t] : 0;
  int val = v;
  lds[t] = val;
  for (int ofs = 1; ofs < 512; ofs <<= 1) {
    __syncthreads();
    int u = (t >= ofs) ? lds[t - ofs] : 0;
    __syncthreads();
    val += u;
    lds[t] = val;
  }
  if (t < nb) bsumx[t] = val - v;
}

__global__ void k_scan3(int* __restrict__ row_start, int* __restrict__ cursor,
                        const int* __restrict__ bsumx, int n, int total) {
  int idx = blockIdx.x * 256 + threadIdx.x;
  if (idx < n) {
    int v = row_start[idx] + bsumx[blockIdx.x];
    row_start[idx] = v;
    cursor[idx] = v;
  }
  if (idx == 0) row_start[n] = total;
}

// pack each edge as 16B {src, a0, a1, pad} at its CSR slot
__global__ void k_scatter(const int* __restrict__ ei, const float* __restrict__ ea,
                          int* __restrict__ cursor, int4* __restrict__ epack) {
  int e = blockIdx.x * 256 + threadIdx.x;
  if (e >= N_EDGES) return;
  int s = ei[e];
  int d = ei[N_EDGES + e];
  int pos = atomicAdd(&cursor[d], 1);
  int4 pk;
  pk.x = s;
  pk.y = __float_as_int(ea[2 * e]);
  pk.z = __float_as_int(ea[2 * e + 1]);
  pk.w = 0;
  epack[pos] = pk;
}

// ======= FUSED agg+gemm1: one block = one 32-node chunk =======
// Prologue (l>0): finalize BN2(l-1) from statPrev into LDS s/t (3125 blocks x 32KB
// = 100MB L2 ~ 3us — cheap at THIS grid size; round-13 lesson: not at 12500).
// Phase 1: 8 half-waves x 4 sequential nodes; gather/aggregate exactly as k_agg
// (bit-identical z, bf16-rounded) into LDS z-tile (stride 136: 2-way-free banks).
// Phase 2 (after barrier): load B hi/lo from L2 (AFTER the barrier — no live range
// crosses it, round-9 collapse can't trigger), a-frags via 16B LDS reads, MFMA,
// then gemm1's exact epilogue (y1 + statA). z never touches global memory.
__global__ void __launch_bounds__(256) k_aggemm(
    const __bf16* __restrict__ h, const int* __restrict__ row_start,
    const int4* __restrict__ epack,
    const float* __restrict__ ew,       // edge_w + l*2*D, layout [2][D]
    const float* __restrict__ ebp,      // edge_b + l*D
    const float* __restrict__ statPrev, // statB of layer l-1 (or null)
    const float* __restrict__ gammaP, const float* __restrict__ betaP, int hasT,
    const __bf16* __restrict__ Whi, const __bf16* __restrict__ Wlo,
    const float* __restrict__ bias,
    __bf16* __restrict__ Y,
    float* __restrict__ statpart) {
  __shared__ __align__(16) __bf16 zt[32 * ZSTR];   // 8704 B
  __shared__ float sld[DMODEL];
  __shared__ float tld[DMODEL];
  int tid = threadIdx.x;

  if (hasT) {
    if (tid < DMODEL) {
      float sum = 0.0f;
      float sq = 0.0f;
      for (int p = 0; p < NSLOT; ++p) {
        sum += statPrev[p * (2 * DMODEL) + tid];
        sq  += statPrev[p * (2 * DMODEL) + DMODEL + tid];
      }
      float mean = sum * (1.0f / N_NODES);
      float var = sq * (1.0f / N_NODES) - mean * mean;
      float inv = rsqrtf(var + BN_EPS);
      float s = gammaP[tid] * inv;
      sld[tid] = s;
      tld[tid] = betaP[tid] - mean * s;
    }
    __syncthreads();
  }

  // ---- phase 1: gather/aggregate 4 nodes per half-wave ----
  int hw = tid >> 5;
  int ln = tid & 31;
  int d0 = ln * 4;

  float4 ew0 = *(const float4*)(ew + d0);
  float4 ew1 = *(const float4*)(ew + DMODEL + d0);
  float4 eb  = *(const float4*)(ebp + d0);
  float4 s4;
  float4 t4;
  if (hasT) {
    s4 = *(const float4*)(sld + d0);
    t4 = *(const float4*)(tld + d0);
  }

#define AGG_ONE(E, V)                                                          \
  {                                                                            \
    float a0 = __int_as_float((E).y);                                          \
    float a1 = __int_as_float((E).z);                                          \
    float f0 = (float)(V)[0];                                                  \
    float f1 = (float)(V)[1];                                                  \
    float f2 = (float)(V)[2];                                                  \
    float f3 = (float)(V)[3];                                                  \
    if (hasT) {                                                                \
      f0 = fmaxf(s4.x * f0 + t4.x, 0.0f);                                      \
      f1 = fmaxf(s4.y * f1 + t4.y, 0.0f);                                      \
      f2 = fmaxf(s4.z * f2 + t4.z, 0.0f);                                      \
      f3 = fmaxf(s4.w * f3 + t4.w, 0.0f);                                      \
    }                                                                          \
    acc0 += fmaxf(f0 + a0 * ew0.x + a1 * ew1.x + eb.x, 0.0f);                  \
    acc1 += fmaxf(f1 + a0 * ew0.y + a1 * ew1.y + eb.y, 0.0f);                  \
    acc2 += fmaxf(f2 + a0 * ew0.z + a1 * ew1.z + eb.z, 0.0f);                  \
    acc3 += fmaxf(f3 + a0 * ew0.w + a1 * ew1.w + eb.w, 0.0f);                  \
  }

  for (int i = 0; i < 4; ++i) {
    int nl = hw * 4 + i;
    int node = blockIdx.x * 32 + nl;
    bf16x4 hv = *(const bf16x4*)(h + (size_t)node * DMODEL + d0);
    float acc0, acc1, acc2, acc3;
    {
      float r0 = (float)hv[0];
      float r1 = (float)hv[1];
      float r2 = (float)hv[2];
      float r3 = (float)hv[3];
      if (hasT) {
        acc0 = fmaxf(s4.x * r0 + t4.x, 0.0f);
        acc1 = fmaxf(s4.y * r1 + t4.y, 0.0f);
        acc2 = fmaxf(s4.z * r2 + t4.z, 0.0f);
        acc3 = fmaxf(s4.w * r3 + t4.w, 0.0f);
      } else {
        acc0 = r0; acc1 = r1; acc2 = r2; acc3 = r3;
      }
    }
    int j0 = row_start[node];
    int j1 = row_start[node + 1];
    int j = j0;
    for (; j + 4 <= j1; j += 4) {
      int4 e0 = epack[j];
      int4 e1 = epack[j + 1];
      int4 e2 = epack[j + 2];
      int4 e3 = epack[j + 3];
      bf16x4 v0 = *(const bf16x4*)(h + (size_t)e0.x * DMODEL + d0);
      bf16x4 v1 = *(const bf16x4*)(h + (size_t)e1.x * DMODEL + d0);
      bf16x4 v2 = *(const bf16x4*)(h + (size_t)e2.x * DMODEL + d0);
      bf16x4 v3 = *(const bf16x4*)(h + (size_t)e3.x * DMODEL + d0);
      AGG_ONE(e0, v0)
      AGG_ONE(e1, v1)
      AGG_ONE(e2, v2)
      AGG_ONE(e3, v3)
    }
    for (; j < j1; ++j) {
      int4 e0 = epack[j];
      bf16x4 v0 = *(const bf16x4*)(h + (size_t)e0.x * DMODEL + d0);
      AGG_ONE(e0, v0)
    }
    bf16x4 o;
    o[0] = (__bf16)acc0;
    o[1] = (__bf16)acc1;
    o[2] = (__bf16)acc2;
    o[3] = (__bf16)acc3;
    *(bf16x4*)(zt + nl * ZSTR + d0) = o;
  }
#undef AGG_ONE

  __syncthreads();

  // ---- phase 2: 32x128 GEMM on the LDS z-tile ----
  int wave = tid >> 6;
  int lane = tid & 63;
  int n16 = lane & 15;
  int quad = lane >> 4;

  bf16x8 bhi[2][4];
  bf16x8 blo[2][4];
#pragma unroll
  for (int ct = 0; ct < 2; ++ct) {
    int n = (wave * 2 + ct) * 16 + n16;
#pragma unroll
    for (int kk = 0; kk < 4; ++kk) {
      int k0 = kk * 32 + quad * 8;
      bhi[ct][kk] = *(const bf16x8*)(Whi + (size_t)n * DMODEL + k0);
      blo[ct][kk] = *(const bf16x8*)(Wlo + (size_t)n * DMODEL + k0);
    }
  }
  float bc[2];
  bc[0] = bias[(wave * 2 + 0) * 16 + n16];
  bc[1] = bias[(wave * 2 + 1) * 16 + n16];

  bf16x8 a[2][4];
#pragma unroll
  for (int t = 0; t < 2; ++t) {
    const __bf16* zr = zt + (t * 16 + n16) * ZSTR;
#pragma unroll
    for (int kk = 0; kk < 4; ++kk) {
      a[t][kk] = *(const bf16x8*)(zr + kk * 32 + quad * 8);
    }
  }

  f32x4 acc[2][2];
#pragma unroll
  for (int t = 0; t < 2; ++t)
#pragma unroll
    for (int ct = 0; ct < 2; ++ct)
#pragma unroll
      for (int r = 0; r < 4; ++r) acc[t][ct][r] = 0.0f;

#pragma unroll
  for (int kk = 0; kk < 4; ++kk) {
#pragma unroll
    for (int ct = 0; ct < 2; ++ct) {
#pragma unroll
      for (int t = 0; t < 2; ++t) {
        acc[t][ct] = __builtin_amdgcn_mfma_f32_16x16x32_bf16(a[t][kk], bhi[ct][kk], acc[t][ct], 0, 0, 0);
        acc[t][ct] = __builtin_amdgcn_mfma_f32_16x16x32_bf16(a[t][kk], blo[ct][kk], acc[t][ct], 0, 0, 0);
      }
    }
  }

  int row0 = blockIdx.x * 32;
  float ssum[2] = {0.0f, 0.0f};
  float ssq[2] = {0.0f, 0.0f};
#pragma unroll
  for (int t = 0; t < 2; ++t) {
#pragma unroll
    for (int ct = 0; ct < 2; ++ct) {
      int col = (wave * 2 + ct) * 16 + n16;
#pragma unroll
      for (int r = 0; r < 4; ++r) {
        int row = row0 + t * 16 + quad * 4 + r;
        float v = acc[t][ct][r] + bc[ct];
        Y[(size_t)row * DMODEL + col] = (__bf16)v;
        ssum[ct] += v;
        ssq[ct] += v * v;
      }
    }
  }

  int slot = blockIdx.x & (NSLOT - 1);
#pragma unroll
  for (int ct = 0; ct < 2; ++ct) {
    int col = (wave * 2 + ct) * 16 + n16;
    float s = ssum[ct];
    float q = ssq[ct];
    s += __shfl_xor(s, 16);
    q += __shfl_xor(q, 16);
    s += __shfl_xor(s, 32);
    q += __shfl_xor(q, 32);
    if (quad == 0) {
      atomicAdd(&statpart[slot * (2 * DMODEL) + col], s);
      atomicAdd(&statpart[slot * (2 * DMODEL) + DMODEL + col], q);
    }
  }
}

// ------- GEMM2: Y = relu(BN1(X)) @ W + bias, BN1 finalize fused into prologue ------
// (round-12 proven: the single barrier precedes the B live range; 782 blocks)
__global__ void __launch_bounds__(256) k_gemm2(
    const __bf16* __restrict__ X,
    const __bf16* __restrict__ Whi, const __bf16* __restrict__ Wlo,
    const float* __restrict__ bias,
    const float* __restrict__ statA,
    const float* __restrict__ gamma, const float* __restrict__ beta,
    __bf16* __restrict__ Y,
    float* __restrict__ statpart) {
  __shared__ float sld[DMODEL];
  __shared__ float tld[DMODEL];
  int tid = threadIdx.x;

  if (tid < DMODEL) {
    float sum = 0.0f;
    float sq = 0.0f;
    for (int p = 0; p < NSLOT; ++p) {
      sum += statA[p * (2 * DMODEL) + tid];
      sq  += statA[p * (2 * DMODEL) + DMODEL + tid];
    }
    float mean = sum * (1.0f / N_NODES);
    float var = sq * (1.0f / N_NODES) - mean * mean;
    float inv = rsqrtf(var + BN_EPS);
    float s = gamma[tid] * inv;
    sld[tid] = s;
    tld[tid] = beta[tid] - mean * s;
  }
  __syncthreads();

  int wave = tid >> 6;
  int lane = tid & 63;
  int n16 = lane & 15;
  int quad = lane >> 4;

  bf16x8 bhi[2][4];
  bf16x8 blo[2][4];
#pragma unroll
  for (int ct = 0; ct < 2; ++ct) {
    int n = (wave * 2 + ct) * 16 + n16;
#pragma unroll
    for (int kk = 0; kk < 4; ++kk) {
      int k0 = kk * 32 + quad * 8;
      bhi[ct][kk] = *(const bf16x8*)(Whi + (size_t)n * DMODEL + k0);
      blo[ct][kk] = *(const bf16x8*)(Wlo + (size_t)n * DMODEL + k0);
    }
  }
  float bc[2];
  bc[0] = bias[(wave * 2 + 0) * 16 + n16];
  bc[1] = bias[(wave * 2 + 1) * 16 + n16];

  float ssum[2] = {0.0f, 0.0f};
  float ssq[2] = {0.0f, 0.0f};

  const int NCHUNK = N_NODES / 32;   // 3125 exact
  for (int c = blockIdx.x; c < NCHUNK; c += gridDim.x) {
    int row0 = c * 32;
    bf16x8 a[2][4];
#pragma unroll
    for (int t = 0; t < 2; ++t) {
      const __bf16* xr = X + (size_t)(row0 + t * 16 + n16) * DMODEL;
#pragma unroll
      for (int kk = 0; kk < 4; ++kk) {
        a[t][kk] = *(const bf16x8*)(xr + kk * 32 + quad * 8);
      }
    }
#pragma unroll
    for (int kk = 0; kk < 4; ++kk) {
      int k0 = kk * 32 + quad * 8;
      float4 s0 = *(const float4*)(sld + k0);
      float4 s1 = *(const float4*)(sld + k0 + 4);
      float4 t0 = *(const float4*)(tld + k0);
      float4 t1 = *(const float4*)(tld + k0 + 4);
      float sv[8];
      float tv[8];
      sv[0] = s0.x; sv[1] = s0.y; sv[2] = s0.z; sv[3] = s0.w;
      sv[4] = s1.x; sv[5] = s1.y; sv[6] = s1.z; sv[7] = s1.w;
      tv[0] = t0.x; tv[1] = t0.y; tv[2] = t0.z; tv[3] = t0.w;
      tv[4] = t1.x; tv[5] = t1.y; tv[6] = t1.z; tv[7] = t1.w;
#pragma unroll
      for (int t = 0; t < 2; ++t) {
#pragma unroll
        for (int jj = 0; jj < 8; ++jj) {
          float f = (float)a[t][kk][jj];
          a[t][kk][jj] = (__bf16)fmaxf(sv[jj] * f + tv[jj], 0.0f);
        }
      }
    }

    f32x4 acc[2][2];
#pragma unroll
    for (int t = 0; t < 2; ++t)
#pragma unroll
      for (int ct = 0; ct < 2; ++ct)
#pragma unroll
        for (int r = 0; r < 4; ++r) acc[t][ct][r] = 0.0f;

#pragma unroll
    for (int kk = 0; kk < 4; ++kk) {
#pragma unroll
      for (int ct = 0; ct < 2; ++ct) {
#pragma unroll
        for (int t = 0; t < 2; ++t) {
          acc[t][ct] = __builtin_amdgcn_mfma_f32_16x16x32_bf16(a[t][kk], bhi[ct][kk], acc[t][ct], 0, 0, 0);
          acc[t][ct] = __builtin_amdgcn_mfma_f32_16x16x32_bf16(a[t][kk], blo[ct][kk], acc[t][ct], 0, 0, 0);
        }
      }
    }

#pragma unroll
    for (int t = 0; t < 2; ++t) {
#pragma unroll
      for (int ct = 0; ct < 2; ++ct) {
        int col = (wave * 2 + ct) * 16 + n16;
#pragma unroll
        for (int r = 0; r < 4; ++r) {
          int row = row0 + t * 16 + quad * 4 + r;
          float v = acc[t][ct][r] + bc[ct];
          Y[(size_t)row * DMODEL + col] = (__bf16)v;
          ssum[ct] += v;
          ssq[ct] += v * v;
        }
      }
    }
  }

  int slot = blockIdx.x & (NSLOT - 1);
#pragma unroll
  for (int ct = 0; ct < 2; ++ct) {
    int col = (wave * 2 + ct) * 16 + n16;
    float s = ssum[ct];
    float q = ssq[ct];
    s += __shfl_xor(s, 16);
    q += __shfl_xor(q, 16);
    s += __shfl_xor(s, 32);
    q += __shfl_xor(q, 32);
    if (quad == 0) {
      atomicAdd(&statpart[slot * (2 * DMODEL) + col], s);
      atomicAdd(&statpart[slot * (2 * DMODEL) + DMODEL + col], q);
    }
  }
}

// ------- pooling partial sums of raw h (affine deferred to classifier) -------
__global__ void k_pool(const __bf16* __restrict__ h, const int* __restrict__ gstart,
                       float* __restrict__ psum) {
  int g = blockIdx.x;
  int slice = blockIdx.y;   // 0..7
  int lane = threadIdx.x;   // 64
  int d0 = lane * 2;
  int i0 = gstart[g];
  int i1 = gstart[g + 1];
  float a0 = 0.0f;
  float a1 = 0.0f;
  for (int i = i0 + slice; i < i1; i += 8) {
    bf16x2 v = *(const bf16x2*)(h + (size_t)i * DMODEL + d0);
    a0 += (float)v[0];
    a1 += (float)v[1];
  }
  atomicAdd(&psum[g * DMODEL + d0], a0);
  atomicAdd(&psum[g * DMODEL + d0 + 1], a1);
}

// ------- classifier: fused final BN2 finalize, mean + affine, Linear-ReLU-Linear ---
__global__ void k_classifier(const float* __restrict__ psum, const int* __restrict__ gstart,
                             const float* __restrict__ statB,
                             const float* __restrict__ gamma, const float* __restrict__ beta,
                             const float* __restrict__ cw1, const float* __restrict__ cb1,
                             const float* __restrict__ cw2, const float* __restrict__ cb2,
                             float* __restrict__ out) {
  __shared__ float pl[DMODEL];
  __shared__ float hid[DMODEL];
  int g = blockIdx.x;
  int d = threadIdx.x;
  float sum = 0.0f;
  float sq = 0.0f;
  for (int p = 0; p < NSLOT; ++p) {
    sum += statB[p * (2 * DMODEL) + d];
    sq  += statB[p * (2 * DMODEL) + DMODEL + d];
  }
  float mean = sum * (1.0f / N_NODES);
  float var = sq * (1.0f / N_NODES) - mean * mean;
  float inv = rsqrtf(var + BN_EPS);
  float s2 = gamma[d] * inv;
  float t2 = beta[d] - mean * s2;

  int cnt = gstart[g + 1] - gstart[g];
  pl[d] = (cnt > 0) ? (s2 * (psum[g * DMODEL + d] / (float)cnt) + t2) : 0.0f;
  __syncthreads();
  float acc = cb1[d];
  for (int k = 0; k < DMODEL; ++k) acc += pl[k] * cw1[k * DMODEL + d];
  hid[d] = fmaxf(acc, 0.0f);
  __syncthreads();
  if (d < NCLASS) {
    float acc2 = cb2[d];
    for (int k = 0; k < DMODEL; ++k) acc2 += hid[k] * cw2[k * NCLASS + d];
    out[g * NCLASS + d] = acc2;
  }
}

// ---------------- launcher ----------------
extern "C" void kernel_launch(void* const* d_in, const int* in_sizes, int n_in,
                              void* d_out, int out_size, void* d_ws, size_t ws_size,
                              hipStream_t stream) {
  const int*   x      = (const int*)d_in[0];
  const int*   ei     = (const int*)d_in[1];
  const float* ea     = (const float*)d_in[2];
  const int*   batch  = (const int*)d_in[3];
  const float* emb    = (const float*)d_in[4];
  const float* edge_w = (const float*)d_in[5];
  const float* edge_b = (const float*)d_in[6];
  const float* w1     = (const float*)d_in[7];
  const float* b1     = (const float*)d_in[8];
  const float* g1     = (const float*)d_in[9];
  const float* beta1  = (const float*)d_in[10];
  const float* w2     = (const float*)d_in[11];
  const float* b2     = (const float*)d_in[12];
  const float* ng     = (const float*)d_in[13];
  const float* nb     = (const float*)d_in[14];
  const float* cw1    = (const float*)d_in[15];
  const float* cb1    = (const float*)d_in[16];
  const float* cw2    = (const float*)d_in[17];
  const float* cb2    = (const float*)d_in[18];

  char* ws = (char*)d_ws;
  size_t off = 0;
  auto alloc = [&](size_t bytes) -> void* {
    void* p = ws + off;
    off += (bytes + 255) & ~(size_t)255;
    return p;
  };

  __bf16* h_bf      = (__bf16*)alloc((size_t)N_NODES * DMODEL * sizeof(__bf16));
  __bf16* y1_bf     = (__bf16*)alloc((size_t)N_NODES * DMODEL * sizeof(__bf16));
  int*    row_start = (int*)alloc((N_NODES + 1) * sizeof(int));
  int*    cursor    = (int*)alloc(N_NODES * sizeof(int));
  int*    deg       = (int*)alloc(N_NODES * sizeof(int));
  int4*   epack     = (int4*)alloc((size_t)N_EDGES * sizeof(int4));
  __bf16* wt_hi     = (__bf16*)alloc((size_t)NLAYERS * 2 * DMODEL * DMODEL * sizeof(__bf16));
  __bf16* wt_lo     = (__bf16*)alloc((size_t)NLAYERS * 2 * DMODEL * DMODEL * sizeof(__bf16));
  float*  statA     = (float*)alloc((size_t)NLAYERS * STATSZ * sizeof(float));
  float*  statB     = (float*)alloc((size_t)NLAYERS * STATSZ * sizeof(float));
  int*    gstart    = (int*)alloc((NGRAPH + 1) * sizeof(int));
  float*  psum      = (float*)alloc((size_t)NGRAPH * DMODEL * sizeof(float));
  int*    bsum      = (int*)alloc(512 * sizeof(int));
  int*    bsumx     = (int*)alloc(512 * sizeof(int));

  auto statAL = [&](int l) { return statA + (size_t)l * STATSZ; };
  auto statBL = [&](int l) { return statB + (size_t)l * STATSZ; };

  const int nbScan = (N_NODES + 255) / 256;              // 391
  const int nbEdge = (N_EDGES + 255) / 256;              // 2344
  const int nbEmb  = (N_NODES * DMODEL / 8 + 255) / 256; // 6250
  const int nbGemm = 782;                                // gemm2 grid-stride
  const int nbFuse = N_NODES / 32;                       // 3125, one chunk per block

  k_init<<<512, 256, 0, stream>>>(deg, statA, statB, psum,
                                  w1, w2, wt_hi, wt_lo, batch, gstart);
  k_embed<<<nbEmb, 256, 0, stream>>>(x, emb, h_bf);
  k_hist<<<nbEdge, 256, 0, stream>>>(ei + N_EDGES, deg);
  k_scan1<<<nbScan, 256, 0, stream>>>(deg, row_start, bsum, N_NODES);
  k_scan2<<<1, 512, 0, stream>>>(bsum, bsumx, nbScan);
  k_scan3<<<nbScan, 256, 0, stream>>>(row_start, cursor, bsumx, N_NODES, N_EDGES);
  k_scatter<<<nbEdge, 256, 0, stream>>>(ei, ea, cursor, epack);

  for (int l = 0; l < NLAYERS; ++l) {
    const float* sPrev = (l > 0) ? statBL(l - 1) : (const float*)nullptr;
    const float* gPrev = (l > 0) ? (ng + (size_t)(l - 1) * DMODEL) : (const float*)nullptr;
    const float* bPrev = (l > 0) ? (nb + (size_t)(l - 1) * DMODEL) : (const float*)nullptr;
    // fused: z (LDS only) = agg(act(h)); y1 = z @ w1[l] + b1[l]; stats -> statA[l]
    k_aggemm<<<nbFuse, 256, 0, stream>>>(
        h_bf, row_start, epack,
        edge_w + (size_t)l * 2 * DMODEL,
        edge_b + (size_t)l * DMODEL,
        sPrev, gPrev, bPrev, (l > 0) ? 1 : 0,
        wt_hi + (size_t)(l * 2 + 0) * DMODEL * DMODEL,
        wt_lo + (size_t)(l * 2 + 0) * DMODEL * DMODEL,
        b1 + (size_t)l * DMODEL,
        y1_bf, statAL(l));
    // h = relu(BN1(y1)) @ w2[l] + b2[l]; BN1 finalize fused; stats -> statB[l]
    k_gemm2<<<nbGemm, 256, 0, stream>>>(
        y1_bf,
        wt_hi + (size_t)(l * 2 + 1) * DMODEL * DMODEL,
        wt_lo + (size_t)(l * 2 + 1) * DMODEL * DMODEL,
        b2 + (size_t)l * DMODEL,
        statAL(l), g1 + (size_t)l * DMODEL, beta1 + (size_t)l * DMODEL,
        h_bf, statBL(l));
  }

  dim3 poolGrid(NGRAPH, 8);
  k_pool<<<poolGrid, 64, 0, stream>>>(h_bf, gstart, psum);
  k_classifier<<<NGRAPH, DMODEL, 0, stream>>>(psum, gstart, statBL(NLAYERS - 1),
                                              ng + (size_t)(NLAYERS - 1) * DMODEL,
                                              nb + (size_t)(NLAYERS - 1) * DMODEL,
                                              cw1, cb1, cw2, cb2, (float*)d_out);
}

// Round 15
// 660.763 us; speedup vs baseline: 1.0194x; 1.0050x over previous
//
#include <hip/hip_runtime.h>
#include <stdint.h>

#define N_NODES 100000
#define N_EDGES 600000
#define DMODEL  128
#define NLAYERS 4
#define NGRAPH  128
#define NCLASS  10
#define BN_EPS  1e-5f
#define NSLOT   32     // stat partial slots (atomic contention spreading)
#define STATSZ  (NSLOT * 2 * DMODEL)   // floats per layer-stat buffer
#define ZSTR    136    // LDS z-tile row stride in bf16
#define NBIN    64     // degree bins for the schedule counting-sort

typedef __bf16 bf16x8 __attribute__((ext_vector_type(8)));
typedef __bf16 bf16x4 __attribute__((ext_vector_type(4)));
typedef __bf16 bf16x2 __attribute__((ext_vector_type(2)));
typedef float  f32x4  __attribute__((ext_vector_type(4)));

// ------- init: zero per-layer stat buffers, psum, deg, dbin; transpose+split W;
//         graph boundaries by binary search -------
__global__ void k_init(int* __restrict__ deg, float* __restrict__ statA,
                       float* __restrict__ statB, float* __restrict__ psum,
                       int* __restrict__ dbin,
                       const float* __restrict__ w1, const float* __restrict__ w2,
                       __bf16* __restrict__ wt_hi, __bf16* __restrict__ wt_lo,
                       const int* __restrict__ batch, int* __restrict__ gstart) {
  int i = blockIdx.x * 256 + threadIdx.x;   // grid 512*256 = 131072
  if (i < N_NODES) deg[i] = 0;
  if (i < NLAYERS * STATSZ) {
    statA[i] = 0.0f;
    statB[i] = 0.0f;
  }
  if (i < NGRAPH * DMODEL) psum[i] = 0.0f;
  if (i < NBIN) dbin[i] = 0;
  {
    int mat = i >> 14;
    int rem = i & 16383;
    int n = rem >> 7;
    int k = rem & 127;
    int l = mat >> 1;
    int which = mat & 1;
    const float* w = which ? w2 : w1;
    float v = w[(size_t)l * DMODEL * DMODEL + (size_t)k * DMODEL + n];
    __bf16 hi = (__bf16)v;
    wt_hi[i] = hi;
    wt_lo[i] = (__bf16)(v - (float)hi);
  }
  if (i <= NGRAPH) {
    int lo = 0;
    int hi = N_NODES;
    while (lo < hi) {
      int mid = (lo + hi) >> 1;
      if (batch[mid] < i) lo = mid + 1; else hi = mid;
    }
    gstart[i] = lo;
  }
}

// ---------------- embedding gather: h[i,:] = bf16(emb[x[i],:]), 16B stores --------
__global__ void k_embed(const int* __restrict__ x, const float* __restrict__ emb,
                        __bf16* __restrict__ h) {
  int idx = blockIdx.x * 256 + threadIdx.x;        // over N*D/8
  if (idx >= N_NODES * DMODEL / 8) return;
  int i = idx >> 4;
  int p = idx & 15;
  const float* src = emb + (size_t)x[i] * DMODEL + p * 8;
  float4 v0 = *(const float4*)(src);
  float4 v1 = *(const float4*)(src + 4);
  bf16x8 o;
  o[0] = (__bf16)v0.x; o[1] = (__bf16)v0.y; o[2] = (__bf16)v0.z; o[3] = (__bf16)v0.w;
  o[4] = (__bf16)v1.x; o[5] = (__bf16)v1.y; o[6] = (__bf16)v1.z; o[7] = (__bf16)v1.w;
  *(bf16x8*)(h + (size_t)i * DMODEL + p * 8) = o;
}

// ---------------- CSR build ----------------
__global__ void k_hist(const int* __restrict__ dst, int* __restrict__ deg) {
  int e = blockIdx.x * 256 + threadIdx.x;
  if (e < N_EDGES) atomicAdd(&deg[dst[e]], 1);
}

__global__ void k_scan1(const int* __restrict__ deg, int* __restrict__ out,
                        int* __restrict__ bsum, int n) {
  __shared__ int lds[256];
  int t = threadIdx.x;
  int idx = blockIdx.x * 256 + t;
  int v = (idx < n) ? deg[idx] : 0;
  int val = v;
  lds[t] = val;
  for (int ofs = 1; ofs < 256; ofs <<= 1) {
    __syncthreads();
    int u = (t >= ofs) ? lds[t - ofs] : 0;
    __syncthreads();
    val += u;
    lds[t] = val;
  }
  if (idx < n) out[idx] = val - v;
  if (t == 255) bsum[blockIdx.x] = val;
}

__global__ void k_scan2(const int* __restrict__ bsum, int* __restrict__ bsumx, int nb) {
  __shared__ int lds[512];
  int t = threadIdx.x;
  int v = (t < nb) ? bsum[t] : 0;
  int val = v;
  lds[t] = val;
  for (int ofs = 1; ofs < 512; ofs <<= 1) {
    __syncthreads();
    int u = (t >= ofs) ? lds[t - ofs] : 0;
    __syncthreads();
    val += u;
    lds[t] = val;
  }
  if (t < nb) bsumx[t] = val - v;
}

__global__ void k_scan3(int* __restrict__ row_start, int* __restrict__ cursor,
                        const int* __restrict__ bsumx, int n, int total) {
  int idx = blockIdx.x * 256 + threadIdx.x;
  if (idx < n) {
    int v = row_start[idx] + bsumx[blockIdx.x];
    row_start[idx] = v;
    cursor[idx] = v;
  }
  if (idx == 0) row_start[n] = total;
}

// pack each edge as 16B {src, a0, a1, pad} at its CSR slot
__global__ void k_scatter(const int* __restrict__ ei, const float* __restrict__ ea,
                          int* __restrict__ cursor, int4* __restrict__ epack) {
  int e = blockIdx.x * 256 + threadIdx.x;
  if (e >= N_EDGES) return;
  int s = ei[e];
  int d = ei[N_EDGES + e];
  int pos = atomicAdd(&cursor[d], 1);
  int4 pk;
  pk.x = s;
  pk.y = __float_as_int(ea[2 * e]);
  pk.z = __float_as_int(ea[2 * e + 1]);
  pk.w = 0;
  epack[pos] = pk;
}

// ------- degree-grouped schedule: counting sort nodes by clamped degree --------
// (two-level reductions throughout: round-3 showed flat same-address atomics
//  serialize ~10cyc each; mode bins here have ~16k nodes)
__global__ void k_dhist(const int* __restrict__ deg, int* __restrict__ dbin) {
  __shared__ int lbin[NBIN];
  int t = threadIdx.x;
  if (t < NBIN) lbin[t] = 0;
  __syncthreads();
  int i = blockIdx.x * 256 + t;
  if (i < N_NODES) {
    int b = min(deg[i], NBIN - 1);
    atomicAdd(&lbin[b], 1);
  }
  __syncthreads();
  if (t < NBIN && lbin[t] > 0) atomicAdd(&dbin[t], lbin[t]);
}

__global__ void k_dscan(const int* __restrict__ dbin, int* __restrict__ dcursor) {
  __shared__ int lds[NBIN];
  int t = threadIdx.x;   // 64
  int v = dbin[t];
  int val = v;
  lds[t] = val;
  for (int ofs = 1; ofs < NBIN; ofs <<= 1) {
    __syncthreads();
    int u = (t >= ofs) ? lds[t - ofs] : 0;
    __syncthreads();
    val += u;
    lds[t] = val;
  }
  dcursor[t] = val - v;   // exclusive bin start
}

__global__ void k_dscatter(const int* __restrict__ deg, int* __restrict__ dcursor,
                           int* __restrict__ sched) {
  __shared__ int lcnt[NBIN];
  __shared__ int lbase[NBIN];
  int t = threadIdx.x;
  if (t < NBIN) lcnt[t] = 0;
  __syncthreads();
  int i = blockIdx.x * 256 + t;
  int b = 0;
  int lrank = 0;
  if (i < N_NODES) {
    b = min(deg[i], NBIN - 1);
    lrank = atomicAdd(&lcnt[b], 1);
  }
  __syncthreads();
  if (t < NBIN) lbase[t] = (lcnt[t] > 0) ? atomicAdd(&dcursor[t], lcnt[t]) : 0;
  __syncthreads();
  if (i < N_NODES) sched[lbase[b] + lrank] = i;
}

// ======= FUSED agg+gemm1: one block = 32 degree-similar nodes from sched =======
// Prologue (l>0): finalize BN2(l-1) into LDS s/t (3125 blocks x 32KB = 100MB L2).
// Phase 1: 8 half-waves x 4 sequential nodes (node IDs from sched -> uniform degree
// per block, removing the max-degree barrier tail); gather/aggregate bit-identically
// into the LDS z-tile. Phase 2 (after barrier): B hi/lo from L2 (after the barrier —
// round-9 collapse can't trigger), MFMA, epilogue writes y1 at snode[m] rows + statA.
__global__ void __launch_bounds__(256) k_aggemm(
    const __bf16* __restrict__ h, const int* __restrict__ row_start,
    const int4* __restrict__ epack, const int* __restrict__ sched,
    const float* __restrict__ ew,       // edge_w + l*2*D, layout [2][D]
    const float* __restrict__ ebp,      // edge_b + l*D
    const float* __restrict__ statPrev, // statB of layer l-1 (or null)
    const float* __restrict__ gammaP, const float* __restrict__ betaP, int hasT,
    const __bf16* __restrict__ Whi, const __bf16* __restrict__ Wlo,
    const float* __restrict__ bias,
    __bf16* __restrict__ Y,
    float* __restrict__ statpart) {
  __shared__ __align__(16) __bf16 zt[32 * ZSTR];   // 8704 B
  __shared__ float sld[DMODEL];
  __shared__ float tld[DMODEL];
  __shared__ int snode[32];
  int tid = threadIdx.x;

  if (hasT) {
    if (tid < DMODEL) {
      float sum = 0.0f;
      float sq = 0.0f;
      for (int p = 0; p < NSLOT; ++p) {
        sum += statPrev[p * (2 * DMODEL) + tid];
        sq  += statPrev[p * (2 * DMODEL) + DMODEL + tid];
      }
      float mean = sum * (1.0f / N_NODES);
      float var = sq * (1.0f / N_NODES) - mean * mean;
      float inv = rsqrtf(var + BN_EPS);
      float s = gammaP[tid] * inv;
      sld[tid] = s;
      tld[tid] = betaP[tid] - mean * s;
    }
    __syncthreads();
  }

  // ---- phase 1: gather/aggregate 4 nodes per half-wave ----
  int hw = tid >> 5;
  int ln = tid & 31;
  int d0 = ln * 4;

  float4 ew0 = *(const float4*)(ew + d0);
  float4 ew1 = *(const float4*)(ew + DMODEL + d0);
  float4 eb  = *(const float4*)(ebp + d0);
  float4 s4;
  float4 t4;
  if (hasT) {
    s4 = *(const float4*)(sld + d0);
    t4 = *(const float4*)(tld + d0);
  }

#define AGG_ONE(E, V)                                                          \
  {                                                                            \
    float a0 = __int_as_float((E).y);                                          \
    float a1 = __int_as_float((E).z);                                          \
    float f0 = (float)(V)[0];                                                  \
    float f1 = (float)(V)[1];                                                  \
    float f2 = (float)(V)[2];                                                  \
    float f3 = (float)(V)[3];                                                  \
    if (hasT) {                                                                \
      f0 = fmaxf(s4.x * f0 + t4.x, 0.0f);                                      \
      f1 = fmaxf(s4.y * f1 + t4.y, 0.0f);                                      \
      f2 = fmaxf(s4.z * f2 + t4.z, 0.0f);                                      \
      f3 = fmaxf(s4.w * f3 + t4.w, 0.0f);                                      \
    }                                                                          \
    acc0 += fmaxf(f0 + a0 * ew0.x + a1 * ew1.x + eb.x, 0.0f);                  \
    acc1 += fmaxf(f1 + a0 * ew0.y + a1 * ew1.y + eb.y, 0.0f);                  \
    acc2 += fmaxf(f2 + a0 * ew0.z + a1 * ew1.z + eb.z, 0.0f);                  \
    acc3 += fmaxf(f3 + a0 * ew0.w + a1 * ew1.w + eb.w, 0.0f);                  \
  }

  for (int i = 0; i < 4; ++i) {
    int nl = hw * 4 + i;
    int node = sched[blockIdx.x * 32 + nl];
    if (ln == 0) snode[nl] = node;
    bf16x4 hv = *(const bf16x4*)(h + (size_t)node * DMODEL + d0);
    float acc0, acc1, acc2, acc3;
    {
      float r0 = (float)hv[0];
      float r1 = (float)hv[1];
      float r2 = (float)hv[2];
      float r3 = (float)hv[3];
      if (hasT) {
        acc0 = fmaxf(s4.x * r0 + t4.x, 0.0f);
        acc1 = fmaxf(s4.y * r1 + t4.y, 0.0f);
        acc2 = fmaxf(s4.z * r2 + t4.z, 0.0f);
        acc3 = fmaxf(s4.w * r3 + t4.w, 0.0f);
      } else {
        acc0 = r0; acc1 = r1; acc2 = r2; acc3 = r3;
      }
    }
    int j0 = row_start[node];
    int j1 = row_start[node + 1];
    int j = j0;
    for (; j + 4 <= j1; j += 4) {
      int4 e0 = epack[j];
      int4 e1 = epack[j + 1];
      int4 e2 = epack[j + 2];
      int4 e3 = epack[j + 3];
      bf16x4 v0 = *(const bf16x4*)(h + (size_t)e0.x * DMODEL + d0);
      bf16x4 v1 = *(const bf16x4*)(h + (size_t)e1.x * DMODEL + d0);
      bf16x4 v2 = *(const bf16x4*)(h + (size_t)e2.x * DMODEL + d0);
      bf16x4 v3 = *(const bf16x4*)(h + (size_t)e3.x * DMODEL + d0);
      AGG_ONE(e0, v0)
      AGG_ONE(e1, v1)
      AGG_ONE(e2, v2)
      AGG_ONE(e3, v3)
    }
    for (; j < j1; ++j) {
      int4 e0 = epack[j];
      bf16x4 v0 = *(const bf16x4*)(h + (size_t)e0.x * DMODEL + d0);
      AGG_ONE(e0, v0)
    }
    bf16x4 o;
    o[0] = (__bf16)acc0;
    o[1] = (__bf16)acc1;
    o[2] = (__bf16)acc2;
    o[3] = (__bf16)acc3;
    *(bf16x4*)(zt + nl * ZSTR + d0) = o;
  }
#undef AGG_ONE

  __syncthreads();

  // ---- phase 2: 32x128 GEMM on the LDS z-tile ----
  int wave = tid >> 6;
  int lane = tid & 63;
  int n16 = lane & 15;
  int quad = lane >> 4;

  bf16x8 bhi[2][4];
  bf16x8 blo[2][4];
#pragma unroll
  for (int ct = 0; ct < 2; ++ct) {
    int n = (wave * 2 + ct) * 16 + n16;
#pragma unroll
    for (int kk = 0; kk < 4; ++kk) {
      int k0 = kk * 32 + quad * 8;
      bhi[ct][kk] = *(const bf16x8*)(Whi + (size_t)n * DMODEL + k0);
      blo[ct][kk] = *(const bf16x8*)(Wlo + (size_t)n * DMODEL + k0);
    }
  }
  float bc[2];
  bc[0] = bias[(wave * 2 + 0) * 16 + n16];
  bc[1] = bias[(wave * 2 + 1) * 16 + n16];

  bf16x8 a[2][4];
#pragma unroll
  for (int t = 0; t < 2; ++t) {
    const __bf16* zr = zt + (t * 16 + n16) * ZSTR;
#pragma unroll
    for (int kk = 0; kk < 4; ++kk) {
      a[t][kk] = *(const bf16x8*)(zr + kk * 32 + quad * 8);
    }
  }

  f32x4 acc[2][2];
#pragma unroll
  for (int t = 0; t < 2; ++t)
#pragma unroll
    for (int ct = 0; ct < 2; ++ct)
#pragma unroll
      for (int r = 0; r < 4; ++r) acc[t][ct][r] = 0.0f;

#pragma unroll
  for (int kk = 0; kk < 4; ++kk) {
#pragma unroll
    for (int ct = 0; ct < 2; ++ct) {
#pragma unroll
      for (int t = 0; t < 2; ++t) {
        acc[t][ct] = __builtin_amdgcn_mfma_f32_16x16x32_bf16(a[t][kk], bhi[ct][kk], acc[t][ct], 0, 0, 0);
        acc[t][ct] = __builtin_amdgcn_mfma_f32_16x16x32_bf16(a[t][kk], blo[ct][kk], acc[t][ct], 0, 0, 0);
      }
    }
  }

  float ssum[2] = {0.0f, 0.0f};
  float ssq[2] = {0.0f, 0.0f};
#pragma unroll
  for (int t = 0; t < 2; ++t) {
#pragma unroll
    for (int ct = 0; ct < 2; ++ct) {
      int col = (wave * 2 + ct) * 16 + n16;
#pragma unroll
      for (int r = 0; r < 4; ++r) {
        int row = snode[t * 16 + quad * 4 + r];
        float v = acc[t][ct][r] + bc[ct];
        Y[(size_t)row * DMODEL + col] = (__bf16)v;
        ssum[ct] += v;
        ssq[ct] += v * v;
      }
    }
  }

  int slot = blockIdx.x & (NSLOT - 1);
#pragma unroll
  for (int ct = 0; ct < 2; ++ct) {
    int col = (wave * 2 + ct) * 16 + n16;
    float s = ssum[ct];
    float q = ssq[ct];
    s += __shfl_xor(s, 16);
    q += __shfl_xor(q, 16);
    s += __shfl_xor(s, 32);
    q += __shfl_xor(q, 32);
    if (quad == 0) {
      atomicAdd(&statpart[slot * (2 * DMODEL) + col], s);
      atomicAdd(&statpart[slot * (2 * DMODEL) + DMODEL + col], q);
    }
  }
}

// ------- GEMM2: Y = relu(BN1(X)) @ W + bias, BN1 finalize fused into prologue ------
__global__ void __launch_bounds__(256) k_gemm2(
    const __bf16* __restrict__ X,
    const __bf16* __restrict__ Whi, const __bf16* __restrict__ Wlo,
    const float* __restrict__ bias,
    const float* __restrict__ statA,
    const float* __restrict__ gamma, const float* __restrict__ beta,
    __bf16* __restrict__ Y,
    float* __restrict__ statpart) {
  __shared__ float sld[DMODEL];
  __shared__ float tld[DMODEL];
  int tid = threadIdx.x;

  if (tid < DMODEL) {
    float sum = 0.0f;
    float sq = 0.0f;
    for (int p = 0; p < NSLOT; ++p) {
      sum += statA[p * (2 * DMODEL) + tid];
      sq  += statA[p * (2 * DMODEL) + DMODEL + tid];
    }
    float mean = sum * (1.0f / N_NODES);
    float var = sq * (1.0f / N_NODES) - mean * mean;
    float inv = rsqrtf(var + BN_EPS);
    float s = gamma[tid] * inv;
    sld[tid] = s;
    tld[tid] = beta[tid] - mean * s;
  }
  __syncthreads();

  int wave = tid >> 6;
  int lane = tid & 63;
  int n16 = lane & 15;
  int quad = lane >> 4;

  bf16x8 bhi[2][4];
  bf16x8 blo[2][4];
#pragma unroll
  for (int ct = 0; ct < 2; ++ct) {
    int n = (wave * 2 + ct) * 16 + n16;
#pragma unroll
    for (int kk = 0; kk < 4; ++kk) {
      int k0 = kk * 32 + quad * 8;
      bhi[ct][kk] = *(const bf16x8*)(Whi + (size_t)n * DMODEL + k0);
      blo[ct][kk] = *(const bf16x8*)(Wlo + (size_t)n * DMODEL + k0);
    }
  }
  float bc[2];
  bc[0] = bias[(wave * 2 + 0) * 16 + n16];
  bc[1] = bias[(wave * 2 + 1) * 16 + n16];

  float ssum[2] = {0.0f, 0.0f};
  float ssq[2] = {0.0f, 0.0f};

  const int NCHUNK = N_NODES / 32;   // 3125 exact
  for (int c = blockIdx.x; c < NCHUNK; c += gridDim.x) {
    int row0 = c * 32;
    bf16x8 a[2][4];
#pragma unroll
    for (int t = 0; t < 2; ++t) {
      const __bf16* xr = X + (size_t)(row0 + t * 16 + n16) * DMODEL;
#pragma unroll
      for (int kk = 0; kk < 4; ++kk) {
        a[t][kk] = *(const bf16x8*)(xr + kk * 32 + quad * 8);
      }
    }
#pragma unroll
    for (int kk = 0; kk < 4; ++kk) {
      int k0 = kk * 32 + quad * 8;
      float4 s0 = *(const float4*)(sld + k0);
      float4 s1 = *(const float4*)(sld + k0 + 4);
      float4 t0 = *(const float4*)(tld + k0);
      float4 t1 = *(const float4*)(tld + k0 + 4);
      float sv[8];
      float tv[8];
      sv[0] = s0.x; sv[1] = s0.y; sv[2] = s0.z; sv[3] = s0.w;
      sv[4] = s1.x; sv[5] = s1.y; sv[6] = s1.z; sv[7] = s1.w;
      tv[0] = t0.x; tv[1] = t0.y; tv[2] = t0.z; tv[3] = t0.w;
      tv[4] = t1.x; tv[5] = t1.y; tv[6] = t1.z; tv[7] = t1.w;
#pragma unroll
      for (int t = 0; t < 2; ++t) {
#pragma unroll
        for (int jj = 0; jj < 8; ++jj) {
          float f = (float)a[t][kk][jj];
          a[t][kk][jj] = (__bf16)fmaxf(sv[jj] * f + tv[jj], 0.0f);
        }
      }
    }

    f32x4 acc[2][2];
#pragma unroll
    for (int t = 0; t < 2; ++t)
#pragma unroll
      for (int ct = 0; ct < 2; ++ct)
#pragma unroll
        for (int r = 0; r < 4; ++r) acc[t][ct][r] = 0.0f;

#pragma unroll
    for (int kk = 0; kk < 4; ++kk) {
#pragma unroll
      for (int ct = 0; ct < 2; ++ct) {
#pragma unroll
        for (int t = 0; t < 2; ++t) {
          acc[t][ct] = __builtin_amdgcn_mfma_f32_16x16x32_bf16(a[t][kk], bhi[ct][kk], acc[t][ct], 0, 0, 0);
          acc[t][ct] = __builtin_amdgcn_mfma_f32_16x16x32_bf16(a[t][kk], blo[ct][kk], acc[t][ct], 0, 0, 0);
        }
      }
    }

#pragma unroll
    for (int t = 0; t < 2; ++t) {
#pragma unroll
      for (int ct = 0; ct < 2; ++ct) {
        int col = (wave * 2 + ct) * 16 + n16;
#pragma unroll
        for (int r = 0; r < 4; ++r) {
          int row = row0 + t * 16 + quad * 4 + r;
          float v = acc[t][ct][r] + bc[ct];
          Y[(size_t)row * DMODEL + col] = (__bf16)v;
          ssum[ct] += v;
          ssq[ct] += v * v;
        }
      }
    }
  }

  int slot = blockIdx.x & (NSLOT - 1);
#pragma unroll
  for (int ct = 0; ct < 2; ++ct) {
    int col = (wave * 2 + ct) * 16 + n16;
    float s = ssum[ct];
    float q = ssq[ct];
    s += __shfl_xor(s, 16);
    q += __shfl_xor(q, 16);
    s += __shfl_xor(s, 32);
    q += __shfl_xor(q, 32);
    if (quad == 0) {
      atomicAdd(&statpart[slot * (2 * DMODEL) + col], s);
      atomicAdd(&statpart[slot * (2 * DMODEL) + DMODEL + col], q);
    }
  }
}

// ------- pooling partial sums of raw h (affine deferred to classifier) -------
__global__ void k_pool(const __bf16* __restrict__ h, const int* __restrict__ gstart,
                       float* __restrict__ psum) {
  int g = blockIdx.x;
  int slice = blockIdx.y;   // 0..7
  int lane = threadIdx.x;   // 64
  int d0 = lane * 2;
  int i0 = gstart[g];
  int i1 = gstart[g + 1];
  float a0 = 0.0f;
  float a1 = 0.0f;
  for (int i = i0 + slice; i < i1; i += 8) {
    bf16x2 v = *(const bf16x2*)(h + (size_t)i * DMODEL + d0);
    a0 += (float)v[0];
    a1 += (float)v[1];
  }
  atomicAdd(&psum[g * DMODEL + d0], a0);
  atomicAdd(&psum[g * DMODEL + d0 + 1], a1);
}

// ------- classifier: fused final BN2 finalize, mean + affine, Linear-ReLU-Linear ---
__global__ void k_classifier(const float* __restrict__ psum, const int* __restrict__ gstart,
                             const float* __restrict__ statB,
                             const float* __restrict__ gamma, const float* __restrict__ beta,
                             const float* __restrict__ cw1, const float* __restrict__ cb1,
                             const float* __restrict__ cw2, const float* __restrict__ cb2,
                             float* __restrict__ out) {
  __shared__ float pl[DMODEL];
  __shared__ float hid[DMODEL];
  int g = blockIdx.x;
  int d = threadIdx.x;
  float sum = 0.0f;
  float sq = 0.0f;
  for (int p = 0; p < NSLOT; ++p) {
    sum += statB[p * (2 * DMODEL) + d];
    sq  += statB[p * (2 * DMODEL) + DMODEL + d];
  }
  float mean = sum * (1.0f / N_NODES);
  float var = sq * (1.0f / N_NODES) - mean * mean;
  float inv = rsqrtf(var + BN_EPS);
  float s2 = gamma[d] * inv;
  float t2 = beta[d] - mean * s2;

  int cnt = gstart[g + 1] - gstart[g];
  pl[d] = (cnt > 0) ? (s2 * (psum[g * DMODEL + d] / (float)cnt) + t2) : 0.0f;
  __syncthreads();
  float acc = cb1[d];
  for (int k = 0; k < DMODEL; ++k) acc += pl[k] * cw1[k * DMODEL + d];
  hid[d] = fmaxf(acc, 0.0f);
  __syncthreads();
  if (d < NCLASS) {
    float acc2 = cb2[d];
    for (int k = 0; k < DMODEL; ++k) acc2 += hid[k] * cw2[k * NCLASS + d];
    out[g * NCLASS + d] = acc2;
  }
}

// ---------------- launcher ----------------
extern "C" void kernel_launch(void* const* d_in, const int* in_sizes, int n_in,
                              void* d_out, int out_size, void* d_ws, size_t ws_size,
                              hipStream_t stream) {
  const int*   x      = (const int*)d_in[0];
  const int*   ei     = (const int*)d_in[1];
  const float* ea     = (const float*)d_in[2];
  const int*   batch  = (const int*)d_in[3];
  const float* emb    = (const float*)d_in[4];
  const float* edge_w = (const float*)d_in[5];
  const float* edge_b = (const float*)d_in[6];
  const float* w1     = (const float*)d_in[7];
  const float* b1     = (const float*)d_in[8];
  const float* g1     = (const float*)d_in[9];
  const float* beta1  = (const float*)d_in[10];
  const float* w2     = (const float*)d_in[11];
  const float* b2     = (const float*)d_in[12];
  const float* ng     = (const float*)d_in[13];
  const float* nb     = (const float*)d_in[14];
  const float* cw1    = (const float*)d_in[15];
  const float* cb1    = (const float*)d_in[16];
  const float* cw2    = (const float*)d_in[17];
  const float* cb2    = (const float*)d_in[18];

  char* ws = (char*)d_ws;
  size_t off = 0;
  auto alloc = [&](size_t bytes) -> void* {
    void* p = ws + off;
    off += (bytes + 255) & ~(size_t)255;
    return p;
  };

  __bf16* h_bf      = (__bf16*)alloc((size_t)N_NODES * DMODEL * sizeof(__bf16));
  __bf16* y1_bf     = (__bf16*)alloc((size_t)N_NODES * DMODEL * sizeof(__bf16));
  int*    row_start = (int*)alloc((N_NODES + 1) * sizeof(int));
  int*    cursor    = (int*)alloc(N_NODES * sizeof(int));
  int*    deg       = (int*)alloc(N_NODES * sizeof(int));
  int*    sched     = (int*)alloc(N_NODES * sizeof(int));
  int4*   epack     = (int4*)alloc((size_t)N_EDGES * sizeof(int4));
  __bf16* wt_hi     = (__bf16*)alloc((size_t)NLAYERS * 2 * DMODEL * DMODEL * sizeof(__bf16));
  __bf16* wt_lo     = (__bf16*)alloc((size_t)NLAYERS * 2 * DMODEL * DMODEL * sizeof(__bf16));
  float*  statA     = (float*)alloc((size_t)NLAYERS * STATSZ * sizeof(float));
  float*  statB     = (float*)alloc((size_t)NLAYERS * STATSZ * sizeof(float));
  int*    gstart    = (int*)alloc((NGRAPH + 1) * sizeof(int));
  float*  psum      = (float*)alloc((size_t)NGRAPH * DMODEL * sizeof(float));
  int*    dbin      = (int*)alloc(NBIN * sizeof(int));
  int*    dcursor   = (int*)alloc(NBIN * sizeof(int));
  int*    bsum      = (int*)alloc(512 * sizeof(int));
  int*    bsumx     = (int*)alloc(512 * sizeof(int));

  auto statAL = [&](int l) { return statA + (size_t)l * STATSZ; };
  auto statBL = [&](int l) { return statB + (size_t)l * STATSZ; };

  const int nbScan = (N_NODES + 255) / 256;              // 391
  const int nbEdge = (N_EDGES + 255) / 256;              // 2344
  const int nbEmb  = (N_NODES * DMODEL / 8 + 255) / 256; // 6250
  const int nbGemm = 782;                                // gemm2 grid-stride
  const int nbFuse = N_NODES / 32;                       // 3125, one 32-node block

  k_init<<<512, 256, 0, stream>>>(deg, statA, statB, psum, dbin,
                                  w1, w2, wt_hi, wt_lo, batch, gstart);
  k_embed<<<nbEmb, 256, 0, stream>>>(x, emb, h_bf);
  k_hist<<<nbEdge, 256, 0, stream>>>(ei + N_EDGES, deg);
  k_scan1<<<nbScan, 256, 0, stream>>>(deg, row_start, bsum, N_NODES);
  k_scan2<<<1, 512, 0, stream>>>(bsum, bsumx, nbScan);
  k_scan3<<<nbScan, 256, 0, stream>>>(row_start, cursor, bsumx, N_NODES, N_EDGES);
  k_scatter<<<nbEdge, 256, 0, stream>>>(ei, ea, cursor, epack);
  // degree-grouped schedule
  k_dhist<<<nbScan, 256, 0, stream>>>(deg, dbin);
  k_dscan<<<1, NBIN, 0, stream>>>(dbin, dcursor);
  k_dscatter<<<nbScan, 256, 0, stream>>>(deg, dcursor, sched);

  for (int l = 0; l < NLAYERS; ++l) {
    const float* sPrev = (l > 0) ? statBL(l - 1) : (const float*)nullptr;
    const float* gPrev = (l > 0) ? (ng + (size_t)(l - 1) * DMODEL) : (const float*)nullptr;
    const float* bPrev = (l > 0) ? (nb + (size_t)(l - 1) * DMODEL) : (const float*)nullptr;
    // fused: z (LDS only) = agg(act(h)); y1 = z @ w1[l] + b1[l]; stats -> statA[l]
    k_aggemm<<<nbFuse, 256, 0, stream>>>(
        h_bf, row_start, epack, sched,
        edge_w + (size_t)l * 2 * DMODEL,
        edge_b + (size_t)l * DMODEL,
        sPrev, gPrev, bPrev, (l > 0) ? 1 : 0,
        wt_hi + (size_t)(l * 2 + 0) * DMODEL * DMODEL,
        wt_lo + (size_t)(l * 2 + 0) * DMODEL * DMODEL,
        b1 + (size_t)l * DMODEL,
        y1_bf, statAL(l));
    // h = relu(BN1(y1)) @ w2[l] + b2[l]; BN1 finalize fused; stats -> statB[l]
    k_gemm2<<<nbGemm, 256, 0, stream>>>(
        y1_bf,
        wt_hi + (size_t)(l * 2 + 1) * DMODEL * DMODEL,
        wt_lo + (size_t)(l * 2 + 1) * DMODEL * DMODEL,
        b2 + (size_t)l * DMODEL,
        statAL(l), g1 + (size_t)l * DMODEL, beta1 + (size_t)l * DMODEL,
        h_bf, statBL(l));
  }

  dim3 poolGrid(NGRAPH, 8);
  k_pool<<<poolGrid, 64, 0, stream>>>(h_bf, gstart, psum);
  k_classifier<<<NGRAPH, DMODEL, 0, stream>>>(psum, gstart, statBL(NLAYERS - 1),
                                              ng + (size_t)(NLAYERS - 1) * DMODEL,
                                              nb + (size_t)(NLAYERS - 1) * DMODEL,
                                              cw1, cb1, cw2, cb2, (float*)d_out);
}

// Round 16
// 639.646 us; speedup vs baseline: 1.0531x; 1.0330x over previous
//
#include <hip/hip_runtime.h>
#include <stdint.h>

#define N_NODES 100000
#define N_EDGES 600000
#define DMODEL  128
#define NLAYERS 4
#define NGRAPH  128
#define NCLASS  10
#define BN_EPS  1e-5f
#define NSLOT   32     // stat partial slots (atomic contention spreading)
#define STATSZ  (NSLOT * 2 * DMODEL)   // floats per layer-stat buffer
#define ZSTR    136    // LDS z-tile row stride in bf16
#define NBIN    64     // degree bins for the schedule counting-sort

typedef __bf16 bf16x8 __attribute__((ext_vector_type(8)));
typedef __bf16 bf16x4 __attribute__((ext_vector_type(4)));
typedef __bf16 bf16x2 __attribute__((ext_vector_type(2)));
typedef float  f32x4  __attribute__((ext_vector_type(4)));

static __device__ __forceinline__ bf16x2 unpack_bf16x2(int v) {
  union { int i; bf16x2 h; } u;
  u.i = v;
  return u.h;
}
static __device__ __forceinline__ int pack_bf16x2(float a, float b) {
  union { int i; bf16x2 h; } u;
  u.h[0] = (__bf16)a;
  u.h[1] = (__bf16)b;
  return u.i;
}

// ======= pre1: init (zero buffers, split weights, graph bounds) + embed =======
// grid 6250x256 = 1.6M threads; init jobs live in the first 131072 indices.
__global__ void k_pre1(int* __restrict__ deg, float* __restrict__ statA,
                       float* __restrict__ statB, float* __restrict__ psum,
                       int* __restrict__ dbin,
                       const float* __restrict__ w1, const float* __restrict__ w2,
                       __bf16* __restrict__ wt_hi, __bf16* __restrict__ wt_lo,
                       const int* __restrict__ batch, int* __restrict__ gstart,
                       const int* __restrict__ x, const float* __restrict__ emb,
                       __bf16* __restrict__ h) {
  int idx = blockIdx.x * 256 + threadIdx.x;
  // ---- embed job: h[i,:] = bf16(emb[x[i],:]), 16B stores ----
  if (idx < N_NODES * DMODEL / 8) {
    int i = idx >> 4;
    int p = idx & 15;
    const float* src = emb + (size_t)x[i] * DMODEL + p * 8;
    float4 v0 = *(const float4*)(src);
    float4 v1 = *(const float4*)(src + 4);
    bf16x8 o;
    o[0] = (__bf16)v0.x; o[1] = (__bf16)v0.y; o[2] = (__bf16)v0.z; o[3] = (__bf16)v0.w;
    o[4] = (__bf16)v1.x; o[5] = (__bf16)v1.y; o[6] = (__bf16)v1.z; o[7] = (__bf16)v1.w;
    *(bf16x8*)(h + (size_t)i * DMODEL + p * 8) = o;
  }
  // ---- init jobs (first 131072 indices) ----
  if (idx < NLAYERS * 2 * DMODEL * DMODEL) {
    int i = idx;
    if (i < N_NODES) deg[i] = 0;
    if (i < NLAYERS * STATSZ) {
      statA[i] = 0.0f;
      statB[i] = 0.0f;
    }
    if (i < NGRAPH * DMODEL) psum[i] = 0.0f;
    if (i < NBIN) dbin[i] = 0;
    {
      int mat = i >> 14;
      int rem = i & 16383;
      int n = rem >> 7;
      int k = rem & 127;
      int l = mat >> 1;
      int which = mat & 1;
      const float* w = which ? w2 : w1;
      float v = w[(size_t)l * DMODEL * DMODEL + (size_t)k * DMODEL + n];
      __bf16 hi = (__bf16)v;
      wt_hi[i] = hi;
      wt_lo[i] = (__bf16)(v - (float)hi);
    }
    if (i <= NGRAPH) {
      int lo = 0;
      int hi = N_NODES;
      while (lo < hi) {
        int mid = (lo + hi) >> 1;
        if (batch[mid] < i) lo = mid + 1; else hi = mid;
      }
      gstart[i] = lo;
    }
  }
}

// ---------------- histogram of dst degrees (needs zeroed deg) ----------------
__global__ void k_hist(const int* __restrict__ dst, int* __restrict__ deg) {
  int e = blockIdx.x * 256 + threadIdx.x;
  if (e < N_EDGES) atomicAdd(&deg[dst[e]], 1);
}

// ======= pre2: scan1 (block-local exclusive scan of deg) + dhist (degree bins) ====
__global__ void k_pre2(const int* __restrict__ deg, int* __restrict__ out,
                       int* __restrict__ bsum, int* __restrict__ dbin) {
  __shared__ int lds[256];
  __shared__ int lbin[NBIN];
  int t = threadIdx.x;
  int idx = blockIdx.x * 256 + t;
  int v = (idx < N_NODES) ? deg[idx] : 0;
  int val = v;
  lds[t] = val;
  if (t < NBIN) lbin[t] = 0;
  for (int ofs = 1; ofs < 256; ofs <<= 1) {
    __syncthreads();
    int u = (t >= ofs) ? lds[t - ofs] : 0;
    __syncthreads();
    val += u;
    lds[t] = val;
  }
  if (idx < N_NODES) out[idx] = val - v;
  if (t == 255) bsum[blockIdx.x] = val;
  // dhist job (two-level: LDS bins then one global atomic per bin)
  __syncthreads();
  if (idx < N_NODES) atomicAdd(&lbin[min(v, NBIN - 1)], 1);
  __syncthreads();
  if (t < NBIN && lbin[t] > 0) atomicAdd(&dbin[t], lbin[t]);
}

// ======= pre3: scan2 (block sums) + dscan (degree-bin exclusive scan), 1 block ====
__global__ void k_pre3(const int* __restrict__ bsum, int* __restrict__ bsumx, int nb,
                       const int* __restrict__ dbin, int* __restrict__ dcursor) {
  __shared__ int lds[512];
  __shared__ int ldb[NBIN];
  int t = threadIdx.x;
  int v = (t < nb) ? bsum[t] : 0;
  int val = v;
  lds[t] = val;
  for (int ofs = 1; ofs < 512; ofs <<= 1) {
    __syncthreads();
    int u = (t >= ofs) ? lds[t - ofs] : 0;
    __syncthreads();
    val += u;
    lds[t] = val;
  }
  if (t < nb) bsumx[t] = val - v;
  // dscan job
  __syncthreads();
  if (t < NBIN) {
    int dv = dbin[t];
    int dval = dv;
    ldb[t] = dval;
    for (int ofs = 1; ofs < NBIN; ofs <<= 1) {
      __syncthreads();
      int u = (t >= ofs) ? ldb[t - ofs] : 0;
      __syncthreads();
      dval += u;
      ldb[t] = dval;
    }
    dcursor[t] = dval - dv;
  }
}

// ======= pre4: scan3 (finalize row_start/cursor) + dscatter (schedule build) ======
__global__ void k_pre4(int* __restrict__ row_start, int* __restrict__ cursor,
                       const int* __restrict__ bsumx,
                       const int* __restrict__ deg, int* __restrict__ dcursor,
                       int* __restrict__ sched) {
  __shared__ int lcnt[NBIN];
  __shared__ int lbase[NBIN];
  int t = threadIdx.x;
  int idx = blockIdx.x * 256 + t;
  if (idx < N_NODES) {
    int v = row_start[idx] + bsumx[blockIdx.x];
    row_start[idx] = v;
    cursor[idx] = v;
  }
  if (idx == 0) row_start[N_NODES] = N_EDGES;
  // dscatter job (two-level rank assignment)
  if (t < NBIN) lcnt[t] = 0;
  __syncthreads();
  int b = 0;
  int lrank = 0;
  if (idx < N_NODES) {
    b = min(deg[idx], NBIN - 1);
    lrank = atomicAdd(&lcnt[b], 1);
  }
  __syncthreads();
  if (t < NBIN) lbase[t] = (lcnt[t] > 0) ? atomicAdd(&dcursor[t], lcnt[t]) : 0;
  __syncthreads();
  if (idx < N_NODES) sched[lbase[b] + lrank] = idx;
}

// ------- pre5: pack each edge as 8B {src, bf16 a0, bf16 a1} at its CSR slot -------
__global__ void k_scatter(const int* __restrict__ ei, const float* __restrict__ ea,
                          int* __restrict__ cursor, int2* __restrict__ epack) {
  int e = blockIdx.x * 256 + threadIdx.x;
  if (e >= N_EDGES) return;
  int s = ei[e];
  int d = ei[N_EDGES + e];
  int pos = atomicAdd(&cursor[d], 1);
  int2 pk;
  pk.x = s;
  pk.y = pack_bf16x2(ea[2 * e], ea[2 * e + 1]);
  epack[pos] = pk;
}

// ======= FUSED agg+gemm1: one block = 32 degree-similar nodes from sched =======
// Prologue (l>0): finalize BN2(l-1) into LDS s/t. Phase 1: 8 half-waves x 4 nodes,
// gather/aggregate bit-identically into LDS z-tile. Phase 2 (after barrier): B hi/lo
// from L2 (post-barrier: round-9 register collapse can't trigger), MFMA, epilogue
// writes y1 at snode[m] rows + statA partials.
__global__ void __launch_bounds__(256) k_aggemm(
    const __bf16* __restrict__ h, const int* __restrict__ row_start,
    const int2* __restrict__ epack, const int* __restrict__ sched,
    const float* __restrict__ ew,       // edge_w + l*2*D, layout [2][D]
    const float* __restrict__ ebp,      // edge_b + l*D
    const float* __restrict__ statPrev, // statB of layer l-1 (or null)
    const float* __restrict__ gammaP, const float* __restrict__ betaP, int hasT,
    const __bf16* __restrict__ Whi, const __bf16* __restrict__ Wlo,
    const float* __restrict__ bias,
    __bf16* __restrict__ Y,
    float* __restrict__ statpart) {
  __shared__ __align__(16) __bf16 zt[32 * ZSTR];   // 8704 B
  __shared__ float sld[DMODEL];
  __shared__ float tld[DMODEL];
  __shared__ int snode[32];
  int tid = threadIdx.x;

  if (hasT) {
    if (tid < DMODEL) {
      float sum = 0.0f;
      float sq = 0.0f;
      for (int p = 0; p < NSLOT; ++p) {
        sum += statPrev[p * (2 * DMODEL) + tid];
        sq  += statPrev[p * (2 * DMODEL) + DMODEL + tid];
      }
      float mean = sum * (1.0f / N_NODES);
      float var = sq * (1.0f / N_NODES) - mean * mean;
      float inv = rsqrtf(var + BN_EPS);
      float s = gammaP[tid] * inv;
      sld[tid] = s;
      tld[tid] = betaP[tid] - mean * s;
    }
    __syncthreads();
  }

  // ---- phase 1: gather/aggregate 4 nodes per half-wave ----
  int hw = tid >> 5;
  int ln = tid & 31;
  int d0 = ln * 4;

  float4 ew0 = *(const float4*)(ew + d0);
  float4 ew1 = *(const float4*)(ew + DMODEL + d0);
  float4 eb  = *(const float4*)(ebp + d0);
  float4 s4;
  float4 t4;
  if (hasT) {
    s4 = *(const float4*)(sld + d0);
    t4 = *(const float4*)(tld + d0);
  }

#define AGG_ONE(E, V)                                                          \
  {                                                                            \
    bf16x2 av = unpack_bf16x2((E).y);                                          \
    float a0 = (float)av[0];                                                   \
    float a1 = (float)av[1];                                                   \
    float f0 = (float)(V)[0];                                                  \
    float f1 = (float)(V)[1];                                                  \
    float f2 = (float)(V)[2];                                                  \
    float f3 = (float)(V)[3];                                                  \
    if (hasT) {                                                                \
      f0 = fmaxf(s4.x * f0 + t4.x, 0.0f);                                      \
      f1 = fmaxf(s4.y * f1 + t4.y, 0.0f);                                      \
      f2 = fmaxf(s4.z * f2 + t4.z, 0.0f);                                      \
      f3 = fmaxf(s4.w * f3 + t4.w, 0.0f);                                      \
    }                                                                          \
    acc0 += fmaxf(f0 + a0 * ew0.x + a1 * ew1.x + eb.x, 0.0f);                  \
    acc1 += fmaxf(f1 + a0 * ew0.y + a1 * ew1.y + eb.y, 0.0f);                  \
    acc2 += fmaxf(f2 + a0 * ew0.z + a1 * ew1.z + eb.z, 0.0f);                  \
    acc3 += fmaxf(f3 + a0 * ew0.w + a1 * ew1.w + eb.w, 0.0f);                  \
  }

  for (int i = 0; i < 4; ++i) {
    int nl = hw * 4 + i;
    int node = sched[blockIdx.x * 32 + nl];
    if (ln == 0) snode[nl] = node;
    bf16x4 hv = *(const bf16x4*)(h + (size_t)node * DMODEL + d0);
    float acc0, acc1, acc2, acc3;
    {
      float r0 = (float)hv[0];
      float r1 = (float)hv[1];
      float r2 = (float)hv[2];
      float r3 = (float)hv[3];
      if (hasT) {
        acc0 = fmaxf(s4.x * r0 + t4.x, 0.0f);
        acc1 = fmaxf(s4.y * r1 + t4.y, 0.0f);
        acc2 = fmaxf(s4.z * r2 + t4.z, 0.0f);
        acc3 = fmaxf(s4.w * r3 + t4.w, 0.0f);
      } else {
        acc0 = r0; acc1 = r1; acc2 = r2; acc3 = r3;
      }
    }
    int j0 = row_start[node];
    int j1 = row_start[node + 1];
    int j = j0;
    for (; j + 4 <= j1; j += 4) {
      int2 e0 = epack[j];
      int2 e1 = epack[j + 1];
      int2 e2 = epack[j + 2];
      int2 e3 = epack[j + 3];
      bf16x4 v0 = *(const bf16x4*)(h + (size_t)e0.x * DMODEL + d0);
      bf16x4 v1 = *(const bf16x4*)(h + (size_t)e1.x * DMODEL + d0);
      bf16x4 v2 = *(const bf16x4*)(h + (size_t)e2.x * DMODEL + d0);
      bf16x4 v3 = *(const bf16x4*)(h + (size_t)e3.x * DMODEL + d0);
      AGG_ONE(e0, v0)
      AGG_ONE(e1, v1)
      AGG_ONE(e2, v2)
      AGG_ONE(e3, v3)
    }
    for (; j < j1; ++j) {
      int2 e0 = epack[j];
      bf16x4 v0 = *(const bf16x4*)(h + (size_t)e0.x * DMODEL + d0);
      AGG_ONE(e0, v0)
    }
    bf16x4 o;
    o[0] = (__bf16)acc0;
    o[1] = (__bf16)acc1;
    o[2] = (__bf16)acc2;
    o[3] = (__bf16)acc3;
    *(bf16x4*)(zt + nl * ZSTR + d0) = o;
  }
#undef AGG_ONE

  __syncthreads();

  // ---- phase 2: 32x128 GEMM on the LDS z-tile ----
  int wave = tid >> 6;
  int lane = tid & 63;
  int n16 = lane & 15;
  int quad = lane >> 4;

  bf16x8 bhi[2][4];
  bf16x8 blo[2][4];
#pragma unroll
  for (int ct = 0; ct < 2; ++ct) {
    int n = (wave * 2 + ct) * 16 + n16;
#pragma unroll
    for (int kk = 0; kk < 4; ++kk) {
      int k0 = kk * 32 + quad * 8;
      bhi[ct][kk] = *(const bf16x8*)(Whi + (size_t)n * DMODEL + k0);
      blo[ct][kk] = *(const bf16x8*)(Wlo + (size_t)n * DMODEL + k0);
    }
  }
  float bc[2];
  bc[0] = bias[(wave * 2 + 0) * 16 + n16];
  bc[1] = bias[(wave * 2 + 1) * 16 + n16];

  bf16x8 a[2][4];
#pragma unroll
  for (int t = 0; t < 2; ++t) {
    const __bf16* zr = zt + (t * 16 + n16) * ZSTR;
#pragma unroll
    for (int kk = 0; kk < 4; ++kk) {
      a[t][kk] = *(const bf16x8*)(zr + kk * 32 + quad * 8);
    }
  }

  f32x4 acc[2][2];
#pragma unroll
  for (int t = 0; t < 2; ++t)
#pragma unroll
    for (int ct = 0; ct < 2; ++ct)
#pragma unroll
      for (int r = 0; r < 4; ++r) acc[t][ct][r] = 0.0f;

#pragma unroll
  for (int kk = 0; kk < 4; ++kk) {
#pragma unroll
    for (int ct = 0; ct < 2; ++ct) {
#pragma unroll
      for (int t = 0; t < 2; ++t) {
        acc[t][ct] = __builtin_amdgcn_mfma_f32_16x16x32_bf16(a[t][kk], bhi[ct][kk], acc[t][ct], 0, 0, 0);
        acc[t][ct] = __builtin_amdgcn_mfma_f32_16x16x32_bf16(a[t][kk], blo[ct][kk], acc[t][ct], 0, 0, 0);
      }
    }
  }

  float ssum[2] = {0.0f, 0.0f};
  float ssq[2] = {0.0f, 0.0f};
#pragma unroll
  for (int t = 0; t < 2; ++t) {
#pragma unroll
    for (int ct = 0; ct < 2; ++ct) {
      int col = (wave * 2 + ct) * 16 + n16;
#pragma unroll
      for (int r = 0; r < 4; ++r) {
        int row = snode[t * 16 + quad * 4 + r];
        float v = acc[t][ct][r] + bc[ct];
        Y[(size_t)row * DMODEL + col] = (__bf16)v;
        ssum[ct] += v;
        ssq[ct] += v * v;
      }
    }
  }

  int slot = blockIdx.x & (NSLOT - 1);
#pragma unroll
  for (int ct = 0; ct < 2; ++ct) {
    int col = (wave * 2 + ct) * 16 + n16;
    float s = ssum[ct];
    float q = ssq[ct];
    s += __shfl_xor(s, 16);
    q += __shfl_xor(q, 16);
    s += __shfl_xor(s, 32);
    q += __shfl_xor(q, 32);
    if (quad == 0) {
      atomicAdd(&statpart[slot * (2 * DMODEL) + col], s);
      atomicAdd(&statpart[slot * (2 * DMODEL) + DMODEL + col], q);
    }
  }
}

// ------- GEMM2: Y = relu(BN1(X)) @ W + bias, BN1 finalize fused into prologue ------
__global__ void __launch_bounds__(256) k_gemm2(
    const __bf16* __restrict__ X,
    const __bf16* __restrict__ Whi, const __bf16* __restrict__ Wlo,
    const float* __restrict__ bias,
    const float* __restrict__ statA,
    const float* __restrict__ gamma, const float* __restrict__ beta,
    __bf16* __restrict__ Y,
    float* __restrict__ statpart) {
  __shared__ float sld[DMODEL];
  __shared__ float tld[DMODEL];
  int tid = threadIdx.x;

  if (tid < DMODEL) {
    float sum = 0.0f;
    float sq = 0.0f;
    for (int p = 0; p < NSLOT; ++p) {
      sum += statA[p * (2 * DMODEL) + tid];
      sq  += statA[p * (2 * DMODEL) + DMODEL + tid];
    }
    float mean = sum * (1.0f / N_NODES);
    float var = sq * (1.0f / N_NODES) - mean * mean;
    float inv = rsqrtf(var + BN_EPS);
    float s = gamma[tid] * inv;
    sld[tid] = s;
    tld[tid] = beta[tid] - mean * s;
  }
  __syncthreads();

  int wave = tid >> 6;
  int lane = tid & 63;
  int n16 = lane & 15;
  int quad = lane >> 4;

  bf16x8 bhi[2][4];
  bf16x8 blo[2][4];
#pragma unroll
  for (int ct = 0; ct < 2; ++ct) {
    int n = (wave * 2 + ct) * 16 + n16;
#pragma unroll
    for (int kk = 0; kk < 4; ++kk) {
      int k0 = kk * 32 + quad * 8;
      bhi[ct][kk] = *(const bf16x8*)(Whi + (size_t)n * DMODEL + k0);
      blo[ct][kk] = *(const bf16x8*)(Wlo + (size_t)n * DMODEL + k0);
    }
  }
  float bc[2];
  bc[0] = bias[(wave * 2 + 0) * 16 + n16];
  bc[1] = bias[(wave * 2 + 1) * 16 + n16];

  float ssum[2] = {0.0f, 0.0f};
  float ssq[2] = {0.0f, 0.0f};

  const int NCHUNK = N_NODES / 32;   // 3125 exact
  for (int c = blockIdx.x; c < NCHUNK; c += gridDim.x) {
    int row0 = c * 32;
    bf16x8 a[2][4];
#pragma unroll
    for (int t = 0; t < 2; ++t) {
      const __bf16* xr = X + (size_t)(row0 + t * 16 + n16) * DMODEL;
#pragma unroll
      for (int kk = 0; kk < 4; ++kk) {
        a[t][kk] = *(const bf16x8*)(xr + kk * 32 + quad * 8);
      }
    }
#pragma unroll
    for (int kk = 0; kk < 4; ++kk) {
      int k0 = kk * 32 + quad * 8;
      float4 s0 = *(const float4*)(sld + k0);
      float4 s1 = *(const float4*)(sld + k0 + 4);
      float4 t0 = *(const float4*)(tld + k0);
      float4 t1 = *(const float4*)(tld + k0 + 4);
      float sv[8];
      float tv[8];
      sv[0] = s0.x; sv[1] = s0.y; sv[2] = s0.z; sv[3] = s0.w;
      sv[4] = s1.x; sv[5] = s1.y; sv[6] = s1.z; sv[7] = s1.w;
      tv[0] = t0.x; tv[1] = t0.y; tv[2] = t0.z; tv[3] = t0.w;
      tv[4] = t1.x; tv[5] = t1.y; tv[6] = t1.z; tv[7] = t1.w;
#pragma unroll
      for (int t = 0; t < 2; ++t) {
#pragma unroll
        for (int jj = 0; jj < 8; ++jj) {
          float f = (float)a[t][kk][jj];
          a[t][kk][jj] = (__bf16)fmaxf(sv[jj] * f + tv[jj], 0.0f);
        }
      }
    }

    f32x4 acc[2][2];
#pragma unroll
    for (int t = 0; t < 2; ++t)
#pragma unroll
      for (int ct = 0; ct < 2; ++ct)
#pragma unroll
        for (int r = 0; r < 4; ++r) acc[t][ct][r] = 0.0f;

#pragma unroll
    for (int kk = 0; kk < 4; ++kk) {
#pragma unroll
      for (int ct = 0; ct < 2; ++ct) {
#pragma unroll
        for (int t = 0; t < 2; ++t) {
          acc[t][ct] = __builtin_amdgcn_mfma_f32_16x16x32_bf16(a[t][kk], bhi[ct][kk], acc[t][ct], 0, 0, 0);
          acc[t][ct] = __builtin_amdgcn_mfma_f32_16x16x32_bf16(a[t][kk], blo[ct][kk], acc[t][ct], 0, 0, 0);
        }
      }
    }

#pragma unroll
    for (int t = 0; t < 2; ++t) {
#pragma unroll
      for (int ct = 0; ct < 2; ++ct) {
        int col = (wave * 2 + ct) * 16 + n16;
#pragma unroll
        for (int r = 0; r < 4; ++r) {
          int row = row0 + t * 16 + quad * 4 + r;
          float v = acc[t][ct][r] + bc[ct];
          Y[(size_t)row * DMODEL + col] = (__bf16)v;
          ssum[ct] += v;
          ssq[ct] += v * v;
        }
      }
    }
  }

  int slot = blockIdx.x & (NSLOT - 1);
#pragma unroll
  for (int ct = 0; ct < 2; ++ct) {
    int col = (wave * 2 + ct) * 16 + n16;
    float s = ssum[ct];
    float q = ssq[ct];
    s += __shfl_xor(s, 16);
    q += __shfl_xor(q, 16);
    s += __shfl_xor(s, 32);
    q += __shfl_xor(q, 32);
    if (quad == 0) {
      atomicAdd(&statpart[slot * (2 * DMODEL) + col], s);
      atomicAdd(&statpart[slot * (2 * DMODEL) + DMODEL + col], q);
    }
  }
}

// ------- pooling partial sums of raw h (affine deferred to classifier) -------
__global__ void k_pool(const __bf16* __restrict__ h, const int* __restrict__ gstart,
                       float* __restrict__ psum) {
  int g = blockIdx.x;
  int slice = blockIdx.y;   // 0..7
  int lane = threadIdx.x;   // 64
  int d0 = lane * 2;
  int i0 = gstart[g];
  int i1 = gstart[g + 1];
  float a0 = 0.0f;
  float a1 = 0.0f;
  for (int i = i0 + slice; i < i1; i += 8) {
    bf16x2 v = *(const bf16x2*)(h + (size_t)i * DMODEL + d0);
    a0 += (float)v[0];
    a1 += (float)v[1];
  }
  atomicAdd(&psum[g * DMODEL + d0], a0);
  atomicAdd(&psum[g * DMODEL + d0 + 1], a1);
}

// ------- classifier: fused final BN2 finalize, mean + affine, Linear-ReLU-Linear ---
__global__ void k_classifier(const float* __restrict__ psum, const int* __restrict__ gstart,
                             const float* __restrict__ statB,
                             const float* __restrict__ gamma, const float* __restrict__ beta,
                             const float* __restrict__ cw1, const float* __restrict__ cb1,
                             const float* __restrict__ cw2, const float* __restrict__ cb2,
                             float* __restrict__ out) {
  __shared__ float pl[DMODEL];
  __shared__ float hid[DMODEL];
  int g = blockIdx.x;
  int d = threadIdx.x;
  float sum = 0.0f;
  float sq = 0.0f;
  for (int p = 0; p < NSLOT; ++p) {
    sum += statB[p * (2 * DMODEL) + d];
    sq  += statB[p * (2 * DMODEL) + DMODEL + d];
  }
  float mean = sum * (1.0f / N_NODES);
  float var = sq * (1.0f / N_NODES) - mean * mean;
  float inv = rsqrtf(var + BN_EPS);
  float s2 = gamma[d] * inv;
  float t2 = beta[d] - mean * s2;

  int cnt = gstart[g + 1] - gstart[g];
  pl[d] = (cnt > 0) ? (s2 * (psum[g * DMODEL + d] / (float)cnt) + t2) : 0.0f;
  __syncthreads();
  float acc = cb1[d];
  for (int k = 0; k < DMODEL; ++k) acc += pl[k] * cw1[k * DMODEL + d];
  hid[d] = fmaxf(acc, 0.0f);
  __syncthreads();
  if (d < NCLASS) {
    float acc2 = cb2[d];
    for (int k = 0; k < DMODEL; ++k) acc2 += hid[k] * cw2[k * NCLASS + d];
    out[g * NCLASS + d] = acc2;
  }
}

// ---------------- launcher ----------------
extern "C" void kernel_launch(void* const* d_in, const int* in_sizes, int n_in,
                              void* d_out, int out_size, void* d_ws, size_t ws_size,
                              hipStream_t stream) {
  const int*   x      = (const int*)d_in[0];
  const int*   ei     = (const int*)d_in[1];
  const float* ea     = (const float*)d_in[2];
  const int*   batch  = (const int*)d_in[3];
  const float* emb    = (const float*)d_in[4];
  const float* edge_w = (const float*)d_in[5];
  const float* edge_b = (const float*)d_in[6];
  const float* w1     = (const float*)d_in[7];
  const float* b1     = (const float*)d_in[8];
  const float* g1     = (const float*)d_in[9];
  const float* beta1  = (const float*)d_in[10];
  const float* w2     = (const float*)d_in[11];
  const float* b2     = (const float*)d_in[12];
  const float* ng     = (const float*)d_in[13];
  const float* nb     = (const float*)d_in[14];
  const float* cw1    = (const float*)d_in[15];
  const float* cb1    = (const float*)d_in[16];
  const float* cw2    = (const float*)d_in[17];
  const float* cb2    = (const float*)d_in[18];

  char* ws = (char*)d_ws;
  size_t off = 0;
  auto alloc = [&](size_t bytes) -> void* {
    void* p = ws + off;
    off += (bytes + 255) & ~(size_t)255;
    return p;
  };

  __bf16* h_bf      = (__bf16*)alloc((size_t)N_NODES * DMODEL * sizeof(__bf16));
  __bf16* y1_bf     = (__bf16*)alloc((size_t)N_NODES * DMODEL * sizeof(__bf16));
  int*    row_start = (int*)alloc((N_NODES + 1) * sizeof(int));
  int*    cursor    = (int*)alloc(N_NODES * sizeof(int));
  int*    deg       = (int*)alloc(N_NODES * sizeof(int));
  int*    sched     = (int*)alloc(N_NODES * sizeof(int));
  int2*   epack     = (int2*)alloc((size_t)N_EDGES * sizeof(int2));
  __bf16* wt_hi     = (__bf16*)alloc((size_t)NLAYERS * 2 * DMODEL * DMODEL * sizeof(__bf16));
  __bf16* wt_lo     = (__bf16*)alloc((size_t)NLAYERS * 2 * DMODEL * DMODEL * sizeof(__bf16));
  float*  statA     = (float*)alloc((size_t)NLAYERS * STATSZ * sizeof(float));
  float*  statB     = (float*)alloc((size_t)NLAYERS * STATSZ * sizeof(float));
  int*    gstart    = (int*)alloc((NGRAPH + 1) * sizeof(int));
  float*  psum      = (float*)alloc((size_t)NGRAPH * DMODEL * sizeof(float));
  int*    dbin      = (int*)alloc(NBIN * sizeof(int));
  int*    dcursor   = (int*)alloc(NBIN * sizeof(int));
  int*    bsum      = (int*)alloc(512 * sizeof(int));
  int*    bsumx     = (int*)alloc(512 * sizeof(int));

  auto statAL = [&](int l) { return statA + (size_t)l * STATSZ; };
  auto statBL = [&](int l) { return statB + (size_t)l * STATSZ; };

  const int nbScan = (N_NODES + 255) / 256;              // 391
  const int nbEdge = (N_EDGES + 255) / 256;              // 2344
  const int nbPre1 = (N_NODES * DMODEL / 8 + 255) / 256; // 6250
  const int nbGemm = 782;                                // gemm2 grid-stride
  const int nbFuse = N_NODES / 32;                       // 3125, one 32-node block

  k_pre1<<<nbPre1, 256, 0, stream>>>(deg, statA, statB, psum, dbin,
                                     w1, w2, wt_hi, wt_lo, batch, gstart,
                                     x, emb, h_bf);
  k_hist<<<nbEdge, 256, 0, stream>>>(ei + N_EDGES, deg);
  k_pre2<<<nbScan, 256, 0, stream>>>(deg, row_start, bsum, dbin);
  k_pre3<<<1, 512, 0, stream>>>(bsum, bsumx, nbScan, dbin, dcursor);
  k_pre4<<<nbScan, 256, 0, stream>>>(row_start, cursor, bsumx, deg, dcursor, sched);
  k_scatter<<<nbEdge, 256, 0, stream>>>(ei, ea, cursor, epack);

  for (int l = 0; l < NLAYERS; ++l) {
    const float* sPrev = (l > 0) ? statBL(l - 1) : (const float*)nullptr;
    const float* gPrev = (l > 0) ? (ng + (size_t)(l - 1) * DMODEL) : (const float*)nullptr;
    const float* bPrev = (l > 0) ? (nb + (size_t)(l - 1) * DMODEL) : (const float*)nullptr;
    // fused: z (LDS only) = agg(act(h)); y1 = z @ w1[l] + b1[l]; stats -> statA[l]
    k_aggemm<<<nbFuse, 256, 0, stream>>>(
        h_bf, row_start, epack, sched,
        edge_w + (size_t)l * 2 * DMODEL,
        edge_b + (size_t)l * DMODEL,
        sPrev, gPrev, bPrev, (l > 0) ? 1 : 0,
        wt_hi + (size_t)(l * 2 + 0) * DMODEL * DMODEL,
        wt_lo + (size_t)(l * 2 + 0) * DMODEL * DMODEL,
        b1 + (size_t)l * DMODEL,
        y1_bf, statAL(l));
    // h = relu(BN1(y1)) @ w2[l] + b2[l]; BN1 finalize fused; stats -> statB[l]
    k_gemm2<<<nbGemm, 256, 0, stream>>>(
        y1_bf,
        wt_hi + (size_t)(l * 2 + 1) * DMODEL * DMODEL,
        wt_lo + (size_t)(l * 2 + 1) * DMODEL * DMODEL,
        b2 + (size_t)l * DMODEL,
        statAL(l), g1 + (size_t)l * DMODEL, beta1 + (size_t)l * DMODEL,
        h_bf, statBL(l));
  }

  dim3 poolGrid(NGRAPH, 8);
  k_pool<<<poolGrid, 64, 0, stream>>>(h_bf, gstart, psum);
  k_classifier<<<NGRAPH, DMODEL, 0, stream>>>(psum, gstart, statBL(NLAYERS - 1),
                                              ng + (size_t)(NLAYERS - 1) * DMODEL,
                                              nb + (size_t)(NLAYERS - 1) * DMODEL,
                                              cw1, cb1, cw2, cb2, (float*)d_out);
}

// Round 17
// 622.281 us; speedup vs baseline: 1.0825x; 1.0279x over previous
//
#include <hip/hip_runtime.h>
#include <stdint.h>

#define N_NODES 100000
#define N_EDGES 600000
#define DMODEL  128
#define NLAYERS 4
#define NGRAPH  128
#define NCLASS  10
#define BN_EPS  1e-5f
#define NSLOT   32     // stat partial slots (atomic contention spreading)
#define STATSZ  (NSLOT * 2 * DMODEL)   // floats per layer-stat buffer
#define ZSTR    136    // LDS z-tile row stride in bf16
#define NBIN    64     // degree bins for the schedule counting-sort

typedef __bf16 bf16x8 __attribute__((ext_vector_type(8)));
typedef __bf16 bf16x4 __attribute__((ext_vector_type(4)));
typedef __bf16 bf16x2 __attribute__((ext_vector_type(2)));
typedef float  f32x4  __attribute__((ext_vector_type(4)));

static __device__ __forceinline__ bf16x2 unpack_bf16x2(int v) {
  union { int i; bf16x2 h; } u;
  u.i = v;
  return u.h;
}
static __device__ __forceinline__ int pack_bf16x2(float a, float b) {
  union { int i; bf16x2 h; } u;
  u.h[0] = (__bf16)a;
  u.h[1] = (__bf16)b;
  return u.i;
}

// ======= pre1: init (zero buffers, split weights, graph bounds) + embed =======
__global__ void k_pre1(int* __restrict__ deg, float* __restrict__ statA,
                       float* __restrict__ statB, float* __restrict__ psum,
                       int* __restrict__ dbin,
                       const float* __restrict__ w1, const float* __restrict__ w2,
                       __bf16* __restrict__ wt_hi, __bf16* __restrict__ wt_lo,
                       const int* __restrict__ batch, int* __restrict__ gstart,
                       const int* __restrict__ x, const float* __restrict__ emb,
                       __bf16* __restrict__ h) {
  int idx = blockIdx.x * 256 + threadIdx.x;
  // ---- embed job: h[i,:] = bf16(emb[x[i],:]), 16B stores ----
  if (idx < N_NODES * DMODEL / 8) {
    int i = idx >> 4;
    int p = idx & 15;
    const float* src = emb + (size_t)x[i] * DMODEL + p * 8;
    float4 v0 = *(const float4*)(src);
    float4 v1 = *(const float4*)(src + 4);
    bf16x8 o;
    o[0] = (__bf16)v0.x; o[1] = (__bf16)v0.y; o[2] = (__bf16)v0.z; o[3] = (__bf16)v0.w;
    o[4] = (__bf16)v1.x; o[5] = (__bf16)v1.y; o[6] = (__bf16)v1.z; o[7] = (__bf16)v1.w;
    *(bf16x8*)(h + (size_t)i * DMODEL + p * 8) = o;
  }
  // ---- init jobs (first 131072 indices) ----
  if (idx < NLAYERS * 2 * DMODEL * DMODEL) {
    int i = idx;
    if (i < N_NODES) deg[i] = 0;
    if (i < NLAYERS * STATSZ) {
      statA[i] = 0.0f;
      statB[i] = 0.0f;
    }
    if (i < NGRAPH * DMODEL) psum[i] = 0.0f;
    if (i < NBIN) dbin[i] = 0;
    {
      int mat = i >> 14;
      int rem = i & 16383;
      int n = rem >> 7;
      int k = rem & 127;
      int l = mat >> 1;
      int which = mat & 1;
      const float* w = which ? w2 : w1;
      float v = w[(size_t)l * DMODEL * DMODEL + (size_t)k * DMODEL + n];
      __bf16 hi = (__bf16)v;
      wt_hi[i] = hi;
      wt_lo[i] = (__bf16)(v - (float)hi);
    }
    if (i <= NGRAPH) {
      int lo = 0;
      int hi = N_NODES;
      while (lo < hi) {
        int mid = (lo + hi) >> 1;
        if (batch[mid] < i) lo = mid + 1; else hi = mid;
      }
      gstart[i] = lo;
    }
  }
}

// ---------------- histogram of dst degrees (needs zeroed deg) ----------------
__global__ void k_hist(const int* __restrict__ dst, int* __restrict__ deg) {
  int e = blockIdx.x * 256 + threadIdx.x;
  if (e < N_EDGES) atomicAdd(&deg[dst[e]], 1);
}

// ======= pre2: scan1 (block-local exclusive scan of deg) + dhist (degree bins) ====
__global__ void k_pre2(const int* __restrict__ deg, int* __restrict__ out,
                       int* __restrict__ bsum, int* __restrict__ dbin) {
  __shared__ int lds[256];
  __shared__ int lbin[NBIN];
  int t = threadIdx.x;
  int idx = blockIdx.x * 256 + t;
  int v = (idx < N_NODES) ? deg[idx] : 0;
  int val = v;
  lds[t] = val;
  if (t < NBIN) lbin[t] = 0;
  for (int ofs = 1; ofs < 256; ofs <<= 1) {
    __syncthreads();
    int u = (t >= ofs) ? lds[t - ofs] : 0;
    __syncthreads();
    val += u;
    lds[t] = val;
  }
  if (idx < N_NODES) out[idx] = val - v;
  if (t == 255) bsum[blockIdx.x] = val;
  // dhist job (two-level: LDS bins then one global atomic per bin)
  __syncthreads();
  if (idx < N_NODES) atomicAdd(&lbin[min(v, NBIN - 1)], 1);
  __syncthreads();
  if (t < NBIN && lbin[t] > 0) atomicAdd(&dbin[t], lbin[t]);
}

// ======= pre3: scan2 (block sums) + dscan (degree-bin exclusive scan), 1 block ====
__global__ void k_pre3(const int* __restrict__ bsum, int* __restrict__ bsumx, int nb,
                       const int* __restrict__ dbin, int* __restrict__ dcursor) {
  __shared__ int lds[512];
  __shared__ int ldb[NBIN];
  int t = threadIdx.x;
  int v = (t < nb) ? bsum[t] : 0;
  int val = v;
  lds[t] = val;
  for (int ofs = 1; ofs < 512; ofs <<= 1) {
    __syncthreads();
    int u = (t >= ofs) ? lds[t - ofs] : 0;
    __syncthreads();
    val += u;
    lds[t] = val;
  }
  if (t < nb) bsumx[t] = val - v;
  // dscan job
  __syncthreads();
  if (t < NBIN) {
    int dv = dbin[t];
    int dval = dv;
    ldb[t] = dval;
    for (int ofs = 1; ofs < NBIN; ofs <<= 1) {
      __syncthreads();
      int u = (t >= ofs) ? ldb[t - ofs] : 0;
      __syncthreads();
      dval += u;
      ldb[t] = dval;
    }
    dcursor[t] = dval - dv;
  }
}

// ======= pre4: scan3 (finalize row_start/cursor) + dscatter (schedule build) ======
__global__ void k_pre4(int* __restrict__ row_start, int* __restrict__ cursor,
                       const int* __restrict__ bsumx,
                       const int* __restrict__ deg, int* __restrict__ dcursor,
                       int* __restrict__ sched) {
  __shared__ int lcnt[NBIN];
  __shared__ int lbase[NBIN];
  int t = threadIdx.x;
  int idx = blockIdx.x * 256 + t;
  if (idx < N_NODES) {
    int v = row_start[idx] + bsumx[blockIdx.x];
    row_start[idx] = v;
    cursor[idx] = v;
  }
  if (idx == 0) row_start[N_NODES] = N_EDGES;
  // dscatter job (two-level rank assignment)
  if (t < NBIN) lcnt[t] = 0;
  __syncthreads();
  int b = 0;
  int lrank = 0;
  if (idx < N_NODES) {
    b = min(deg[idx], NBIN - 1);
    lrank = atomicAdd(&lcnt[b], 1);
  }
  __syncthreads();
  if (t < NBIN) lbase[t] = (lcnt[t] > 0) ? atomicAdd(&dcursor[t], lcnt[t]) : 0;
  __syncthreads();
  if (idx < N_NODES) sched[lbase[b] + lrank] = idx;
}

// ------- pre5: pack each edge as 8B {src, bf16 a0, bf16 a1} at its CSR slot -------
__global__ void k_scatter(const int* __restrict__ ei, const float* __restrict__ ea,
                          int* __restrict__ cursor, int2* __restrict__ epack) {
  int e = blockIdx.x * 256 + threadIdx.x;
  if (e >= N_EDGES) return;
  int s = ei[e];
  int d = ei[N_EDGES + e];
  int pos = atomicAdd(&cursor[d], 1);
  int2 pk;
  pk.x = s;
  pk.y = pack_bf16x2(ea[2 * e], ea[2 * e + 1]);
  epack[pos] = pk;
}

// ======= FUSED agg+gemm1: one block = 32 degree-similar nodes from sched =======
// LPT dispatch: hardware block b handles logical chunk gridDim.x-1-b, so the
// high-degree chunks (end of sched, bins ascending) launch FIRST and cheap chunks
// backfill the drain tail (round-16 counters: 38% avg occupancy from the tail).
// Prologue (l>0): finalize BN2(l-1) into LDS s/t. Phase 1: 8 half-waves x 4 nodes,
// gather/aggregate bit-identically into LDS z-tile. Phase 2 (after barrier): B hi/lo
// from L2 (post-barrier: round-9 register collapse can't trigger), MFMA, epilogue
// writes y1 at snode[m] rows + statA partials.
__global__ void __launch_bounds__(256) k_aggemm(
    const __bf16* __restrict__ h, const int* __restrict__ row_start,
    const int2* __restrict__ epack, const int* __restrict__ sched,
    const float* __restrict__ ew,       // edge_w + l*2*D, layout [2][D]
    const float* __restrict__ ebp,      // edge_b + l*D
    const float* __restrict__ statPrev, // statB of layer l-1 (or null)
    const float* __restrict__ gammaP, const float* __restrict__ betaP, int hasT,
    const __bf16* __restrict__ Whi, const __bf16* __restrict__ Wlo,
    const float* __restrict__ bias,
    __bf16* __restrict__ Y,
    float* __restrict__ statpart) {
  __shared__ __align__(16) __bf16 zt[32 * ZSTR];   // 8704 B
  __shared__ float sld[DMODEL];
  __shared__ float tld[DMODEL];
  __shared__ int snode[32];
  int tid = threadIdx.x;
  int cb = (int)gridDim.x - 1 - (int)blockIdx.x;   // LPT: heavy chunks first

  if (hasT) {
    if (tid < DMODEL) {
      float sum = 0.0f;
      float sq = 0.0f;
      for (int p = 0; p < NSLOT; ++p) {
        sum += statPrev[p * (2 * DMODEL) + tid];
        sq  += statPrev[p * (2 * DMODEL) + DMODEL + tid];
      }
      float mean = sum * (1.0f / N_NODES);
      float var = sq * (1.0f / N_NODES) - mean * mean;
      float inv = rsqrtf(var + BN_EPS);
      float s = gammaP[tid] * inv;
      sld[tid] = s;
      tld[tid] = betaP[tid] - mean * s;
    }
    __syncthreads();
  }

  // ---- phase 1: gather/aggregate 4 nodes per half-wave ----
  int hw = tid >> 5;
  int ln = tid & 31;
  int d0 = ln * 4;

  float4 ew0 = *(const float4*)(ew + d0);
  float4 ew1 = *(const float4*)(ew + DMODEL + d0);
  float4 eb  = *(const float4*)(ebp + d0);
  float4 s4;
  float4 t4;
  if (hasT) {
    s4 = *(const float4*)(sld + d0);
    t4 = *(const float4*)(tld + d0);
  }

#define AGG_ONE(E, V)                                                          \
  {                                                                            \
    bf16x2 av = unpack_bf16x2((E).y);                                          \
    float a0 = (float)av[0];                                                   \
    float a1 = (float)av[1];                                                   \
    float f0 = (float)(V)[0];                                                  \
    float f1 = (float)(V)[1];                                                  \
    float f2 = (float)(V)[2];                                                  \
    float f3 = (float)(V)[3];                                                  \
    if (hasT) {                                                                \
      f0 = fmaxf(s4.x * f0 + t4.x, 0.0f);                                      \
      f1 = fmaxf(s4.y * f1 + t4.y, 0.0f);                                      \
      f2 = fmaxf(s4.z * f2 + t4.z, 0.0f);                                      \
      f3 = fmaxf(s4.w * f3 + t4.w, 0.0f);                                      \
    }                                                                          \
    acc0 += fmaxf(f0 + a0 * ew0.x + a1 * ew1.x + eb.x, 0.0f);                  \
    acc1 += fmaxf(f1 + a0 * ew0.y + a1 * ew1.y + eb.y, 0.0f);                  \
    acc2 += fmaxf(f2 + a0 * ew0.z + a1 * ew1.z + eb.z, 0.0f);                  \
    acc3 += fmaxf(f3 + a0 * ew0.w + a1 * ew1.w + eb.w, 0.0f);                  \
  }

  for (int i = 0; i < 4; ++i) {
    int nl = hw * 4 + i;
    int node = sched[cb * 32 + nl];
    if (ln == 0) snode[nl] = node;
    bf16x4 hv = *(const bf16x4*)(h + (size_t)node * DMODEL + d0);
    float acc0, acc1, acc2, acc3;
    {
      float r0 = (float)hv[0];
      float r1 = (float)hv[1];
      float r2 = (float)hv[2];
      float r3 = (float)hv[3];
      if (hasT) {
        acc0 = fmaxf(s4.x * r0 + t4.x, 0.0f);
        acc1 = fmaxf(s4.y * r1 + t4.y, 0.0f);
        acc2 = fmaxf(s4.z * r2 + t4.z, 0.0f);
        acc3 = fmaxf(s4.w * r3 + t4.w, 0.0f);
      } else {
        acc0 = r0; acc1 = r1; acc2 = r2; acc3 = r3;
      }
    }
    int j0 = row_start[node];
    int j1 = row_start[node + 1];
    int j = j0;
    for (; j + 4 <= j1; j += 4) {
      int2 e0 = epack[j];
      int2 e1 = epack[j + 1];
      int2 e2 = epack[j + 2];
      int2 e3 = epack[j + 3];
      bf16x4 v0 = *(const bf16x4*)(h + (size_t)e0.x * DMODEL + d0);
      bf16x4 v1 = *(const bf16x4*)(h + (size_t)e1.x * DMODEL + d0);
      bf16x4 v2 = *(const bf16x4*)(h + (size_t)e2.x * DMODEL + d0);
      bf16x4 v3 = *(const bf16x4*)(h + (size_t)e3.x * DMODEL + d0);
      AGG_ONE(e0, v0)
      AGG_ONE(e1, v1)
      AGG_ONE(e2, v2)
      AGG_ONE(e3, v3)
    }
    for (; j < j1; ++j) {
      int2 e0 = epack[j];
      bf16x4 v0 = *(const bf16x4*)(h + (size_t)e0.x * DMODEL + d0);
      AGG_ONE(e0, v0)
    }
    bf16x4 o;
    o[0] = (__bf16)acc0;
    o[1] = (__bf16)acc1;
    o[2] = (__bf16)acc2;
    o[3] = (__bf16)acc3;
    *(bf16x4*)(zt + nl * ZSTR + d0) = o;
  }
#undef AGG_ONE

  __syncthreads();

  // ---- phase 2: 32x128 GEMM on the LDS z-tile ----
  int wave = tid >> 6;
  int lane = tid & 63;
  int n16 = lane & 15;
  int quad = lane >> 4;

  bf16x8 bhi[2][4];
  bf16x8 blo[2][4];
#pragma unroll
  for (int ct = 0; ct < 2; ++ct) {
    int n = (wave * 2 + ct) * 16 + n16;
#pragma unroll
    for (int kk = 0; kk < 4; ++kk) {
      int k0 = kk * 32 + quad * 8;
      bhi[ct][kk] = *(const bf16x8*)(Whi + (size_t)n * DMODEL + k0);
      blo[ct][kk] = *(const bf16x8*)(Wlo + (size_t)n * DMODEL + k0);
    }
  }
  float bc[2];
  bc[0] = bias[(wave * 2 + 0) * 16 + n16];
  bc[1] = bias[(wave * 2 + 1) * 16 + n16];

  bf16x8 a[2][4];
#pragma unroll
  for (int t = 0; t < 2; ++t) {
    const __bf16* zr = zt + (t * 16 + n16) * ZSTR;
#pragma unroll
    for (int kk = 0; kk < 4; ++kk) {
      a[t][kk] = *(const bf16x8*)(zr + kk * 32 + quad * 8);
    }
  }

  f32x4 acc[2][2];
#pragma unroll
  for (int t = 0; t < 2; ++t)
#pragma unroll
    for (int ct = 0; ct < 2; ++ct)
#pragma unroll
      for (int r = 0; r < 4; ++r) acc[t][ct][r] = 0.0f;

#pragma unroll
  for (int kk = 0; kk < 4; ++kk) {
#pragma unroll
    for (int ct = 0; ct < 2; ++ct) {
#pragma unroll
      for (int t = 0; t < 2; ++t) {
        acc[t][ct] = __builtin_amdgcn_mfma_f32_16x16x32_bf16(a[t][kk], bhi[ct][kk], acc[t][ct], 0, 0, 0);
        acc[t][ct] = __builtin_amdgcn_mfma_f32_16x16x32_bf16(a[t][kk], blo[ct][kk], acc[t][ct], 0, 0, 0);
      }
    }
  }

  float ssum[2] = {0.0f, 0.0f};
  float ssq[2] = {0.0f, 0.0f};
#pragma unroll
  for (int t = 0; t < 2; ++t) {
#pragma unroll
    for (int ct = 0; ct < 2; ++ct) {
      int col = (wave * 2 + ct) * 16 + n16;
#pragma unroll
      for (int r = 0; r < 4; ++r) {
        int row = snode[t * 16 + quad * 4 + r];
        float v = acc[t][ct][r] + bc[ct];
        Y[(size_t)row * DMODEL + col] = (__bf16)v;
        ssum[ct] += v;
        ssq[ct] += v * v;
      }
    }
  }

  int slot = cb & (NSLOT - 1);
#pragma unroll
  for (int ct = 0; ct < 2; ++ct) {
    int col = (wave * 2 + ct) * 16 + n16;
    float s = ssum[ct];
    float q = ssq[ct];
    s += __shfl_xor(s, 16);
    q += __shfl_xor(q, 16);
    s += __shfl_xor(s, 32);
    q += __shfl_xor(q, 32);
    if (quad == 0) {
      atomicAdd(&statpart[slot * (2 * DMODEL) + col], s);
      atomicAdd(&statpart[slot * (2 * DMODEL) + DMODEL + col], q);
    }
  }
}

// ------- GEMM2: Y = relu(BN1(X)) @ W + bias, BN1 finalize fused into prologue ------
__global__ void __launch_bounds__(256) k_gemm2(
    const __bf16* __restrict__ X,
    const __bf16* __restrict__ Whi, const __bf16* __restrict__ Wlo,
    const float* __restrict__ bias,
    const float* __restrict__ statA,
    const float* __restrict__ gamma, const float* __restrict__ beta,
    __bf16* __restrict__ Y,
    float* __restrict__ statpart) {
  __shared__ float sld[DMODEL];
  __shared__ float tld[DMODEL];
  int tid = threadIdx.x;

  if (tid < DMODEL) {
    float sum = 0.0f;
    float sq = 0.0f;
    for (int p = 0; p < NSLOT; ++p) {
      sum += statA[p * (2 * DMODEL) + tid];
      sq  += statA[p * (2 * DMODEL) + DMODEL + tid];
    }
    float mean = sum * (1.0f / N_NODES);
    float var = sq * (1.0f / N_NODES) - mean * mean;
    float inv = rsqrtf(var + BN_EPS);
    float s = gamma[tid] * inv;
    sld[tid] = s;
    tld[tid] = beta[tid] - mean * s;
  }
  __syncthreads();

  int wave = tid >> 6;
  int lane = tid & 63;
  int n16 = lane & 15;
  int quad = lane >> 4;

  bf16x8 bhi[2][4];
  bf16x8 blo[2][4];
#pragma unroll
  for (int ct = 0; ct < 2; ++ct) {
    int n = (wave * 2 + ct) * 16 + n16;
#pragma unroll
    for (int kk = 0; kk < 4; ++kk) {
      int k0 = kk * 32 + quad * 8;
      bhi[ct][kk] = *(const bf16x8*)(Whi + (size_t)n * DMODEL + k0);
      blo[ct][kk] = *(const bf16x8*)(Wlo + (size_t)n * DMODEL + k0);
    }
  }
  float bc[2];
  bc[0] = bias[(wave * 2 + 0) * 16 + n16];
  bc[1] = bias[(wave * 2 + 1) * 16 + n16];

  float ssum[2] = {0.0f, 0.0f};
  float ssq[2] = {0.0f, 0.0f};

  const int NCHUNK = N_NODES / 32;   // 3125 exact
  for (int c = blockIdx.x; c < NCHUNK; c += gridDim.x) {
    int row0 = c * 32;
    bf16x8 a[2][4];
#pragma unroll
    for (int t = 0; t < 2; ++t) {
      const __bf16* xr = X + (size_t)(row0 + t * 16 + n16) * DMODEL;
#pragma unroll
      for (int kk = 0; kk < 4; ++kk) {
        a[t][kk] = *(const bf16x8*)(xr + kk * 32 + quad * 8);
      }
    }
#pragma unroll
    for (int kk = 0; kk < 4; ++kk) {
      int k0 = kk * 32 + quad * 8;
      float4 s0 = *(const float4*)(sld + k0);
      float4 s1 = *(const float4*)(sld + k0 + 4);
      float4 t0 = *(const float4*)(tld + k0);
      float4 t1 = *(const float4*)(tld + k0 + 4);
      float sv[8];
      float tv[8];
      sv[0] = s0.x; sv[1] = s0.y; sv[2] = s0.z; sv[3] = s0.w;
      sv[4] = s1.x; sv[5] = s1.y; sv[6] = s1.z; sv[7] = s1.w;
      tv[0] = t0.x; tv[1] = t0.y; tv[2] = t0.z; tv[3] = t0.w;
      tv[4] = t1.x; tv[5] = t1.y; tv[6] = t1.z; tv[7] = t1.w;
#pragma unroll
      for (int t = 0; t < 2; ++t) {
#pragma unroll
        for (int jj = 0; jj < 8; ++jj) {
          float f = (float)a[t][kk][jj];
          a[t][kk][jj] = (__bf16)fmaxf(sv[jj] * f + tv[jj], 0.0f);
        }
      }
    }

    f32x4 acc[2][2];
#pragma unroll
    for (int t = 0; t < 2; ++t)
#pragma unroll
      for (int ct = 0; ct < 2; ++ct)
#pragma unroll
        for (int r = 0; r < 4; ++r) acc[t][ct][r] = 0.0f;

#pragma unroll
    for (int kk = 0; kk < 4; ++kk) {
#pragma unroll
      for (int ct = 0; ct < 2; ++ct) {
#pragma unroll
        for (int t = 0; t < 2; ++t) {
          acc[t][ct] = __builtin_amdgcn_mfma_f32_16x16x32_bf16(a[t][kk], bhi[ct][kk], acc[t][ct], 0, 0, 0);
          acc[t][ct] = __builtin_amdgcn_mfma_f32_16x16x32_bf16(a[t][kk], blo[ct][kk], acc[t][ct], 0, 0, 0);
        }
      }
    }

#pragma unroll
    for (int t = 0; t < 2; ++t) {
#pragma unroll
      for (int ct = 0; ct < 2; ++ct) {
        int col = (wave * 2 + ct) * 16 + n16;
#pragma unroll
        for (int r = 0; r < 4; ++r) {
          int row = row0 + t * 16 + quad * 4 + r;
          float v = acc[t][ct][r] + bc[ct];
          Y[(size_t)row * DMODEL + col] = (__bf16)v;
          ssum[ct] += v;
          ssq[ct] += v * v;
        }
      }
    }
  }

  int slot = blockIdx.x & (NSLOT - 1);
#pragma unroll
  for (int ct = 0; ct < 2; ++ct) {
    int col = (wave * 2 + ct) * 16 + n16;
    float s = ssum[ct];
    float q = ssq[ct];
    s += __shfl_xor(s, 16);
    q += __shfl_xor(q, 16);
    s += __shfl_xor(s, 32);
    q += __shfl_xor(q, 32);
    if (quad == 0) {
      atomicAdd(&statpart[slot * (2 * DMODEL) + col], s);
      atomicAdd(&statpart[slot * (2 * DMODEL) + DMODEL + col], q);
    }
  }
}

// ------- pooling partial sums of raw h (affine deferred to classifier) -------
__global__ void k_pool(const __bf16* __restrict__ h, const int* __restrict__ gstart,
                       float* __restrict__ psum) {
  int g = blockIdx.x;
  int slice = blockIdx.y;   // 0..7
  int lane = threadIdx.x;   // 64
  int d0 = lane * 2;
  int i0 = gstart[g];
  int i1 = gstart[g + 1];
  float a0 = 0.0f;
  float a1 = 0.0f;
  for (int i = i0 + slice; i < i1; i += 8) {
    bf16x2 v = *(const bf16x2*)(h + (size_t)i * DMODEL + d0);
    a0 += (float)v[0];
    a1 += (float)v[1];
  }
  atomicAdd(&psum[g * DMODEL + d0], a0);
  atomicAdd(&psum[g * DMODEL + d0 + 1], a1);
}

// ------- classifier: fused final BN2 finalize, mean + affine, Linear-ReLU-Linear ---
__global__ void k_classifier(const float* __restrict__ psum, const int* __restrict__ gstart,
                             const float* __restrict__ statB,
                             const float* __restrict__ gamma, const float* __restrict__ beta,
                             const float* __restrict__ cw1, const float* __restrict__ cb1,
                             const float* __restrict__ cw2, const float* __restrict__ cb2,
                             float* __restrict__ out) {
  __shared__ float pl[DMODEL];
  __shared__ float hid[DMODEL];
  int g = blockIdx.x;
  int d = threadIdx.x;
  float sum = 0.0f;
  float sq = 0.0f;
  for (int p = 0; p < NSLOT; ++p) {
    sum += statB[p * (2 * DMODEL) + d];
    sq  += statB[p * (2 * DMODEL) + DMODEL + d];
  }
  float mean = sum * (1.0f / N_NODES);
  float var = sq * (1.0f / N_NODES) - mean * mean;
  float inv = rsqrtf(var + BN_EPS);
  float s2 = gamma[d] * inv;
  float t2 = beta[d] - mean * s2;

  int cnt = gstart[g + 1] - gstart[g];
  pl[d] = (cnt > 0) ? (s2 * (psum[g * DMODEL + d] / (float)cnt) + t2) : 0.0f;
  __syncthreads();
  float acc = cb1[d];
  for (int k = 0; k < DMODEL; ++k) acc += pl[k] * cw1[k * DMODEL + d];
  hid[d] = fmaxf(acc, 0.0f);
  __syncthreads();
  if (d < NCLASS) {
    float acc2 = cb2[d];
    for (int k = 0; k < DMODEL; ++k) acc2 += hid[k] * cw2[k * NCLASS + d];
    out[g * NCLASS + d] = acc2;
  }
}

// ---------------- launcher ----------------
extern "C" void kernel_launch(void* const* d_in, const int* in_sizes, int n_in,
                              void* d_out, int out_size, void* d_ws, size_t ws_size,
                              hipStream_t stream) {
  const int*   x      = (const int*)d_in[0];
  const int*   ei     = (const int*)d_in[1];
  const float* ea     = (const float*)d_in[2];
  const int*   batch  = (const int*)d_in[3];
  const float* emb    = (const float*)d_in[4];
  const float* edge_w = (const float*)d_in[5];
  const float* edge_b = (const float*)d_in[6];
  const float* w1     = (const float*)d_in[7];
  const float* b1     = (const float*)d_in[8];
  const float* g1     = (const float*)d_in[9];
  const float* beta1  = (const float*)d_in[10];
  const float* w2     = (const float*)d_in[11];
  const float* b2     = (const float*)d_in[12];
  const float* ng     = (const float*)d_in[13];
  const float* nb     = (const float*)d_in[14];
  const float* cw1    = (const float*)d_in[15];
  const float* cb1    = (const float*)d_in[16];
  const float* cw2    = (const float*)d_in[17];
  const float* cb2    = (const float*)d_in[18];

  char* ws = (char*)d_ws;
  size_t off = 0;
  auto alloc = [&](size_t bytes) -> void* {
    void* p = ws + off;
    off += (bytes + 255) & ~(size_t)255;
    return p;
  };

  __bf16* h_bf      = (__bf16*)alloc((size_t)N_NODES * DMODEL * sizeof(__bf16));
  __bf16* y1_bf     = (__bf16*)alloc((size_t)N_NODES * DMODEL * sizeof(__bf16));
  int*    row_start = (int*)alloc((N_NODES + 1) * sizeof(int));
  int*    cursor    = (int*)alloc(N_NODES * sizeof(int));
  int*    deg       = (int*)alloc(N_NODES * sizeof(int));
  int*    sched     = (int*)alloc(N_NODES * sizeof(int));
  int2*   epack     = (int2*)alloc((size_t)N_EDGES * sizeof(int2));
  __bf16* wt_hi     = (__bf16*)alloc((size_t)NLAYERS * 2 * DMODEL * DMODEL * sizeof(__bf16));
  __bf16* wt_lo     = (__bf16*)alloc((size_t)NLAYERS * 2 * DMODEL * DMODEL * sizeof(__bf16));
  float*  statA     = (float*)alloc((size_t)NLAYERS * STATSZ * sizeof(float));
  float*  statB     = (float*)alloc((size_t)NLAYERS * STATSZ * sizeof(float));
  int*    gstart    = (int*)alloc((NGRAPH + 1) * sizeof(int));
  float*  psum      = (float*)alloc((size_t)NGRAPH * DMODEL * sizeof(float));
  int*    dbin      = (int*)alloc(NBIN * sizeof(int));
  int*    dcursor   = (int*)alloc(NBIN * sizeof(int));
  int*    bsum      = (int*)alloc(512 * sizeof(int));
  int*    bsumx     = (int*)alloc(512 * sizeof(int));

  auto statAL = [&](int l) { return statA + (size_t)l * STATSZ; };
  auto statBL = [&](int l) { return statB + (size_t)l * STATSZ; };

  const int nbScan = (N_NODES + 255) / 256;              // 391
  const int nbEdge = (N_EDGES + 255) / 256;              // 2344
  const int nbPre1 = (N_NODES * DMODEL / 8 + 255) / 256; // 6250
  const int nbGemm = 782;                                // gemm2 grid-stride
  const int nbFuse = N_NODES / 32;                       // 3125, one 32-node block

  k_pre1<<<nbPre1, 256, 0, stream>>>(deg, statA, statB, psum, dbin,
                                     w1, w2, wt_hi, wt_lo, batch, gstart,
                                     x, emb, h_bf);
  k_hist<<<nbEdge, 256, 0, stream>>>(ei + N_EDGES, deg);
  k_pre2<<<nbScan, 256, 0, stream>>>(deg, row_start, bsum, dbin);
  k_pre3<<<1, 512, 0, stream>>>(bsum, bsumx, nbScan, dbin, dcursor);
  k_pre4<<<nbScan, 256, 0, stream>>>(row_start, cursor, bsumx, deg, dcursor, sched);
  k_scatter<<<nbEdge, 256, 0, stream>>>(ei, ea, cursor, epack);

  for (int l = 0; l < NLAYERS; ++l) {
    const float* sPrev = (l > 0) ? statBL(l - 1) : (const float*)nullptr;
    const float* gPrev = (l > 0) ? (ng + (size_t)(l - 1) * DMODEL) : (const float*)nullptr;
    const float* bPrev = (l > 0) ? (nb + (size_t)(l - 1) * DMODEL) : (const float*)nullptr;
    // fused: z (LDS only) = agg(act(h)); y1 = z @ w1[l] + b1[l]; stats -> statA[l]
    k_aggemm<<<nbFuse, 256, 0, stream>>>(
        h_bf, row_start, epack, sched,
        edge_w + (size_t)l * 2 * DMODEL,
        edge_b + (size_t)l * DMODEL,
        sPrev, gPrev, bPrev, (l > 0) ? 1 : 0,
        wt_hi + (size_t)(l * 2 + 0) * DMODEL * DMODEL,
        wt_lo + (size_t)(l * 2 + 0) * DMODEL * DMODEL,
        b1 + (size_t)l * DMODEL,
        y1_bf, statAL(l));
    // h = relu(BN1(y1)) @ w2[l] + b2[l]; BN1 finalize fused; stats -> statB[l]
    k_gemm2<<<nbGemm, 256, 0, stream>>>(
        y1_bf,
        wt_hi + (size_t)(l * 2 + 1) * DMODEL * DMODEL,
        wt_lo + (size_t)(l * 2 + 1) * DMODEL * DMODEL,
        b2 + (size_t)l * DMODEL,
        statAL(l), g1 + (size_t)l * DMODEL, beta1 + (size_t)l * DMODEL,
        h_bf, statBL(l));
  }

  dim3 poolGrid(NGRAPH, 8);
  k_pool<<<poolGrid, 64, 0, stream>>>(h_bf, gstart, psum);
  k_classifier<<<NGRAPH, DMODEL, 0, stream>>>(psum, gstart, statBL(NLAYERS - 1),
                                              ng + (size_t)(NLAYERS - 1) * DMODEL,
                                              nb + (size_t)(NLAYERS - 1) * DMODEL,
                                              cw1, cb1, cw2, cb2, (float*)d_out);
}

// Round 18
// 600.473 us; speedup vs baseline: 1.1218x; 1.0363x over previous
//
#include <hip/hip_runtime.h>
#include <stdint.h>

#define N_NODES 100000
#define N_EDGES 600000
#define DMODEL  128
#define NLAYERS 4
#define NGRAPH  128
#define NCLASS  10
#define BN_EPS  1e-5f
#define NSLOT   8      // stat partial slots (8 is enough: ~390 blocks/slot, uncontended)
#define STATSZ  (NSLOT * 2 * DMODEL)   // floats per layer-stat buffer
#define ZSTR    136    // LDS z-tile row stride in bf16
#define NBIN    64     // degree bins for the schedule counting-sort

typedef __bf16 bf16x8 __attribute__((ext_vector_type(8)));
typedef __bf16 bf16x4 __attribute__((ext_vector_type(4)));
typedef __bf16 bf16x2 __attribute__((ext_vector_type(2)));
typedef float  f32x4  __attribute__((ext_vector_type(4)));

static __device__ __forceinline__ bf16x2 unpack_bf16x2(int v) {
  union { int i; bf16x2 h; } u;
  u.i = v;
  return u.h;
}
static __device__ __forceinline__ int pack_bf16x2(float a, float b) {
  union { int i; bf16x2 h; } u;
  u.h[0] = (__bf16)a;
  u.h[1] = (__bf16)b;
  return u.i;
}

// ======= pre1: init (zero buffers, split weights, graph bounds) + embed =======
__global__ void k_pre1(int* __restrict__ deg, float* __restrict__ statA,
                       float* __restrict__ statB, float* __restrict__ psum,
                       int* __restrict__ dbin,
                       const float* __restrict__ w1, const float* __restrict__ w2,
                       __bf16* __restrict__ wt_hi, __bf16* __restrict__ wt_lo,
                       const int* __restrict__ batch, int* __restrict__ gstart,
                       const int* __restrict__ x, const float* __restrict__ emb,
                       __bf16* __restrict__ h) {
  int idx = blockIdx.x * 256 + threadIdx.x;
  // ---- embed job: h[i,:] = bf16(emb[x[i],:]), 16B stores ----
  if (idx < N_NODES * DMODEL / 8) {
    int i = idx >> 4;
    int p = idx & 15;
    const float* src = emb + (size_t)x[i] * DMODEL + p * 8;
    float4 v0 = *(const float4*)(src);
    float4 v1 = *(const float4*)(src + 4);
    bf16x8 o;
    o[0] = (__bf16)v0.x; o[1] = (__bf16)v0.y; o[2] = (__bf16)v0.z; o[3] = (__bf16)v0.w;
    o[4] = (__bf16)v1.x; o[5] = (__bf16)v1.y; o[6] = (__bf16)v1.z; o[7] = (__bf16)v1.w;
    *(bf16x8*)(h + (size_t)i * DMODEL + p * 8) = o;
  }
  // ---- init jobs (first 131072 indices) ----
  if (idx < NLAYERS * 2 * DMODEL * DMODEL) {
    int i = idx;
    if (i < N_NODES) deg[i] = 0;
    if (i < NLAYERS * STATSZ) {
      statA[i] = 0.0f;
      statB[i] = 0.0f;
    }
    if (i < NGRAPH * DMODEL) psum[i] = 0.0f;
    if (i < NBIN) dbin[i] = 0;
    {
      int mat = i >> 14;
      int rem = i & 16383;
      int n = rem >> 7;
      int k = rem & 127;
      int l = mat >> 1;
      int which = mat & 1;
      const float* w = which ? w2 : w1;
      float v = w[(size_t)l * DMODEL * DMODEL + (size_t)k * DMODEL + n];
      __bf16 hi = (__bf16)v;
      wt_hi[i] = hi;
      wt_lo[i] = (__bf16)(v - (float)hi);
    }
    if (i <= NGRAPH) {
      int lo = 0;
      int hi = N_NODES;
      while (lo < hi) {
        int mid = (lo + hi) >> 1;
        if (batch[mid] < i) lo = mid + 1; else hi = mid;
      }
      gstart[i] = lo;
    }
  }
}

// ---------------- histogram of dst degrees (needs zeroed deg) ----------------
__global__ void k_hist(const int* __restrict__ dst, int* __restrict__ deg) {
  int e = blockIdx.x * 256 + threadIdx.x;
  if (e < N_EDGES) atomicAdd(&deg[dst[e]], 1);
}

// ======= pre2: scan1 (block-local exclusive scan of deg) + dhist (degree bins) ====
__global__ void k_pre2(const int* __restrict__ deg, int* __restrict__ out,
                       int* __restrict__ bsum, int* __restrict__ dbin) {
  __shared__ int lds[256];
  __shared__ int lbin[NBIN];
  int t = threadIdx.x;
  int idx = blockIdx.x * 256 + t;
  int v = (idx < N_NODES) ? deg[idx] : 0;
  int val = v;
  lds[t] = val;
  if (t < NBIN) lbin[t] = 0;
  for (int ofs = 1; ofs < 256; ofs <<= 1) {
    __syncthreads();
    int u = (t >= ofs) ? lds[t - ofs] : 0;
    __syncthreads();
    val += u;
    lds[t] = val;
  }
  if (idx < N_NODES) out[idx] = val - v;
  if (t == 255) bsum[blockIdx.x] = val;
  // dhist job (two-level: LDS bins then one global atomic per bin)
  __syncthreads();
  if (idx < N_NODES) atomicAdd(&lbin[min(v, NBIN - 1)], 1);
  __syncthreads();
  if (t < NBIN && lbin[t] > 0) atomicAdd(&dbin[t], lbin[t]);
}

// ======= pre3: scan2 (block sums) + dscan (degree-bin exclusive scan), 1 block ====
__global__ void k_pre3(const int* __restrict__ bsum, int* __restrict__ bsumx, int nb,
                       const int* __restrict__ dbin, int* __restrict__ dcursor) {
  __shared__ int lds[512];
  __shared__ int ldb[NBIN];
  int t = threadIdx.x;
  int v = (t < nb) ? bsum[t] : 0;
  int val = v;
  lds[t] = val;
  for (int ofs = 1; ofs < 512; ofs <<= 1) {
    __syncthreads();
    int u = (t >= ofs) ? lds[t - ofs] : 0;
    __syncthreads();
    val += u;
    lds[t] = val;
  }
  if (t < nb) bsumx[t] = val - v;
  // dscan job
  __syncthreads();
  if (t < NBIN) {
    int dv = dbin[t];
    int dval = dv;
    ldb[t] = dval;
    for (int ofs = 1; ofs < NBIN; ofs <<= 1) {
      __syncthreads();
      int u = (t >= ofs) ? ldb[t - ofs] : 0;
      __syncthreads();
      dval += u;
      ldb[t] = dval;
    }
    dcursor[t] = dval - dv;
  }
}

// ======= pre4: scan3 (finalize row_start/cursor) + dscatter (schedule build) ======
__global__ void k_pre4(int* __restrict__ row_start, int* __restrict__ cursor,
                       const int* __restrict__ bsumx,
                       const int* __restrict__ deg, int* __restrict__ dcursor,
                       int* __restrict__ sched) {
  __shared__ int lcnt[NBIN];
  __shared__ int lbase[NBIN];
  int t = threadIdx.x;
  int idx = blockIdx.x * 256 + t;
  if (idx < N_NODES) {
    int v = row_start[idx] + bsumx[blockIdx.x];
    row_start[idx] = v;
    cursor[idx] = v;
  }
  if (idx == 0) row_start[N_NODES] = N_EDGES;
  // dscatter job (two-level rank assignment)
  if (t < NBIN) lcnt[t] = 0;
  __syncthreads();
  int b = 0;
  int lrank = 0;
  if (idx < N_NODES) {
    b = min(deg[idx], NBIN - 1);
    lrank = atomicAdd(&lcnt[b], 1);
  }
  __syncthreads();
  if (t < NBIN) lbase[t] = (lcnt[t] > 0) ? atomicAdd(&dcursor[t], lcnt[t]) : 0;
  __syncthreads();
  if (idx < N_NODES) sched[lbase[b] + lrank] = idx;
}

// ------- pre5: pack each edge as 8B {src, bf16 a0, bf16 a1} at its CSR slot -------
__global__ void k_scatter(const int* __restrict__ ei, const float* __restrict__ ea,
                          int* __restrict__ cursor, int2* __restrict__ epack) {
  int e = blockIdx.x * 256 + threadIdx.x;
  if (e >= N_EDGES) return;
  int s = ei[e];
  int d = ei[N_EDGES + e];
  int pos = atomicAdd(&cursor[d], 1);
  int2 pk;
  pk.x = s;
  pk.y = pack_bf16x2(ea[2 * e], ea[2 * e + 1]);
  epack[pos] = pk;
}

// ======= FUSED agg+gemm1: one block = 32 degree-similar nodes from sched =======
// LPT dispatch: hardware block b handles logical chunk gridDim.x-1-b (heavy chunks
// first; cheap chunks backfill the drain — round-17: 83->77.5us).
// Phase 1 j-loop is software-pipelined: next 4-edge group's epack loads issue before
// the current group's gathers/compute (hides epack L2 latency; accumulation order
// unchanged -> bit-identical).
__global__ void __launch_bounds__(256) k_aggemm(
    const __bf16* __restrict__ h, const int* __restrict__ row_start,
    const int2* __restrict__ epack, const int* __restrict__ sched,
    const float* __restrict__ ew,       // edge_w + l*2*D, layout [2][D]
    const float* __restrict__ ebp,      // edge_b + l*D
    const float* __restrict__ statPrev, // statB of layer l-1 (or null)
    const float* __restrict__ gammaP, const float* __restrict__ betaP, int hasT,
    const __bf16* __restrict__ Whi, const __bf16* __restrict__ Wlo,
    const float* __restrict__ bias,
    __bf16* __restrict__ Y,
    float* __restrict__ statpart) {
  __shared__ __align__(16) __bf16 zt[32 * ZSTR];   // 8704 B
  __shared__ float sld[DMODEL];
  __shared__ float tld[DMODEL];
  __shared__ int snode[32];
  int tid = threadIdx.x;
  int cb = (int)gridDim.x - 1 - (int)blockIdx.x;   // LPT: heavy chunks first

  if (hasT) {
    if (tid < DMODEL) {
      float sum = 0.0f;
      float sq = 0.0f;
      for (int p = 0; p < NSLOT; ++p) {
        sum += statPrev[p * (2 * DMODEL) + tid];
        sq  += statPrev[p * (2 * DMODEL) + DMODEL + tid];
      }
      float mean = sum * (1.0f / N_NODES);
      float var = sq * (1.0f / N_NODES) - mean * mean;
      float inv = rsqrtf(var + BN_EPS);
      float s = gammaP[tid] * inv;
      sld[tid] = s;
      tld[tid] = betaP[tid] - mean * s;
    }
    __syncthreads();
  }

  // ---- phase 1: gather/aggregate 4 nodes per half-wave ----
  int hw = tid >> 5;
  int ln = tid & 31;
  int d0 = ln * 4;

  float4 ew0 = *(const float4*)(ew + d0);
  float4 ew1 = *(const float4*)(ew + DMODEL + d0);
  float4 eb  = *(const float4*)(ebp + d0);
  float4 s4;
  float4 t4;
  if (hasT) {
    s4 = *(const float4*)(sld + d0);
    t4 = *(const float4*)(tld + d0);
  }

#define AGG_ONE(E, V)                                                          \
  {                                                                            \
    bf16x2 av = unpack_bf16x2((E).y);                                          \
    float a0 = (float)av[0];                                                   \
    float a1 = (float)av[1];                                                   \
    float f0 = (float)(V)[0];                                                  \
    float f1 = (float)(V)[1];                                                  \
    float f2 = (float)(V)[2];                                                  \
    float f3 = (float)(V)[3];                                                  \
    if (hasT) {                                                                \
      f0 = fmaxf(s4.x * f0 + t4.x, 0.0f);                                      \
      f1 = fmaxf(s4.y * f1 + t4.y, 0.0f);                                      \
      f2 = fmaxf(s4.z * f2 + t4.z, 0.0f);                                      \
      f3 = fmaxf(s4.w * f3 + t4.w, 0.0f);                                      \
    }                                                                          \
    acc0 += fmaxf(f0 + a0 * ew0.x + a1 * ew1.x + eb.x, 0.0f);                  \
    acc1 += fmaxf(f1 + a0 * ew0.y + a1 * ew1.y + eb.y, 0.0f);                  \
    acc2 += fmaxf(f2 + a0 * ew0.z + a1 * ew1.z + eb.z, 0.0f);                  \
    acc3 += fmaxf(f3 + a0 * ew0.w + a1 * ew1.w + eb.w, 0.0f);                  \
  }

  for (int i = 0; i < 4; ++i) {
    int nl = hw * 4 + i;
    int node = sched[cb * 32 + nl];
    if (ln == 0) snode[nl] = node;
    bf16x4 hv = *(const bf16x4*)(h + (size_t)node * DMODEL + d0);
    float acc0, acc1, acc2, acc3;
    {
      float r0 = (float)hv[0];
      float r1 = (float)hv[1];
      float r2 = (float)hv[2];
      float r3 = (float)hv[3];
      if (hasT) {
        acc0 = fmaxf(s4.x * r0 + t4.x, 0.0f);
        acc1 = fmaxf(s4.y * r1 + t4.y, 0.0f);
        acc2 = fmaxf(s4.z * r2 + t4.z, 0.0f);
        acc3 = fmaxf(s4.w * r3 + t4.w, 0.0f);
      } else {
        acc0 = r0; acc1 = r1; acc2 = r2; acc3 = r3;
      }
    }
    int j0 = row_start[node];
    int j1 = row_start[node + 1];
    int j = j0;
    // software-pipelined 4-edge groups: next group's epack loads issue before
    // the current group's gathers + compute
    int2 e0, e1, e2, e3;
    bool have = (j + 4 <= j1);
    if (have) {
      e0 = epack[j];
      e1 = epack[j + 1];
      e2 = epack[j + 2];
      e3 = epack[j + 3];
    }
    while (have) {
      int jn = j + 4;
      bool haveN = (jn + 4 <= j1);
      int2 n0, n1, n2, n3;
      if (haveN) {
        n0 = epack[jn];
        n1 = epack[jn + 1];
        n2 = epack[jn + 2];
        n3 = epack[jn + 3];
      }
      bf16x4 v0 = *(const bf16x4*)(h + (size_t)e0.x * DMODEL + d0);
      bf16x4 v1 = *(const bf16x4*)(h + (size_t)e1.x * DMODEL + d0);
      bf16x4 v2 = *(const bf16x4*)(h + (size_t)e2.x * DMODEL + d0);
      bf16x4 v3 = *(const bf16x4*)(h + (size_t)e3.x * DMODEL + d0);
      AGG_ONE(e0, v0)
      AGG_ONE(e1, v1)
      AGG_ONE(e2, v2)
      AGG_ONE(e3, v3)
      e0 = n0; e1 = n1; e2 = n2; e3 = n3;
      j = jn;
      have = haveN;
    }
    for (; j < j1; ++j) {
      int2 ex = epack[j];
      bf16x4 vx = *(const bf16x4*)(h + (size_t)ex.x * DMODEL + d0);
      AGG_ONE(ex, vx)
    }
    bf16x4 o;
    o[0] = (__bf16)acc0;
    o[1] = (__bf16)acc1;
    o[2] = (__bf16)acc2;
    o[3] = (__bf16)acc3;
    *(bf16x4*)(zt + nl * ZSTR + d0) = o;
  }
#undef AGG_ONE

  __syncthreads();

  // ---- phase 2: 32x128 GEMM on the LDS z-tile ----
  int wave = tid >> 6;
  int lane = tid & 63;
  int n16 = lane & 15;
  int quad = lane >> 4;

  bf16x8 bhi[2][4];
  bf16x8 blo[2][4];
#pragma unroll
  for (int ct = 0; ct < 2; ++ct) {
    int n = (wave * 2 + ct) * 16 + n16;
#pragma unroll
    for (int kk = 0; kk < 4; ++kk) {
      int k0 = kk * 32 + quad * 8;
      bhi[ct][kk] = *(const bf16x8*)(Whi + (size_t)n * DMODEL + k0);
      blo[ct][kk] = *(const bf16x8*)(Wlo + (size_t)n * DMODEL + k0);
    }
  }
  float bc[2];
  bc[0] = bias[(wave * 2 + 0) * 16 + n16];
  bc[1] = bias[(wave * 2 + 1) * 16 + n16];

  bf16x8 a[2][4];
#pragma unroll
  for (int t = 0; t < 2; ++t) {
    const __bf16* zr = zt + (t * 16 + n16) * ZSTR;
#pragma unroll
    for (int kk = 0; kk < 4; ++kk) {
      a[t][kk] = *(const bf16x8*)(zr + kk * 32 + quad * 8);
    }
  }

  f32x4 acc[2][2];
#pragma unroll
  for (int t = 0; t < 2; ++t)
#pragma unroll
    for (int ct = 0; ct < 2; ++ct)
#pragma unroll
      for (int r = 0; r < 4; ++r) acc[t][ct][r] = 0.0f;

#pragma unroll
  for (int kk = 0; kk < 4; ++kk) {
#pragma unroll
    for (int ct = 0; ct < 2; ++ct) {
#pragma unroll
      for (int t = 0; t < 2; ++t) {
        acc[t][ct] = __builtin_amdgcn_mfma_f32_16x16x32_bf16(a[t][kk], bhi[ct][kk], acc[t][ct], 0, 0, 0);
        acc[t][ct] = __builtin_amdgcn_mfma_f32_16x16x32_bf16(a[t][kk], blo[ct][kk], acc[t][ct], 0, 0, 0);
      }
    }
  }

  float ssum[2] = {0.0f, 0.0f};
  float ssq[2] = {0.0f, 0.0f};
#pragma unroll
  for (int t = 0; t < 2; ++t) {
#pragma unroll
    for (int ct = 0; ct < 2; ++ct) {
      int col = (wave * 2 + ct) * 16 + n16;
#pragma unroll
      for (int r = 0; r < 4; ++r) {
        int row = snode[t * 16 + quad * 4 + r];
        float v = acc[t][ct][r] + bc[ct];
        Y[(size_t)row * DMODEL + col] = (__bf16)v;
        ssum[ct] += v;
        ssq[ct] += v * v;
      }
    }
  }

  int slot = cb & (NSLOT - 1);
#pragma unroll
  for (int ct = 0; ct < 2; ++ct) {
    int col = (wave * 2 + ct) * 16 + n16;
    float s = ssum[ct];
    float q = ssq[ct];
    s += __shfl_xor(s, 16);
    q += __shfl_xor(q, 16);
    s += __shfl_xor(s, 32);
    q += __shfl_xor(q, 32);
    if (quad == 0) {
      atomicAdd(&statpart[slot * (2 * DMODEL) + col], s);
      atomicAdd(&statpart[slot * (2 * DMODEL) + DMODEL + col], q);
    }
  }
}

// ------- GEMM2: Y = relu(BN1(X)) @ W + bias, BN1 finalize fused into prologue ------
__global__ void __launch_bounds__(256) k_gemm2(
    const __bf16* __restrict__ X,
    const __bf16* __restrict__ Whi, const __bf16* __restrict__ Wlo,
    const float* __restrict__ bias,
    const float* __restrict__ statA,
    const float* __restrict__ gamma, const float* __restrict__ beta,
    __bf16* __restrict__ Y,
    float* __restrict__ statpart) {
  __shared__ float sld[DMODEL];
  __shared__ float tld[DMODEL];
  int tid = threadIdx.x;

  if (tid < DMODEL) {
    float sum = 0.0f;
    float sq = 0.0f;
    for (int p = 0; p < NSLOT; ++p) {
      sum += statA[p * (2 * DMODEL) + tid];
      sq  += statA[p * (2 * DMODEL) + DMODEL + tid];
    }
    float mean = sum * (1.0f / N_NODES);
    float var = sq * (1.0f / N_NODES) - mean * mean;
    float inv = rsqrtf(var + BN_EPS);
    float s = gamma[tid] * inv;
    sld[tid] = s;
    tld[tid] = beta[tid] - mean * s;
  }
  __syncthreads();

  int wave = tid >> 6;
  int lane = tid & 63;
  int n16 = lane & 15;
  int quad = lane >> 4;

  bf16x8 bhi[2][4];
  bf16x8 blo[2][4];
#pragma unroll
  for (int ct = 0; ct < 2; ++ct) {
    int n = (wave * 2 + ct) * 16 + n16;
#pragma unroll
    for (int kk = 0; kk < 4; ++kk) {
      int k0 = kk * 32 + quad * 8;
      bhi[ct][kk] = *(const bf16x8*)(Whi + (size_t)n * DMODEL + k0);
      blo[ct][kk] = *(const bf16x8*)(Wlo + (size_t)n * DMODEL + k0);
    }
  }
  float bc[2];
  bc[0] = bias[(wave * 2 + 0) * 16 + n16];
  bc[1] = bias[(wave * 2 + 1) * 16 + n16];

  float ssum[2] = {0.0f, 0.0f};
  float ssq[2] = {0.0f, 0.0f};

  const int NCHUNK = N_NODES / 32;   // 3125 exact
  for (int c = blockIdx.x; c < NCHUNK; c += gridDim.x) {
    int row0 = c * 32;
    bf16x8 a[2][4];
#pragma unroll
    for (int t = 0; t < 2; ++t) {
      const __bf16* xr = X + (size_t)(row0 + t * 16 + n16) * DMODEL;
#pragma unroll
      for (int kk = 0; kk < 4; ++kk) {
        a[t][kk] = *(const bf16x8*)(xr + kk * 32 + quad * 8);
      }
    }
#pragma unroll
    for (int kk = 0; kk < 4; ++kk) {
      int k0 = kk * 32 + quad * 8;
      float4 s0 = *(const float4*)(sld + k0);
      float4 s1 = *(const float4*)(sld + k0 + 4);
      float4 t0 = *(const float4*)(tld + k0);
      float4 t1 = *(const float4*)(tld + k0 + 4);
      float sv[8];
      float tv[8];
      sv[0] = s0.x; sv[1] = s0.y; sv[2] = s0.z; sv[3] = s0.w;
      sv[4] = s1.x; sv[5] = s1.y; sv[6] = s1.z; sv[7] = s1.w;
      tv[0] = t0.x; tv[1] = t0.y; tv[2] = t0.z; tv[3] = t0.w;
      tv[4] = t1.x; tv[5] = t1.y; tv[6] = t1.z; tv[7] = t1.w;
#pragma unroll
      for (int t = 0; t < 2; ++t) {
#pragma unroll
        for (int jj = 0; jj < 8; ++jj) {
          float f = (float)a[t][kk][jj];
          a[t][kk][jj] = (__bf16)fmaxf(sv[jj] * f + tv[jj], 0.0f);
        }
      }
    }

    f32x4 acc[2][2];
#pragma unroll
    for (int t = 0; t < 2; ++t)
#pragma unroll
      for (int ct = 0; ct < 2; ++ct)
#pragma unroll
        for (int r = 0; r < 4; ++r) acc[t][ct][r] = 0.0f;

#pragma unroll
    for (int kk = 0; kk < 4; ++kk) {
#pragma unroll
      for (int ct = 0; ct < 2; ++ct) {
#pragma unroll
        for (int t = 0; t < 2; ++t) {
          acc[t][ct] = __builtin_amdgcn_mfma_f32_16x16x32_bf16(a[t][kk], bhi[ct][kk], acc[t][ct], 0, 0, 0);
          acc[t][ct] = __builtin_amdgcn_mfma_f32_16x16x32_bf16(a[t][kk], blo[ct][kk], acc[t][ct], 0, 0, 0);
        }
      }
    }

#pragma unroll
    for (int t = 0; t < 2; ++t) {
#pragma unroll
      for (int ct = 0; ct < 2; ++ct) {
        int col = (wave * 2 + ct) * 16 + n16;
#pragma unroll
        for (int r = 0; r < 4; ++r) {
          int row = row0 + t * 16 + quad * 4 + r;
          float v = acc[t][ct][r] + bc[ct];
          Y[(size_t)row * DMODEL + col] = (__bf16)v;
          ssum[ct] += v;
          ssq[ct] += v * v;
        }
      }
    }
  }

  int slot = blockIdx.x & (NSLOT - 1);
#pragma unroll
  for (int ct = 0; ct < 2; ++ct) {
    int col = (wave * 2 + ct) * 16 + n16;
    float s = ssum[ct];
    float q = ssq[ct];
    s += __shfl_xor(s, 16);
    q += __shfl_xor(q, 16);
    s += __shfl_xor(s, 32);
    q += __shfl_xor(q, 32);
    if (quad == 0) {
      atomicAdd(&statpart[slot * (2 * DMODEL) + col], s);
      atomicAdd(&statpart[slot * (2 * DMODEL) + DMODEL + col], q);
    }
  }
}

// ------- pooling partial sums of raw h (affine deferred to classifier) -------
__global__ void k_pool(const __bf16* __restrict__ h, const int* __restrict__ gstart,
                       float* __restrict__ psum) {
  int g = blockIdx.x;
  int slice = blockIdx.y;   // 0..7
  int lane = threadIdx.x;   // 64
  int d0 = lane * 2;
  int i0 = gstart[g];
  int i1 = gstart[g + 1];
  float a0 = 0.0f;
  float a1 = 0.0f;
  for (int i = i0 + slice; i < i1; i += 8) {
    bf16x2 v = *(const bf16x2*)(h + (size_t)i * DMODEL + d0);
    a0 += (float)v[0];
    a1 += (float)v[1];
  }
  atomicAdd(&psum[g * DMODEL + d0], a0);
  atomicAdd(&psum[g * DMODEL + d0 + 1], a1);
}

// ------- classifier: fused final BN2 finalize, mean + affine, Linear-ReLU-Linear ---
__global__ void k_classifier(const float* __restrict__ psum, const int* __restrict__ gstart,
                             const float* __restrict__ statB,
                             const float* __restrict__ gamma, const float* __restrict__ beta,
                             const float* __restrict__ cw1, const float* __restrict__ cb1,
                             const float* __restrict__ cw2, const float* __restrict__ cb2,
                             float* __restrict__ out) {
  __shared__ float pl[DMODEL];
  __shared__ float hid[DMODEL];
  int g = blockIdx.x;
  int d = threadIdx.x;
  float sum = 0.0f;
  float sq = 0.0f;
  for (int p = 0; p < NSLOT; ++p) {
    sum += statB[p * (2 * DMODEL) + d];
    sq  += statB[p * (2 * DMODEL) + DMODEL + d];
  }
  float mean = sum * (1.0f / N_NODES);
  float var = sq * (1.0f / N_NODES) - mean * mean;
  float inv = rsqrtf(var + BN_EPS);
  float s2 = gamma[d] * inv;
  float t2 = beta[d] - mean * s2;

  int cnt = gstart[g + 1] - gstart[g];
  pl[d] = (cnt > 0) ? (s2 * (psum[g * DMODEL + d] / (float)cnt) + t2) : 0.0f;
  __syncthreads();
  float acc = cb1[d];
  for (int k = 0; k < DMODEL; ++k) acc += pl[k] * cw1[k * DMODEL + d];
  hid[d] = fmaxf(acc, 0.0f);
  __syncthreads();
  if (d < NCLASS) {
    float acc2 = cb2[d];
    for (int k = 0; k < DMODEL; ++k) acc2 += hid[k] * cw2[k * NCLASS + d];
    out[g * NCLASS + d] = acc2;
  }
}

// ---------------- launcher ----------------
extern "C" void kernel_launch(void* const* d_in, const int* in_sizes, int n_in,
                              void* d_out, int out_size, void* d_ws, size_t ws_size,
                              hipStream_t stream) {
  const int*   x      = (const int*)d_in[0];
  const int*   ei     = (const int*)d_in[1];
  const float* ea     = (const float*)d_in[2];
  const int*   batch  = (const int*)d_in[3];
  const float* emb    = (const float*)d_in[4];
  const float* edge_w = (const float*)d_in[5];
  const float* edge_b = (const float*)d_in[6];
  const float* w1     = (const float*)d_in[7];
  const float* b1     = (const float*)d_in[8];
  const float* g1     = (const float*)d_in[9];
  const float* beta1  = (const float*)d_in[10];
  const float* w2     = (const float*)d_in[11];
  const float* b2     = (const float*)d_in[12];
  const float* ng     = (const float*)d_in[13];
  const float* nb     = (const float*)d_in[14];
  const float* cw1    = (const float*)d_in[15];
  const float* cb1    = (const float*)d_in[16];
  const float* cw2    = (const float*)d_in[17];
  const float* cb2    = (const float*)d_in[18];

  char* ws = (char*)d_ws;
  size_t off = 0;
  auto alloc = [&](size_t bytes) -> void* {
    void* p = ws + off;
    off += (bytes + 255) & ~(size_t)255;
    return p;
  };

  __bf16* h_bf      = (__bf16*)alloc((size_t)N_NODES * DMODEL * sizeof(__bf16));
  __bf16* y1_bf     = (__bf16*)alloc((size_t)N_NODES * DMODEL * sizeof(__bf16));
  int*    row_start = (int*)alloc((N_NODES + 1) * sizeof(int));
  int*    cursor    = (int*)alloc(N_NODES * sizeof(int));
  int*    deg       = (int*)alloc(N_NODES * sizeof(int));
  int*    sched     = (int*)alloc(N_NODES * sizeof(int));
  int2*   epack     = (int2*)alloc((size_t)N_EDGES * sizeof(int2));
  __bf16* wt_hi     = (__bf16*)alloc((size_t)NLAYERS * 2 * DMODEL * DMODEL * sizeof(__bf16));
  __bf16* wt_lo     = (__bf16*)alloc((size_t)NLAYERS * 2 * DMODEL * DMODEL * sizeof(__bf16));
  float*  statA     = (float*)alloc((size_t)NLAYERS * STATSZ * sizeof(float));
  float*  statB     = (float*)alloc((size_t)NLAYERS * STATSZ * sizeof(float));
  int*    gstart    = (int*)alloc((NGRAPH + 1) * sizeof(int));
  float*  psum      = (float*)alloc((size_t)NGRAPH * DMODEL * sizeof(float));
  int*    dbin      = (int*)alloc(NBIN * sizeof(int));
  int*    dcursor   = (int*)alloc(NBIN * sizeof(int));
  int*    bsum      = (int*)alloc(512 * sizeof(int));
  int*    bsumx     = (int*)alloc(512 * sizeof(int));

  auto statAL = [&](int l) { return statA + (size_t)l * STATSZ; };
  auto statBL = [&](int l) { return statB + (size_t)l * STATSZ; };

  const int nbScan = (N_NODES + 255) / 256;              // 391
  const int nbEdge = (N_EDGES + 255) / 256;              // 2344
  const int nbPre1 = (N_NODES * DMODEL / 8 + 255) / 256; // 6250
  const int nbGemm = 782;                                // gemm2 grid-stride
  const int nbFuse = N_NODES / 32;                       // 3125, one 32-node block

  k_pre1<<<nbPre1, 256, 0, stream>>>(deg, statA, statB, psum, dbin,
                                     w1, w2, wt_hi, wt_lo, batch, gstart,
                                     x, emb, h_bf);
  k_hist<<<nbEdge, 256, 0, stream>>>(ei + N_EDGES, deg);
  k_pre2<<<nbScan, 256, 0, stream>>>(deg, row_start, bsum, dbin);
  k_pre3<<<1, 512, 0, stream>>>(bsum, bsumx, nbScan, dbin, dcursor);
  k_pre4<<<nbScan, 256, 0, stream>>>(row_start, cursor, bsumx, deg, dcursor, sched);
  k_scatter<<<nbEdge, 256, 0, stream>>>(ei, ea, cursor, epack);

  for (int l = 0; l < NLAYERS; ++l) {
    const float* sPrev = (l > 0) ? statBL(l - 1) : (const float*)nullptr;
    const float* gPrev = (l > 0) ? (ng + (size_t)(l - 1) * DMODEL) : (const float*)nullptr;
    const float* bPrev = (l > 0) ? (nb + (size_t)(l - 1) * DMODEL) : (const float*)nullptr;
    // fused: z (LDS only) = agg(act(h)); y1 = z @ w1[l] + b1[l]; stats -> statA[l]
    k_aggemm<<<nbFuse, 256, 0, stream>>>(
        h_bf, row_start, epack, sched,
        edge_w + (size_t)l * 2 * DMODEL,
        edge_b + (size_t)l * DMODEL,
        sPrev, gPrev, bPrev, (l > 0) ? 1 : 0,
        wt_hi + (size_t)(l * 2 + 0) * DMODEL * DMODEL,
        wt_lo + (size_t)(l * 2 + 0) * DMODEL * DMODEL,
        b1 + (size_t)l * DMODEL,
        y1_bf, statAL(l));
    // h = relu(BN1(y1)) @ w2[l] + b2[l]; BN1 finalize fused; stats -> statB[l]
    k_gemm2<<<nbGemm, 256, 0, stream>>>(
        y1_bf,
        wt_hi + (size_t)(l * 2 + 1) * DMODEL * DMODEL,
        wt_lo + (size_t)(l * 2 + 1) * DMODEL * DMODEL,
        b2 + (size_t)l * DMODEL,
        statAL(l), g1 + (size_t)l * DMODEL, beta1 + (size_t)l * DMODEL,
        h_bf, statBL(l));
  }

  dim3 poolGrid(NGRAPH, 8);
  k_pool<<<poolGrid, 64, 0, stream>>>(h_bf, gstart, psum);
  k_classifier<<<NGRAPH, DMODEL, 0, stream>>>(psum, gstart, statBL(NLAYERS - 1),
                                              ng + (size_t)(NLAYERS - 1) * DMODEL,
                                              nb + (size_t)(NLAYERS - 1) * DMODEL,
                                              cw1, cb1, cw2, cb2, (float*)d_out);
}

// Round 19
// 594.471 us; speedup vs baseline: 1.1331x; 1.0101x over previous
//
#include <hip/hip_runtime.h>
#include <stdint.h>

#define N_NODES 100000
#define N_EDGES 600000
#define DMODEL  128
#define NLAYERS 4
#define NGRAPH  128
#define NCLASS  10
#define BN_EPS  1e-5f
#define NSLOT   8      // stat partial slots
#define STATSZ  (NSLOT * 2 * DMODEL)
#define ZSTR    136    // LDS z-tile row stride in bf16
#define NBIN    64     // degree bins for the schedule counting-sort

typedef __bf16 bf16x8 __attribute__((ext_vector_type(8)));
typedef __bf16 bf16x4 __attribute__((ext_vector_type(4)));
typedef __bf16 bf16x2 __attribute__((ext_vector_type(2)));
typedef float  f32x4  __attribute__((ext_vector_type(4)));

static __device__ __forceinline__ bf16x2 unpack_bf16x2(int v) {
  union { int i; bf16x2 h; } u;
  u.i = v;
  return u.h;
}
static __device__ __forceinline__ int pack_bf16x2(float a, float b) {
  union { int i; bf16x2 h; } u;
  u.h[0] = (__bf16)a;
  u.h[1] = (__bf16)b;
  return u.i;
}

// ======= pre1: init (zero buffers, split weights, graph bounds) + embed =======
__global__ void k_pre1(int* __restrict__ deg, float* __restrict__ statA,
                       float* __restrict__ statB, float* __restrict__ psum,
                       int* __restrict__ dbin,
                       const float* __restrict__ w1, const float* __restrict__ w2,
                       __bf16* __restrict__ wt_hi, __bf16* __restrict__ wt_lo,
                       const int* __restrict__ batch, int* __restrict__ gstart,
                       const int* __restrict__ x, const float* __restrict__ emb,
                       __bf16* __restrict__ h) {
  int idx = blockIdx.x * 256 + threadIdx.x;
  if (idx < N_NODES * DMODEL / 8) {
    int i = idx >> 4;
    int p = idx & 15;
    const float* src = emb + (size_t)x[i] * DMODEL + p * 8;
    float4 v0 = *(const float4*)(src);
    float4 v1 = *(const float4*)(src + 4);
    bf16x8 o;
    o[0] = (__bf16)v0.x; o[1] = (__bf16)v0.y; o[2] = (__bf16)v0.z; o[3] = (__bf16)v0.w;
    o[4] = (__bf16)v1.x; o[5] = (__bf16)v1.y; o[6] = (__bf16)v1.z; o[7] = (__bf16)v1.w;
    *(bf16x8*)(h + (size_t)i * DMODEL + p * 8) = o;
  }
  if (idx < NLAYERS * 2 * DMODEL * DMODEL) {
    int i = idx;
    if (i < N_NODES) deg[i] = 0;
    if (i < NLAYERS * STATSZ) {
      statA[i] = 0.0f;
      statB[i] = 0.0f;
    }
    if (i < NGRAPH * DMODEL) psum[i] = 0.0f;
    if (i < NBIN) dbin[i] = 0;
    {
      int mat = i >> 14;
      int rem = i & 16383;
      int n = rem >> 7;
      int k = rem & 127;
      int l = mat >> 1;
      int which = mat & 1;
      const float* w = which ? w2 : w1;
      float v = w[(size_t)l * DMODEL * DMODEL + (size_t)k * DMODEL + n];
      __bf16 hi = (__bf16)v;
      wt_hi[i] = hi;
      wt_lo[i] = (__bf16)(v - (float)hi);
    }
    if (i <= NGRAPH) {
      int lo = 0;
      int hi = N_NODES;
      while (lo < hi) {
        int mid = (lo + hi) >> 1;
        if (batch[mid] < i) lo = mid + 1; else hi = mid;
      }
      gstart[i] = lo;
    }
  }
}

// ---------------- histogram of dst degrees (needs zeroed deg) ----------------
__global__ void k_hist(const int* __restrict__ dst, int* __restrict__ deg) {
  int e = blockIdx.x * 256 + threadIdx.x;
  if (e < N_EDGES) atomicAdd(&deg[dst[e]], 1);
}

// ======= pre2: scan1 + dhist =======
__global__ void k_pre2(const int* __restrict__ deg, int* __restrict__ out,
                       int* __restrict__ bsum, int* __restrict__ dbin) {
  __shared__ int lds[256];
  __shared__ int lbin[NBIN];
  int t = threadIdx.x;
  int idx = blockIdx.x * 256 + t;
  int v = (idx < N_NODES) ? deg[idx] : 0;
  int val = v;
  lds[t] = val;
  if (t < NBIN) lbin[t] = 0;
  for (int ofs = 1; ofs < 256; ofs <<= 1) {
    __syncthreads();
    int u = (t >= ofs) ? lds[t - ofs] : 0;
    __syncthreads();
    val += u;
    lds[t] = val;
  }
  if (idx < N_NODES) out[idx] = val - v;
  if (t == 255) bsum[blockIdx.x] = val;
  __syncthreads();
  if (idx < N_NODES) atomicAdd(&lbin[min(v, NBIN - 1)], 1);
  __syncthreads();
  if (t < NBIN && lbin[t] > 0) atomicAdd(&dbin[t], lbin[t]);
}

// ======= pre3: scan2 + dscan, 1 block =======
__global__ void k_pre3(const int* __restrict__ bsum, int* __restrict__ bsumx, int nb,
                       const int* __restrict__ dbin, int* __restrict__ dcursor) {
  __shared__ int lds[512];
  __shared__ int ldb[NBIN];
  int t = threadIdx.x;
  int v = (t < nb) ? bsum[t] : 0;
  int val = v;
  lds[t] = val;
  for (int ofs = 1; ofs < 512; ofs <<= 1) {
    __syncthreads();
    int u = (t >= ofs) ? lds[t - ofs] : 0;
    __syncthreads();
    val += u;
    lds[t] = val;
  }
  if (t < nb) bsumx[t] = val - v;
  __syncthreads();
  if (t < NBIN) {
    int dv = dbin[t];
    int dval = dv;
    ldb[t] = dval;
    for (int ofs = 1; ofs < NBIN; ofs <<= 1) {
      __syncthreads();
      int u = (t >= ofs) ? ldb[t - ofs] : 0;
      __syncthreads();
      dval += u;
      ldb[t] = dval;
    }
    dcursor[t] = dval - dv;
  }
}

// ======= pre4: scan3 + dscatter =======
__global__ void k_pre4(int* __restrict__ row_start, int* __restrict__ cursor,
                       const int* __restrict__ bsumx,
                       const int* __restrict__ deg, int* __restrict__ dcursor,
                       int* __restrict__ sched) {
  __shared__ int lcnt[NBIN];
  __shared__ int lbase[NBIN];
  int t = threadIdx.x;
  int idx = blockIdx.x * 256 + t;
  if (idx < N_NODES) {
    int v = row_start[idx] + bsumx[blockIdx.x];
    row_start[idx] = v;
    cursor[idx] = v;
  }
  if (idx == 0) row_start[N_NODES] = N_EDGES;
  if (t < NBIN) lcnt[t] = 0;
  __syncthreads();
  int b = 0;
  int lrank = 0;
  if (idx < N_NODES) {
    b = min(deg[idx], NBIN - 1);
    lrank = atomicAdd(&lcnt[b], 1);
  }
  __syncthreads();
  if (t < NBIN) lbase[t] = (lcnt[t] > 0) ? atomicAdd(&dcursor[t], lcnt[t]) : 0;
  __syncthreads();
  if (idx < N_NODES) sched[lbase[b] + lrank] = idx;
}

// ------- pre5: pack each edge as 8B {src, bf16 a0, bf16 a1} at its CSR slot -------
__global__ void k_scatter(const int* __restrict__ ei, const float* __restrict__ ea,
                          int* __restrict__ cursor, int2* __restrict__ epack) {
  int e = blockIdx.x * 256 + threadIdx.x;
  if (e >= N_EDGES) return;
  int s = ei[e];
  int d = ei[N_EDGES + e];
  int pos = atomicAdd(&cursor[d], 1);
  int2 pk;
  pk.x = s;
  pk.y = pack_bf16x2(ea[2 * e], ea[2 * e + 1]);
  epack[pos] = pk;
}

// ======= FUSED agg+gemm1: one block = 32 degree-similar nodes from sched =======
// LPT dispatch (heavy chunks first). Phase 1 PAIR-INTERLEAVED: each half-wave
// processes its 4 nodes as 2 pairs; within a pair, A and B's 4-edge groups issue
// together (8 gathers + 8 prefetched epack in flight per wait — halves the count
// of dependent latency waits vs the sequential round-18 form). Degree-sorted
// schedule makes pair degrees near-equal so drains are tiny. Per-node edge order
// unchanged -> bit-identical per-node accumulation.
__global__ void __launch_bounds__(256) k_aggemm(
    const __bf16* __restrict__ h, const int* __restrict__ row_start,
    const int2* __restrict__ epack, const int* __restrict__ sched,
    const float* __restrict__ ew,       // edge_w + l*2*D, layout [2][D]
    const float* __restrict__ ebp,      // edge_b + l*D
    const float* __restrict__ statPrev, // statB of layer l-1 (or null)
    const float* __restrict__ gammaP, const float* __restrict__ betaP, int hasT,
    const __bf16* __restrict__ Whi, const __bf16* __restrict__ Wlo,
    const float* __restrict__ bias,
    __bf16* __restrict__ Y,
    float* __restrict__ statpart) {
  __shared__ __align__(16) __bf16 zt[32 * ZSTR];   // 8704 B
  __shared__ float sld[DMODEL];
  __shared__ float tld[DMODEL];
  __shared__ int snode[32];
  int tid = threadIdx.x;
  int cb = (int)gridDim.x - 1 - (int)blockIdx.x;   // LPT: heavy chunks first

  if (hasT) {
    if (tid < DMODEL) {
      float sum = 0.0f;
      float sq = 0.0f;
      for (int p = 0; p < NSLOT; ++p) {
        sum += statPrev[p * (2 * DMODEL) + tid];
        sq  += statPrev[p * (2 * DMODEL) + DMODEL + tid];
      }
      float mean = sum * (1.0f / N_NODES);
      float var = sq * (1.0f / N_NODES) - mean * mean;
      float inv = rsqrtf(var + BN_EPS);
      float s = gammaP[tid] * inv;
      sld[tid] = s;
      tld[tid] = betaP[tid] - mean * s;
    }
    __syncthreads();
  }

  // ---- phase 1: pair-interleaved gather/aggregate ----
  int hw = tid >> 5;
  int ln = tid & 31;
  int d0 = ln * 4;

  float4 ew0 = *(const float4*)(ew + d0);
  float4 ew1 = *(const float4*)(ew + DMODEL + d0);
  float4 eb  = *(const float4*)(ebp + d0);
  float4 s4;
  float4 t4;
  if (hasT) {
    s4 = *(const float4*)(sld + d0);
    t4 = *(const float4*)(tld + d0);
  }

#define AGG_E(E, V, A0, A1, A2, A3)                                            \
  {                                                                            \
    bf16x2 av = unpack_bf16x2((E).y);                                          \
    float a0 = (float)av[0];                                                   \
    float a1 = (float)av[1];                                                   \
    float f0 = (float)(V)[0];                                                  \
    float f1 = (float)(V)[1];                                                  \
    float f2 = (float)(V)[2];                                                  \
    float f3 = (float)(V)[3];                                                  \
    if (hasT) {                                                                \
      f0 = fmaxf(s4.x * f0 + t4.x, 0.0f);                                      \
      f1 = fmaxf(s4.y * f1 + t4.y, 0.0f);                                      \
      f2 = fmaxf(s4.z * f2 + t4.z, 0.0f);                                      \
      f3 = fmaxf(s4.w * f3 + t4.w, 0.0f);                                      \
    }                                                                          \
    A0 += fmaxf(f0 + a0 * ew0.x + a1 * ew1.x + eb.x, 0.0f);                    \
    A1 += fmaxf(f1 + a0 * ew0.y + a1 * ew1.y + eb.y, 0.0f);                    \
    A2 += fmaxf(f2 + a0 * ew0.z + a1 * ew1.z + eb.z, 0.0f);                    \
    A3 += fmaxf(f3 + a0 * ew0.w + a1 * ew1.w + eb.w, 0.0f);                    \
  }

  for (int p = 0; p < 2; ++p) {
    int nlA = hw * 4 + p * 2;
    int nodeA = sched[cb * 32 + nlA];
    int nodeB = sched[cb * 32 + nlA + 1];
    if (ln == 0) {
      snode[nlA] = nodeA;
      snode[nlA + 1] = nodeB;
    }
    float accA0, accA1, accA2, accA3;
    float accB0, accB1, accB2, accB3;
    {
      bf16x4 hA = *(const bf16x4*)(h + (size_t)nodeA * DMODEL + d0);
      bf16x4 hB = *(const bf16x4*)(h + (size_t)nodeB * DMODEL + d0);
      float rA0 = (float)hA[0], rA1 = (float)hA[1], rA2 = (float)hA[2], rA3 = (float)hA[3];
      float rB0 = (float)hB[0], rB1 = (float)hB[1], rB2 = (float)hB[2], rB3 = (float)hB[3];
      if (hasT) {
        accA0 = fmaxf(s4.x * rA0 + t4.x, 0.0f);
        accA1 = fmaxf(s4.y * rA1 + t4.y, 0.0f);
        accA2 = fmaxf(s4.z * rA2 + t4.z, 0.0f);
        accA3 = fmaxf(s4.w * rA3 + t4.w, 0.0f);
        accB0 = fmaxf(s4.x * rB0 + t4.x, 0.0f);
        accB1 = fmaxf(s4.y * rB1 + t4.y, 0.0f);
        accB2 = fmaxf(s4.z * rB2 + t4.z, 0.0f);
        accB3 = fmaxf(s4.w * rB3 + t4.w, 0.0f);
      } else {
        accA0 = rA0; accA1 = rA1; accA2 = rA2; accA3 = rA3;
        accB0 = rB0; accB1 = rB1; accB2 = rB2; accB3 = rB3;
      }
    }
    int jA = row_start[nodeA];
    int jA1 = row_start[nodeA + 1];
    int jB = row_start[nodeB];
    int jB1 = row_start[nodeB + 1];

    // paired main loop: 4 edges of A + 4 of B per iteration, epack prefetched
    int2 eA0, eA1, eA2, eA3, eB0, eB1, eB2, eB3;
    bool have = (jA + 4 <= jA1) && (jB + 4 <= jB1);
    if (have) {
      eA0 = epack[jA];     eA1 = epack[jA + 1];
      eA2 = epack[jA + 2]; eA3 = epack[jA + 3];
      eB0 = epack[jB];     eB1 = epack[jB + 1];
      eB2 = epack[jB + 2]; eB3 = epack[jB + 3];
    }
    while (have) {
      int jAn = jA + 4;
      int jBn = jB + 4;
      bool haveN = (jAn + 4 <= jA1) && (jBn + 4 <= jB1);
      int2 nA0, nA1, nA2, nA3, nB0, nB1, nB2, nB3;
      if (haveN) {
        nA0 = epack[jAn];     nA1 = epack[jAn + 1];
        nA2 = epack[jAn + 2]; nA3 = epack[jAn + 3];
        nB0 = epack[jBn];     nB1 = epack[jBn + 1];
        nB2 = epack[jBn + 2]; nB3 = epack[jBn + 3];
      }
      bf16x4 vA0 = *(const bf16x4*)(h + (size_t)eA0.x * DMODEL + d0);
      bf16x4 vA1 = *(const bf16x4*)(h + (size_t)eA1.x * DMODEL + d0);
      bf16x4 vA2 = *(const bf16x4*)(h + (size_t)eA2.x * DMODEL + d0);
      bf16x4 vA3 = *(const bf16x4*)(h + (size_t)eA3.x * DMODEL + d0);
      bf16x4 vB0 = *(const bf16x4*)(h + (size_t)eB0.x * DMODEL + d0);
      bf16x4 vB1 = *(const bf16x4*)(h + (size_t)eB1.x * DMODEL + d0);
      bf16x4 vB2 = *(const bf16x4*)(h + (size_t)eB2.x * DMODEL + d0);
      bf16x4 vB3 = *(const bf16x4*)(h + (size_t)eB3.x * DMODEL + d0);
      AGG_E(eA0, vA0, accA0, accA1, accA2, accA3)
      AGG_E(eA1, vA1, accA0, accA1, accA2, accA3)
      AGG_E(eA2, vA2, accA0, accA1, accA2, accA3)
      AGG_E(eA3, vA3, accA0, accA1, accA2, accA3)
      AGG_E(eB0, vB0, accB0, accB1, accB2, accB3)
      AGG_E(eB1, vB1, accB0, accB1, accB2, accB3)
      AGG_E(eB2, vB2, accB0, accB1, accB2, accB3)
      AGG_E(eB3, vB3, accB0, accB1, accB2, accB3)
      eA0 = nA0; eA1 = nA1; eA2 = nA2; eA3 = nA3;
      eB0 = nB0; eB1 = nB1; eB2 = nB2; eB3 = nB3;
      jA = jAn;
      jB = jBn;
      have = haveN;
    }
    // drain A (4-wide then scalar)
    for (; jA + 4 <= jA1; jA += 4) {
      int2 x0 = epack[jA];
      int2 x1 = epack[jA + 1];
      int2 x2 = epack[jA + 2];
      int2 x3 = epack[jA + 3];
      bf16x4 v0 = *(const bf16x4*)(h + (size_t)x0.x * DMODEL + d0);
      bf16x4 v1 = *(const bf16x4*)(h + (size_t)x1.x * DMODEL + d0);
      bf16x4 v2 = *(const bf16x4*)(h + (size_t)x2.x * DMODEL + d0);
      bf16x4 v3 = *(const bf16x4*)(h + (size_t)x3.x * DMODEL + d0);
      AGG_E(x0, v0, accA0, accA1, accA2, accA3)
      AGG_E(x1, v1, accA0, accA1, accA2, accA3)
      AGG_E(x2, v2, accA0, accA1, accA2, accA3)
      AGG_E(x3, v3, accA0, accA1, accA2, accA3)
    }
    for (; jA < jA1; ++jA) {
      int2 x0 = epack[jA];
      bf16x4 v0 = *(const bf16x4*)(h + (size_t)x0.x * DMODEL + d0);
      AGG_E(x0, v0, accA0, accA1, accA2, accA3)
    }
    // drain B (4-wide then scalar)
    for (; jB + 4 <= jB1; jB += 4) {
      int2 x0 = epack[jB];
      int2 x1 = epack[jB + 1];
      int2 x2 = epack[jB + 2];
      int2 x3 = epack[jB + 3];
      bf16x4 v0 = *(const bf16x4*)(h + (size_t)x0.x * DMODEL + d0);
      bf16x4 v1 = *(const bf16x4*)(h + (size_t)x1.x * DMODEL + d0);
      bf16x4 v2 = *(const bf16x4*)(h + (size_t)x2.x * DMODEL + d0);
      bf16x4 v3 = *(const bf16x4*)(h + (size_t)x3.x * DMODEL + d0);
      AGG_E(x0, v0, accB0, accB1, accB2, accB3)
      AGG_E(x1, v1, accB0, accB1, accB2, accB3)
      AGG_E(x2, v2, accB0, accB1, accB2, accB3)
      AGG_E(x3, v3, accB0, accB1, accB2, accB3)
    }
    for (; jB < jB1; ++jB) {
      int2 x0 = epack[jB];
      bf16x4 v0 = *(const bf16x4*)(h + (size_t)x0.x * DMODEL + d0);
      AGG_E(x0, v0, accB0, accB1, accB2, accB3)
    }
    bf16x4 oA;
    oA[0] = (__bf16)accA0;
    oA[1] = (__bf16)accA1;
    oA[2] = (__bf16)accA2;
    oA[3] = (__bf16)accA3;
    *(bf16x4*)(zt + nlA * ZSTR + d0) = oA;
    bf16x4 oB;
    oB[0] = (__bf16)accB0;
    oB[1] = (__bf16)accB1;
    oB[2] = (__bf16)accB2;
    oB[3] = (__bf16)accB3;
    *(bf16x4*)(zt + (nlA + 1) * ZSTR + d0) = oB;
  }
#undef AGG_E

  __syncthreads();

  // ---- phase 2: 32x128 GEMM on the LDS z-tile ----
  int wave = tid >> 6;
  int lane = tid & 63;
  int n16 = lane & 15;
  int quad = lane >> 4;

  bf16x8 bhi[2][4];
  bf16x8 blo[2][4];
#pragma unroll
  for (int ct = 0; ct < 2; ++ct) {
    int n = (wave * 2 + ct) * 16 + n16;
#pragma unroll
    for (int kk = 0; kk < 4; ++kk) {
      int k0 = kk * 32 + quad * 8;
      bhi[ct][kk] = *(const bf16x8*)(Whi + (size_t)n * DMODEL + k0);
      blo[ct][kk] = *(const bf16x8*)(Wlo + (size_t)n * DMODEL + k0);
    }
  }
  float bc[2];
  bc[0] = bias[(wave * 2 + 0) * 16 + n16];
  bc[1] = bias[(wave * 2 + 1) * 16 + n16];

  bf16x8 a[2][4];
#pragma unroll
  for (int t = 0; t < 2; ++t) {
    const __bf16* zr = zt + (t * 16 + n16) * ZSTR;
#pragma unroll
    for (int kk = 0; kk < 4; ++kk) {
      a[t][kk] = *(const bf16x8*)(zr + kk * 32 + quad * 8);
    }
  }

  f32x4 acc[2][2];
#pragma unroll
  for (int t = 0; t < 2; ++t)
#pragma unroll
    for (int ct = 0; ct < 2; ++ct)
#pragma unroll
      for (int r = 0; r < 4; ++r) acc[t][ct][r] = 0.0f;

#pragma unroll
  for (int kk = 0; kk < 4; ++kk) {
#pragma unroll
    for (int ct = 0; ct < 2; ++ct) {
#pragma unroll
      for (int t = 0; t < 2; ++t) {
        acc[t][ct] = __builtin_amdgcn_mfma_f32_16x16x32_bf16(a[t][kk], bhi[ct][kk], acc[t][ct], 0, 0, 0);
        acc[t][ct] = __builtin_amdgcn_mfma_f32_16x16x32_bf16(a[t][kk], blo[ct][kk], acc[t][ct], 0, 0, 0);
      }
    }
  }

  float ssum[2] = {0.0f, 0.0f};
  float ssq[2] = {0.0f, 0.0f};
#pragma unroll
  for (int t = 0; t < 2; ++t) {
#pragma unroll
    for (int ct = 0; ct < 2; ++ct) {
      int col = (wave * 2 + ct) * 16 + n16;
#pragma unroll
      for (int r = 0; r < 4; ++r) {
        int row = snode[t * 16 + quad * 4 + r];
        float v = acc[t][ct][r] + bc[ct];
        Y[(size_t)row * DMODEL + col] = (__bf16)v;
        ssum[ct] += v;
        ssq[ct] += v * v;
      }
    }
  }

  int slot = cb & (NSLOT - 1);
#pragma unroll
  for (int ct = 0; ct < 2; ++ct) {
    int col = (wave * 2 + ct) * 16 + n16;
    float s = ssum[ct];
    float q = ssq[ct];
    s += __shfl_xor(s, 16);
    q += __shfl_xor(q, 16);
    s += __shfl_xor(s, 32);
    q += __shfl_xor(q, 32);
    if (quad == 0) {
      atomicAdd(&statpart[slot * (2 * DMODEL) + col], s);
      atomicAdd(&statpart[slot * (2 * DMODEL) + DMODEL + col], q);
    }
  }
}

// ------- GEMM2: Y = relu(BN1(X)) @ W + bias, BN1 finalize fused into prologue ------
__global__ void __launch_bounds__(256) k_gemm2(
    const __bf16* __restrict__ X,
    const __bf16* __restrict__ Whi, const __bf16* __restrict__ Wlo,
    const float* __restrict__ bias,
    const float* __restrict__ statA,
    const float* __restrict__ gamma, const float* __restrict__ beta,
    __bf16* __restrict__ Y,
    float* __restrict__ statpart) {
  __shared__ float sld[DMODEL];
  __shared__ float tld[DMODEL];
  int tid = threadIdx.x;

  if (tid < DMODEL) {
    float sum = 0.0f;
    float sq = 0.0f;
    for (int p = 0; p < NSLOT; ++p) {
      sum += statA[p * (2 * DMODEL) + tid];
      sq  += statA[p * (2 * DMODEL) + DMODEL + tid];
    }
    float mean = sum * (1.0f / N_NODES);
    float var = sq * (1.0f / N_NODES) - mean * mean;
    float inv = rsqrtf(var + BN_EPS);
    float s = gamma[tid] * inv;
    sld[tid] = s;
    tld[tid] = beta[tid] - mean * s;
  }
  __syncthreads();

  int wave = tid >> 6;
  int lane = tid & 63;
  int n16 = lane & 15;
  int quad = lane >> 4;

  bf16x8 bhi[2][4];
  bf16x8 blo[2][4];
#pragma unroll
  for (int ct = 0; ct < 2; ++ct) {
    int n = (wave * 2 + ct) * 16 + n16;
#pragma unroll
    for (int kk = 0; kk < 4; ++kk) {
      int k0 = kk * 32 + quad * 8;
      bhi[ct][kk] = *(const bf16x8*)(Whi + (size_t)n * DMODEL + k0);
      blo[ct][kk] = *(const bf16x8*)(Wlo + (size_t)n * DMODEL + k0);
    }
  }
  float bc[2];
  bc[0] = bias[(wave * 2 + 0) * 16 + n16];
  bc[1] = bias[(wave * 2 + 1) * 16 + n16];

  float ssum[2] = {0.0f, 0.0f};
  float ssq[2] = {0.0f, 0.0f};

  const int NCHUNK = N_NODES / 32;   // 3125 exact
  for (int c = blockIdx.x; c < NCHUNK; c += gridDim.x) {
    int row0 = c * 32;
    bf16x8 a[2][4];
#pragma unroll
    for (int t = 0; t < 2; ++t) {
      const __bf16* xr = X + (size_t)(row0 + t * 16 + n16) * DMODEL;
#pragma unroll
      for (int kk = 0; kk < 4; ++kk) {
        a[t][kk] = *(const bf16x8*)(xr + kk * 32 + quad * 8);
      }
    }
#pragma unroll
    for (int kk = 0; kk < 4; ++kk) {
      int k0 = kk * 32 + quad * 8;
      float4 s0 = *(const float4*)(sld + k0);
      float4 s1 = *(const float4*)(sld + k0 + 4);
      float4 t0 = *(const float4*)(tld + k0);
      float4 t1 = *(const float4*)(tld + k0 + 4);
      float sv[8];
      float tv[8];
      sv[0] = s0.x; sv[1] = s0.y; sv[2] = s0.z; sv[3] = s0.w;
      sv[4] = s1.x; sv[5] = s1.y; sv[6] = s1.z; sv[7] = s1.w;
      tv[0] = t0.x; tv[1] = t0.y; tv[2] = t0.z; tv[3] = t0.w;
      tv[4] = t1.x; tv[5] = t1.y; tv[6] = t1.z; tv[7] = t1.w;
#pragma unroll
      for (int t = 0; t < 2; ++t) {
#pragma unroll
        for (int jj = 0; jj < 8; ++jj) {
          float f = (float)a[t][kk][jj];
          a[t][kk][jj] = (__bf16)fmaxf(sv[jj] * f + tv[jj], 0.0f);
        }
      }
    }

    f32x4 acc[2][2];
#pragma unroll
    for (int t = 0; t < 2; ++t)
#pragma unroll
      for (int ct = 0; ct < 2; ++ct)
#pragma unroll
        for (int r = 0; r < 4; ++r) acc[t][ct][r] = 0.0f;

#pragma unroll
    for (int kk = 0; kk < 4; ++kk) {
#pragma unroll
      for (int ct = 0; ct < 2; ++ct) {
#pragma unroll
        for (int t = 0; t < 2; ++t) {
          acc[t][ct] = __builtin_amdgcn_mfma_f32_16x16x32_bf16(a[t][kk], bhi[ct][kk], acc[t][ct], 0, 0, 0);
          acc[t][ct] = __builtin_amdgcn_mfma_f32_16x16x32_bf16(a[t][kk], blo[ct][kk], acc[t][ct], 0, 0, 0);
        }
      }
    }

#pragma unroll
    for (int t = 0; t < 2; ++t) {
#pragma unroll
      for (int ct = 0; ct < 2; ++ct) {
        int col = (wave * 2 + ct) * 16 + n16;
#pragma unroll
        for (int r = 0; r < 4; ++r) {
          int row = row0 + t * 16 + quad * 4 + r;
          float v = acc[t][ct][r] + bc[ct];
          Y[(size_t)row * DMODEL + col] = (__bf16)v;
          ssum[ct] += v;
          ssq[ct] += v * v;
        }
      }
    }
  }

  int slot = blockIdx.x & (NSLOT - 1);
#pragma unroll
  for (int ct = 0; ct < 2; ++ct) {
    int col = (wave * 2 + ct) * 16 + n16;
    float s = ssum[ct];
    float q = ssq[ct];
    s += __shfl_xor(s, 16);
    q += __shfl_xor(q, 16);
    s += __shfl_xor(s, 32);
    q += __shfl_xor(q, 32);
    if (quad == 0) {
      atomicAdd(&statpart[slot * (2 * DMODEL) + col], s);
      atomicAdd(&statpart[slot * (2 * DMODEL) + DMODEL + col], q);
    }
  }
}

// ------- pooling partial sums of raw h (affine deferred to classifier) -------
__global__ void k_pool(const __bf16* __restrict__ h, const int* __restrict__ gstart,
                       float* __restrict__ psum) {
  int g = blockIdx.x;
  int slice = blockIdx.y;   // 0..7
  int lane = threadIdx.x;   // 64
  int d0 = lane * 2;
  int i0 = gstart[g];
  int i1 = gstart[g + 1];
  float a0 = 0.0f;
  float a1 = 0.0f;
  for (int i = i0 + slice; i < i1; i += 8) {
    bf16x2 v = *(const bf16x2*)(h + (size_t)i * DMODEL + d0);
    a0 += (float)v[0];
    a1 += (float)v[1];
  }
  atomicAdd(&psum[g * DMODEL + d0], a0);
  atomicAdd(&psum[g * DMODEL + d0 + 1], a1);
}

// ------- classifier: fused final BN2 finalize, mean + affine, Linear-ReLU-Linear ---
__global__ void k_classifier(const float* __restrict__ psum, const int* __restrict__ gstart,
                             const float* __restrict__ statB,
                             const float* __restrict__ gamma, const float* __restrict__ beta,
                             const float* __restrict__ cw1, const float* __restrict__ cb1,
                             const float* __restrict__ cw2, const float* __restrict__ cb2,
                             float* __restrict__ out) {
  __shared__ float pl[DMODEL];
  __shared__ float hid[DMODEL];
  int g = blockIdx.x;
  int d = threadIdx.x;
  float sum = 0.0f;
  float sq = 0.0f;
  for (int p = 0; p < NSLOT; ++p) {
    sum += statB[p * (2 * DMODEL) + d];
    sq  += statB[p * (2 * DMODEL) + DMODEL + d];
  }
  float mean = sum * (1.0f / N_NODES);
  float var = sq * (1.0f / N_NODES) - mean * mean;
  float inv = rsqrtf(var + BN_EPS);
  float s2 = gamma[d] * inv;
  float t2 = beta[d] - mean * s2;

  int cnt = gstart[g + 1] - gstart[g];
  pl[d] = (cnt > 0) ? (s2 * (psum[g * DMODEL + d] / (float)cnt) + t2) : 0.0f;
  __syncthreads();
  float acc = cb1[d];
  for (int k = 0; k < DMODEL; ++k) acc += pl[k] * cw1[k * DMODEL + d];
  hid[d] = fmaxf(acc, 0.0f);
  __syncthreads();
  if (d < NCLASS) {
    float acc2 = cb2[d];
    for (int k = 0; k < DMODEL; ++k) acc2 += hid[k] * cw2[k * NCLASS + d];
    out[g * NCLASS + d] = acc2;
  }
}

// ---------------- launcher ----------------
extern "C" void kernel_launch(void* const* d_in, const int* in_sizes, int n_in,
                              void* d_out, int out_size, void* d_ws, size_t ws_size,
                              hipStream_t stream) {
  const int*   x      = (const int*)d_in[0];
  const int*   ei     = (const int*)d_in[1];
  const float* ea     = (const float*)d_in[2];
  const int*   batch  = (const int*)d_in[3];
  const float* emb    = (const float*)d_in[4];
  const float* edge_w = (const float*)d_in[5];
  const float* edge_b = (const float*)d_in[6];
  const float* w1     = (const float*)d_in[7];
  const float* b1     = (const float*)d_in[8];
  const float* g1     = (const float*)d_in[9];
  const float* beta1  = (const float*)d_in[10];
  const float* w2     = (const float*)d_in[11];
  const float* b2     = (const float*)d_in[12];
  const float* ng     = (const float*)d_in[13];
  const float* nb     = (const float*)d_in[14];
  const float* cw1    = (const float*)d_in[15];
  const float* cb1    = (const float*)d_in[16];
  const float* cw2    = (const float*)d_in[17];
  const float* cb2    = (const float*)d_in[18];

  char* ws = (char*)d_ws;
  size_t off = 0;
  auto alloc = [&](size_t bytes) -> void* {
    void* p = ws + off;
    off += (bytes + 255) & ~(size_t)255;
    return p;
  };

  __bf16* h_bf      = (__bf16*)alloc((size_t)N_NODES * DMODEL * sizeof(__bf16));
  __bf16* y1_bf     = (__bf16*)alloc((size_t)N_NODES * DMODEL * sizeof(__bf16));
  int*    row_start = (int*)alloc((N_NODES + 1) * sizeof(int));
  int*    cursor    = (int*)alloc(N_NODES * sizeof(int));
  int*    deg       = (int*)alloc(N_NODES * sizeof(int));
  int*    sched     = (int*)alloc(N_NODES * sizeof(int));
  int2*   epack     = (int2*)alloc((size_t)N_EDGES * sizeof(int2));
  __bf16* wt_hi     = (__bf16*)alloc((size_t)NLAYERS * 2 * DMODEL * DMODEL * sizeof(__bf16));
  __bf16* wt_lo     = (__bf16*)alloc((size_t)NLAYERS * 2 * DMODEL * DMODEL * sizeof(__bf16));
  float*  statA     = (float*)alloc((size_t)NLAYERS * STATSZ * sizeof(float));
  float*  statB     = (float*)alloc((size_t)NLAYERS * STATSZ * sizeof(float));
  int*    gstart    = (int*)alloc((NGRAPH + 1) * sizeof(int));
  float*  psum      = (float*)alloc((size_t)NGRAPH * DMODEL * sizeof(float));
  int*    dbin      = (int*)alloc(NBIN * sizeof(int));
  int*    dcursor   = (int*)alloc(NBIN * sizeof(int));
  int*    bsum      = (int*)alloc(512 * sizeof(int));
  int*    bsumx     = (int*)alloc(512 * sizeof(int));

  auto statAL = [&](int l) { return statA + (size_t)l * STATSZ; };
  auto statBL = [&](int l) { return statB + (size_t)l * STATSZ; };

  const int nbScan = (N_NODES + 255) / 256;              // 391
  const int nbEdge = (N_EDGES + 255) / 256;              // 2344
  const int nbPre1 = (N_NODES * DMODEL / 8 + 255) / 256; // 6250
  const int nbGemm = 782;                                // gemm2 grid-stride
  const int nbFuse = N_NODES / 32;                       // 3125, one 32-node block

  k_pre1<<<nbPre1, 256, 0, stream>>>(deg, statA, statB, psum, dbin,
                                     w1, w2, wt_hi, wt_lo, batch, gstart,
                                     x, emb, h_bf);
  k_hist<<<nbEdge, 256, 0, stream>>>(ei + N_EDGES, deg);
  k_pre2<<<nbScan, 256, 0, stream>>>(deg, row_start, bsum, dbin);
  k_pre3<<<1, 512, 0, stream>>>(bsum, bsumx, nbScan, dbin, dcursor);
  k_pre4<<<nbScan, 256, 0, stream>>>(row_start, cursor, bsumx, deg, dcursor, sched);
  k_scatter<<<nbEdge, 256, 0, stream>>>(ei, ea, cursor, epack);

  for (int l = 0; l < NLAYERS; ++l) {
    const float* sPrev = (l > 0) ? statBL(l - 1) : (const float*)nullptr;
    const float* gPrev = (l > 0) ? (ng + (size_t)(l - 1) * DMODEL) : (const float*)nullptr;
    const float* bPrev = (l > 0) ? (nb + (size_t)(l - 1) * DMODEL) : (const float*)nullptr;
    // fused: z (LDS only) = agg(act(h)); y1 = z @ w1[l] + b1[l]; stats -> statA[l]
    k_aggemm<<<nbFuse, 256, 0, stream>>>(
        h_bf, row_start, epack, sched,
        edge_w + (size_t)l * 2 * DMODEL,
        edge_b + (size_t)l * DMODEL,
        sPrev, gPrev, bPrev, (l > 0) ? 1 : 0,
        wt_hi + (size_t)(l * 2 + 0) * DMODEL * DMODEL,
        wt_lo + (size_t)(l * 2 + 0) * DMODEL * DMODEL,
        b1 + (size_t)l * DMODEL,
        y1_bf, statAL(l));
    // h = relu(BN1(y1)) @ w2[l] + b2[l]; BN1 finalize fused; stats -> statB[l]
    k_gemm2<<<nbGemm, 256, 0, stream>>>(
        y1_bf,
        wt_hi + (size_t)(l * 2 + 1) * DMODEL * DMODEL,
        wt_lo + (size_t)(l * 2 + 1) * DMODEL * DMODEL,
        b2 + (size_t)l * DMODEL,
        statAL(l), g1 + (size_t)l * DMODEL, beta1 + (size_t)l * DMODEL,
        h_bf, statBL(l));
  }

  dim3 poolGrid(NGRAPH, 8);
  k_pool<<<poolGrid, 64, 0, stream>>>(h_bf, gstart, psum);
  k_classifier<<<NGRAPH, DMODEL, 0, stream>>>(psum, gstart, statBL(NLAYERS - 1),
                                              ng + (size_t)(NLAYERS - 1) * DMODEL,
                                              nb + (size_t)(NLAYERS - 1) * DMODEL,
                                              cw1, cb1, cw2, cb2, (float*)d_out);
}